// Round 1
// baseline (3406.408 us; speedup 1.0000x reference)
//
#include <hip/hip_runtime.h>
#include <hip/hip_bf16.h>
#include <math.h>

#define B_   16
#define L_   2048
#define D_   128
#define H_   4
#define NL_  4
#define DK_  32
#define DFF_ 256
#define INTD_ 11
#define F_OUT 129
#define DM_  16
#define FMINV (-3.402823466e38f)

#define BL_  (B_*L_)      // 32768
#define SZ_X (BL_*D_)     // 4194304 floats

// ---------------------------------------------------------------------------
// Embedding: x[b,l,d] = tanh(t*W1t+b1t)@W2t + tanh(v*W1v+b1v)@W2v + var_table[var]
// ---------------------------------------------------------------------------
__global__ __launch_bounds__(128)
void embed_kernel(const float* __restrict__ values, const float* __restrict__ times,
                  const int* __restrict__ variables,
                  const float* __restrict__ W1t, const float* __restrict__ b1t,
                  const float* __restrict__ W2t,
                  const float* __restrict__ W1v, const float* __restrict__ b1v,
                  const float* __restrict__ W2v,
                  const float* __restrict__ var_table, float* __restrict__ x)
{
    int bl = blockIdx.x;
    int t  = threadIdx.x;
    __shared__ float th[INTD_], vh[INTD_];
    if (t < INTD_)                th[t]    = tanhf(times[bl]  * W1t[t]    + b1t[t]);
    if (t >= 64 && t < 64+INTD_)  vh[t-64] = tanhf(values[bl] * W1v[t-64] + b1v[t-64]);
    __syncthreads();
    int var = variables[bl];
    float acc = var_table[var*D_ + t];
#pragma unroll
    for (int i = 0; i < INTD_; ++i)
        acc += th[i]*W2t[i*D_ + t] + vh[i]*W2v[i*D_ + t];
    x[bl*D_ + t] = acc;
}

// ---------------------------------------------------------------------------
// Repack per-layer QKV weights [3][H][D][DK] -> [3][D][H*DK] for uniform GEMM
// ---------------------------------------------------------------------------
__global__ __launch_bounds__(256)
void repack_kernel(const float* __restrict__ Wq, const float* __restrict__ Wk,
                   const float* __restrict__ Wv, float* __restrict__ wr)
{
    int idx = blockIdx.x*256 + threadIdx.x;   // 0..49151
    int s = idx >> 14;
    int r = idx & 16383;
    int d = r >> 7;
    int c = r & 127;
    int h = c >> 5;
    int e = c & 31;
    const float* src = (s == 0) ? Wq : (s == 1) ? Wk : Wv;
    wr[idx] = src[(h*D_ + d)*DK_ + e];
}

// ---------------------------------------------------------------------------
// Tiled fp32 GEMM: out[M][N] = A[M][K] @ W[K][N] (+ epilogue)
// 64x32 tile per 256-thread block; thread computes 2 rows x 4 cols.
// EPI: 0=none 1=+resid 2=+bias,gelu(exact) 3=+bias,+resid 4=+bias,tanh
// ---------------------------------------------------------------------------
template<int EPI>
__global__ __launch_bounds__(256)
void gemm_kernel(const float* __restrict__ A, const float* __restrict__ W,
                 const float* __restrict__ bias, const float* __restrict__ resid,
                 float* __restrict__ out, int N, int K)
{
    __shared__ float xs[64][132];   // pad 132: 2-way max on compute reads
    __shared__ float ws[128][32];
    int t  = threadIdx.x;
    int tx = t & 7, ty = t >> 3;
    int row0 = blockIdx.x * 64;
    int col0 = blockIdx.y * 32;
    float acc[2][4] = {{0,0,0,0},{0,0,0,0}};

    for (int kb = 0; kb < K; kb += 128) {
#pragma unroll
        for (int i = 0; i < 8; ++i) {           // A tile 64x128
            int j = t + i*256;
            int r = j >> 5;
            int c = (j & 31) << 2;
            *(float4*)&xs[r][c] = *(const float4*)(A + (row0 + r)*K + kb + c);
        }
#pragma unroll
        for (int i = 0; i < 4; ++i) {           // W tile 128x32
            int j = t + i*256;
            int r = j >> 3;
            int c = (j & 7) << 2;
            *(float4*)&ws[r][c] = *(const float4*)(W + (kb + r)*N + col0 + c);
        }
        __syncthreads();
#pragma unroll 4
        for (int d = 0; d < 128; ++d) {
            float a0 = xs[2*ty][d], a1 = xs[2*ty+1][d];
            float4 w = *(float4*)&ws[d][tx<<2];
            acc[0][0] += a0*w.x; acc[0][1] += a0*w.y; acc[0][2] += a0*w.z; acc[0][3] += a0*w.w;
            acc[1][0] += a1*w.x; acc[1][1] += a1*w.y; acc[1][2] += a1*w.z; acc[1][3] += a1*w.w;
        }
        __syncthreads();
    }
#pragma unroll
    for (int r = 0; r < 2; ++r) {
        int row = row0 + 2*ty + r;
#pragma unroll
        for (int c = 0; c < 4; ++c) {
            int col = col0 + (tx<<2) + c;
            float v = acc[r][c];
            if (EPI == 2 || EPI == 3 || EPI == 4) v += bias[col];
            if (EPI == 2) v = 0.5f * v * (1.0f + erff(v * 0.70710678118654752f));
            if (EPI == 4) v = tanhf(v);
            if (EPI == 1 || EPI == 3) v += resid[row*N + col];
            out[row*N + col] = v;
        }
    }
}

// ---------------------------------------------------------------------------
// Flash attention, fp32, online softmax with reference-exact FMIN semantics.
// Block = (64-query tile, head h, batch b); loops over 32 key tiles of 64.
// NOTE: no 1/sqrt(dk) scaling (matches reference).
// ---------------------------------------------------------------------------
__global__ __launch_bounds__(256)
void attn_kernel(const float* __restrict__ q, const float* __restrict__ k,
                 const float* __restrict__ v, const int* __restrict__ mask,
                 float* __restrict__ o)
{
    int t  = threadIdx.x;
    int qt = blockIdx.x;   // 0..31
    int h  = blockIdx.y;   // 0..3
    int b  = blockIdx.z;   // 0..15

    __shared__ float Qs[64][36];
    __shared__ float KsT[32][68];   // transposed: KsT[e][key]
    __shared__ float Vs[64][36];
    __shared__ float Ss[64][68];
    __shared__ float alpha_s[64], l_s[64];
    __shared__ int   qm[64], km[64];

    const float* qbase = q + (b*L_ + qt*64)*D_ + h*DK_;
#pragma unroll
    for (int i = 0; i < 2; ++i) {
        int j = t + i*256;
        int r = j >> 3;
        int c = (j & 7) << 2;
        *(float4*)&Qs[r][c] = *(const float4*)(qbase + r*D_ + c);
    }
    if (t < 64) qm[t] = mask[b*L_ + qt*64 + t];

    int tx = t & 7, ty = t >> 3;      // S-compute / PV mapping
    int srow = t >> 2, ssub = t & 3;  // softmax mapping (4 lanes per row)
    float m_old = -INFINITY, l_run = 0.0f;
    float4 o0 = {0,0,0,0}, o1 = {0,0,0,0};

    for (int kt = 0; kt < L_/64; ++kt) {
        __syncthreads();              // prior PV done before K/V/Ss overwrite
        const float* kbase = k + (b*L_ + kt*64)*D_ + h*DK_;
        const float* vbase = v + (b*L_ + kt*64)*D_ + h*DK_;
#pragma unroll
        for (int i = 0; i < 2; ++i) {
            int j = t + i*256;
            int r = j >> 3;           // key row 0..63
            int c = (j & 7) << 2;     // dim 0,4..28
            float4 kv = *(const float4*)(kbase + r*D_ + c);
            KsT[c+0][r] = kv.x; KsT[c+1][r] = kv.y; KsT[c+2][r] = kv.z; KsT[c+3][r] = kv.w;
            *(float4*)&Vs[r][c] = *(const float4*)(vbase + r*D_ + c);
        }
        if (t < 64) km[t] = mask[b*L_ + kt*64 + t];
        __syncthreads();

        // S tile: rows 2ty,2ty+1; cols 8tx..8tx+7
        float s0[8] = {0,0,0,0,0,0,0,0}, s1[8] = {0,0,0,0,0,0,0,0};
#pragma unroll 4
        for (int e = 0; e < DK_; ++e) {
            float a0 = Qs[2*ty][e], a1 = Qs[2*ty+1][e];
            float4 k0 = *(float4*)&KsT[e][tx<<3];
            float4 k1 = *(float4*)&KsT[e][(tx<<3)+4];
            s0[0]+=a0*k0.x; s0[1]+=a0*k0.y; s0[2]+=a0*k0.z; s0[3]+=a0*k0.w;
            s0[4]+=a0*k1.x; s0[5]+=a0*k1.y; s0[6]+=a0*k1.z; s0[7]+=a0*k1.w;
            s1[0]+=a1*k0.x; s1[1]+=a1*k0.y; s1[2]+=a1*k0.z; s1[3]+=a1*k0.w;
            s1[4]+=a1*k1.x; s1[5]+=a1*k1.y; s1[6]+=a1*k1.z; s1[7]+=a1*k1.w;
        }
        {
            int r0m = qm[2*ty], r1m = qm[2*ty+1];
#pragma unroll
            for (int cc = 0; cc < 8; ++cc) {
                int c = (cc + ty) & 7;        // rotate store order: spread banks
                int col = (tx<<3) + c;
                int kmv = km[col];
                Ss[2*ty  ][col] = s0[c] + ((r0m && kmv) ? 0.0f : FMINV);
                Ss[2*ty+1][col] = s1[c] + ((r1m && kmv) ? 0.0f : FMINV);
            }
        }
        __syncthreads();

        // online softmax over this 64-key tile (4 lanes per row, k = ssub+4i)
        float tmax = -INFINITY;
#pragma unroll
        for (int i = 0; i < 16; ++i) tmax = fmaxf(tmax, Ss[srow][ssub + 4*i]);
        tmax = fmaxf(tmax, __shfl_xor(tmax, 1));
        tmax = fmaxf(tmax, __shfl_xor(tmax, 2));
        float mnew  = fmaxf(m_old, tmax);
        float alpha = expf(m_old - mnew);     // exp(-inf)=0 on first tile
        float psum = 0.0f;
#pragma unroll
        for (int i = 0; i < 16; ++i) {
            int kk = ssub + 4*i;
            float p = expf(Ss[srow][kk] - mnew);  // FMIN-FMIN=0 -> uniform row
            Ss[srow][kk] = p;
            psum += p;
        }
        psum += __shfl_xor(psum, 1);
        psum += __shfl_xor(psum, 2);
        l_run = l_run * alpha + psum;
        m_old = mnew;
        if (ssub == 0) { alpha_s[srow] = alpha; l_s[srow] = l_run; }
        __syncthreads();

        // O = O*alpha + P @ V : rows 2ty,2ty+1; dims 4tx..4tx+3
        {
            float a0 = alpha_s[2*ty], a1 = alpha_s[2*ty+1];
            o0.x*=a0; o0.y*=a0; o0.z*=a0; o0.w*=a0;
            o1.x*=a1; o1.y*=a1; o1.z*=a1; o1.w*=a1;
#pragma unroll 4
            for (int kk = 0; kk < 64; ++kk) {
                float p0 = Ss[2*ty][kk], p1 = Ss[2*ty+1][kk];
                float4 vv = *(float4*)&Vs[kk][tx<<2];
                o0.x += p0*vv.x; o0.y += p0*vv.y; o0.z += p0*vv.z; o0.w += p0*vv.w;
                o1.x += p1*vv.x; o1.y += p1*vv.y; o1.z += p1*vv.z; o1.w += p1*vv.w;
            }
        }
    }

    float inv0 = 1.0f / l_s[2*ty];
    float inv1 = 1.0f / l_s[2*ty+1];
    o0.x*=inv0; o0.y*=inv0; o0.z*=inv0; o0.w*=inv0;
    o1.x*=inv1; o1.y*=inv1; o1.z*=inv1; o1.w*=inv1;
    float* obase = o + (b*L_ + qt*64)*D_ + h*DK_;
    *(float4*)(obase + (2*ty  )*D_ + (tx<<2)) = o0;
    *(float4*)(obase + (2*ty+1)*D_ + (tx<<2)) = o1;
}

// ---------------------------------------------------------------------------
// att[b,l] = tanh(x@Wf+bf) . uf  (+ FMIN mask add). tmp precomputed by gemm<4>.
// ---------------------------------------------------------------------------
__global__ __launch_bounds__(256)
void attdot_kernel(const float* __restrict__ tmp, const float* __restrict__ uf,
                   const int* __restrict__ mask, float* __restrict__ att)
{
    int t   = threadIdx.x;
    int row = blockIdx.x*64 + (t >> 2);
    int sub = t & 3;
    const float* rp = tmp + row*D_ + sub*32;
    const float* up = uf  + sub*32;
    float acc = 0.0f;
#pragma unroll
    for (int j = 0; j < 8; ++j) {
        float4 xv = *(const float4*)(rp + 4*j);
        float4 uv = *(const float4*)(up + 4*j);
        acc += xv.x*uv.x + xv.y*uv.y + xv.z*uv.z + xv.w*uv.w;
    }
    acc += __shfl_xor(acc, 1);
    acc += __shfl_xor(acc, 2);
    if (sub == 0) att[row] = acc + (mask[row] ? 0.0f : FMINV);
}

// ---------------------------------------------------------------------------
// Per-batch softmax pooling: ts[b,d] = sum_l softmax(att)[l] * x[b,l,d]
// ---------------------------------------------------------------------------
__global__ __launch_bounds__(256)
void pool_kernel(const float* __restrict__ att, const float* __restrict__ x,
                 float* __restrict__ ts)
{
    int b = blockIdx.x, t = threadIdx.x;
    __shared__ float red[4];
    __shared__ float p_s[L_];
    __shared__ float part[2][128];

    float m = -INFINITY;
    for (int l = t; l < L_; l += 256) m = fmaxf(m, att[b*L_ + l]);
#pragma unroll
    for (int s = 1; s < 64; s <<= 1) m = fmaxf(m, __shfl_xor(m, s));
    if ((t & 63) == 0) red[t >> 6] = m;
    __syncthreads();
    m = fmaxf(fmaxf(red[0], red[1]), fmaxf(red[2], red[3]));
    __syncthreads();

    float s = 0.0f;
    for (int l = t; l < L_; l += 256) {
        float p = expf(att[b*L_ + l] - m);
        p_s[l] = p;
        s += p;
    }
#pragma unroll
    for (int st = 1; st < 64; st <<= 1) s += __shfl_xor(s, st);
    if ((t & 63) == 0) red[t >> 6] = s;
    __syncthreads();
    s = red[0] + red[1] + red[2] + red[3];
    float inv = 1.0f / s;

    int td = t & 127, half = t >> 7;
    float acc = 0.0f;
    const float* xb = x + ((size_t)(b*L_ + half*1024))*D_ + td;
    for (int i = 0; i < 1024; ++i) acc += p_s[half*1024 + i] * xb[(size_t)i*D_];
    part[half][td] = acc;
    __syncthreads();
    if (t < 128) ts[b*D_ + t] = (part[0][t] + part[1][t]) * inv;
}

// ---------------------------------------------------------------------------
// Demographics MLP: demo = tanh(demog@Wd1+bd1)@Wd2+bd2    (single block)
// ---------------------------------------------------------------------------
__global__ __launch_bounds__(256)
void demo_kernel(const float* __restrict__ demog, const float* __restrict__ Wd1,
                 const float* __restrict__ bd1, const float* __restrict__ Wd2,
                 const float* __restrict__ bd2, float* __restrict__ demo_out)
{
    int t = threadIdx.x;
    __shared__ float dsm[B_][DM_];
    __shared__ float hs[B_][2*D_];
    if (t < B_*DM_) dsm[t >> 4][t & 15] = demog[t];
    __syncthreads();
    {
        int col = t;   // 0..255
#pragma unroll
        for (int r = 0; r < B_; ++r) {
            float acc = bd1[col];
#pragma unroll
            for (int kk = 0; kk < DM_; ++kk) acc += dsm[r][kk]*Wd1[kk*(2*D_)+col];
            hs[r][col] = tanhf(acc);
        }
    }
    __syncthreads();
    {
        int c  = t & (D_-1);
        int r0 = t >> 7;
        for (int r = r0; r < B_; r += 2) {
            float acc = bd2[c];
            for (int kk = 0; kk < 2*D_; ++kk) acc += hs[r][kk]*Wd2[kk*D_+c];
            demo_out[r*D_+c] = acc;
        }
    }
}

// ---------------------------------------------------------------------------
// Head: out[b,f] = concat(ts,demo)[b] @ Wh + bh
// ---------------------------------------------------------------------------
__global__ __launch_bounds__(256)
void head_kernel(const float* __restrict__ ts, const float* __restrict__ demo,
                 const float* __restrict__ Wh, const float* __restrict__ bh,
                 float* __restrict__ out)
{
    int b = blockIdx.x, t = threadIdx.x;
    if (t >= F_OUT) return;
    float acc = bh[t];
    for (int k2 = 0; k2 < D_; ++k2) acc += ts[b*D_ + k2]   * Wh[k2*F_OUT + t];
    for (int k2 = 0; k2 < D_; ++k2) acc += demo[b*D_ + k2] * Wh[(D_+k2)*F_OUT + t];
    out[b*F_OUT + t] = acc;
}

// ---------------------------------------------------------------------------
extern "C" void kernel_launch(void* const* d_in, const int* in_sizes, int n_in,
                              void* d_out, int out_size, void* d_ws, size_t ws_size,
                              hipStream_t stream)
{
    (void)in_sizes; (void)n_in; (void)out_size; (void)ws_size;
    const float* values       = (const float*)d_in[0];
    const float* times        = (const float*)d_in[1];
    const int*   variables    = (const int*)  d_in[2];
    const int*   input_mask   = (const int*)  d_in[3];
    const float* demographics = (const float*)d_in[4];
    const float* W1t = (const float*)d_in[5];
    const float* b1t = (const float*)d_in[6];
    const float* W2t = (const float*)d_in[7];
    const float* W1v = (const float*)d_in[8];
    const float* b1v = (const float*)d_in[9];
    const float* W2v = (const float*)d_in[10];
    const float* var_table = (const float*)d_in[11];
    const float* Wq  = (const float*)d_in[12];
    const float* Wk  = (const float*)d_in[13];
    const float* Wv  = (const float*)d_in[14];
    const float* Wo  = (const float*)d_in[15];
    const float* W1  = (const float*)d_in[16];
    const float* b1  = (const float*)d_in[17];
    const float* W2  = (const float*)d_in[18];
    const float* b2  = (const float*)d_in[19];
    const float* Wf  = (const float*)d_in[20];
    const float* bfv = (const float*)d_in[21];
    const float* uf  = (const float*)d_in[22];
    const float* Wd1 = (const float*)d_in[23];
    const float* bd1 = (const float*)d_in[24];
    const float* Wd2 = (const float*)d_in[25];
    const float* bd2 = (const float*)d_in[26];
    const float* Wh  = (const float*)d_in[27];
    const float* bhv = (const float*)d_in[28];
    float* out = (float*)d_out;

    // Workspace layout (floats). o aliases q (each attn block writes only the
    // q-region it alone reads, after reading it); ffn hidden aliases k+v.
    float* ws    = (float*)d_ws;
    float* x     = ws;
    float* qb    = ws + (size_t)SZ_X;
    float* kb    = ws + (size_t)2*SZ_X;
    float* vb    = ws + (size_t)3*SZ_X;
    float* ob    = qb;                    // alias
    float* hb    = kb;                    // alias, 2*SZ_X (kb..vb)
    float* tmpb  = qb;                    // alias, post-layers
    float* wr    = ws + (size_t)4*SZ_X;   // 3*128*128
    float* attb  = wr + 3*D_*D_;          // BL_
    float* tsb   = attb + BL_;            // B_*D_
    float* demob = tsb + B_*D_;           // B_*D_

    embed_kernel<<<BL_, 128, 0, stream>>>(values, times, variables,
                                          W1t, b1t, W2t, W1v, b1v, W2v,
                                          var_table, x);
    demo_kernel<<<1, 256, 0, stream>>>(demographics, Wd1, bd1, Wd2, bd2, demob);

    for (int i = 0; i < NL_; ++i) {
        repack_kernel<<<192, 256, 0, stream>>>(Wq + (size_t)i*H_*D_*DK_,
                                               Wk + (size_t)i*H_*D_*DK_,
                                               Wv + (size_t)i*H_*D_*DK_, wr);
        gemm_kernel<0><<<dim3(BL_/64, D_/32), 256, 0, stream>>>(x, wr,            nullptr, nullptr, qb, D_, D_);
        gemm_kernel<0><<<dim3(BL_/64, D_/32), 256, 0, stream>>>(x, wr + D_*D_,    nullptr, nullptr, kb, D_, D_);
        gemm_kernel<0><<<dim3(BL_/64, D_/32), 256, 0, stream>>>(x, wr + 2*D_*D_,  nullptr, nullptr, vb, D_, D_);
        attn_kernel<<<dim3(L_/64, H_, B_), 256, 0, stream>>>(qb, kb, vb, input_mask, ob);
        gemm_kernel<1><<<dim3(BL_/64, D_/32), 256, 0, stream>>>(ob, Wo + (size_t)i*D_*D_, nullptr, x, x, D_, D_);
        gemm_kernel<2><<<dim3(BL_/64, DFF_/32), 256, 0, stream>>>(x, W1 + (size_t)i*D_*DFF_, b1 + i*DFF_, nullptr, hb, DFF_, D_);
        gemm_kernel<3><<<dim3(BL_/64, D_/32), 256, 0, stream>>>(hb, W2 + (size_t)i*DFF_*D_, b2 + i*D_, x, x, D_, DFF_);
    }

    gemm_kernel<4><<<dim3(BL_/64, D_/32), 256, 0, stream>>>(x, Wf, bfv, nullptr, tmpb, D_, D_);
    attdot_kernel<<<BL_/64, 256, 0, stream>>>(tmpb, uf, input_mask, attb);
    pool_kernel<<<B_, 256, 0, stream>>>(attb, x, tsb);
    head_kernel<<<B_, 256, 0, stream>>>(tsb, demob, Wh, bhv, out);
}

// Round 3
// 1977.104 us; speedup vs baseline: 1.7229x; 1.7229x over previous
//
#include <hip/hip_runtime.h>
#include <hip/hip_bf16.h>
#include <math.h>

#define B_   16
#define L_   2048
#define D_   128
#define H_   4
#define NL_  4
#define DK_  32
#define DFF_ 256
#define INTD_ 11
#define F_OUT 129
#define DM_  16
#define FMINV (-3.402823466e38f)

#define BL_  (B_*L_)      // 32768
#define SZ_X (BL_*D_)     // 4194304 floats

typedef __attribute__((ext_vector_type(8))) short bf16x8;
typedef __attribute__((ext_vector_type(4))) float f32x4;

static __device__ __forceinline__ short f2bf(float x) {
    union { __hip_bfloat16 h; short s; } u;
    u.h = __float2bfloat16(x);
    return u.s;
}
static __device__ __forceinline__ float bf2f(short s) {
    union { __hip_bfloat16 h; short t; } u;
    u.t = s;
    return __bfloat162float(u.h);
}

// ---------------------------------------------------------------------------
// Embedding: x[b,l,d] = tanh(t*W1t+b1t)@W2t + tanh(v*W1v+b1v)@W2v + var_table[var]
// ---------------------------------------------------------------------------
__global__ __launch_bounds__(128)
void embed_kernel(const float* __restrict__ values, const float* __restrict__ times,
                  const int* __restrict__ variables,
                  const float* __restrict__ W1t, const float* __restrict__ b1t,
                  const float* __restrict__ W2t,
                  const float* __restrict__ W1v, const float* __restrict__ b1v,
                  const float* __restrict__ W2v,
                  const float* __restrict__ var_table, float* __restrict__ x)
{
    int bl = blockIdx.x;
    int t  = threadIdx.x;
    __shared__ float th[INTD_], vh[INTD_];
    if (t < INTD_)                th[t]    = tanhf(times[bl]  * W1t[t]    + b1t[t]);
    if (t >= 64 && t < 64+INTD_)  vh[t-64] = tanhf(values[bl] * W1v[t-64] + b1v[t-64]);
    __syncthreads();
    int var = variables[bl];
    float acc = var_table[var*D_ + t];
#pragma unroll
    for (int i = 0; i < INTD_; ++i)
        acc += th[i]*W2t[i*D_ + t] + vh[i]*W2v[i*D_ + t];
    x[bl*D_ + t] = acc;
}

// ---------------------------------------------------------------------------
// Repack per-layer QKV weights [3][H][D][DK] -> [3][D][H*DK] for uniform GEMM
// ---------------------------------------------------------------------------
__global__ __launch_bounds__(256)
void repack_kernel(const float* __restrict__ Wq, const float* __restrict__ Wk,
                   const float* __restrict__ Wv, float* __restrict__ wr)
{
    int idx = blockIdx.x*256 + threadIdx.x;   // 0..49151
    int s = idx >> 14;
    int r = idx & 16383;
    int d = r >> 7;
    int c = r & 127;
    int h = c >> 5;
    int e = c & 31;
    const float* src = (s == 0) ? Wq : (s == 1) ? Wk : Wv;
    wr[idx] = src[(h*D_ + d)*DK_ + e];
}

// ---------------------------------------------------------------------------
// Tiled fp32 GEMM: out[M][N] = A[M][K] @ W[K][N] (+ epilogue)
// EPI: 0=none 1=+resid 2=+bias,gelu(exact) 3=+bias,+resid 4=+bias,tanh
// ---------------------------------------------------------------------------
template<int EPI>
__global__ __launch_bounds__(256)
void gemm_kernel(const float* __restrict__ A, const float* __restrict__ W,
                 const float* __restrict__ bias, const float* __restrict__ resid,
                 float* __restrict__ out, int N, int K)
{
    __shared__ float xs[64][132];
    __shared__ float ws[128][32];
    int t  = threadIdx.x;
    int tx = t & 7, ty = t >> 3;
    int row0 = blockIdx.x * 64;
    int col0 = blockIdx.y * 32;
    float acc[2][4] = {{0,0,0,0},{0,0,0,0}};

    for (int kb = 0; kb < K; kb += 128) {
#pragma unroll
        for (int i = 0; i < 8; ++i) {
            int j = t + i*256;
            int r = j >> 5;
            int c = (j & 31) << 2;
            *(float4*)&xs[r][c] = *(const float4*)(A + (row0 + r)*K + kb + c);
        }
#pragma unroll
        for (int i = 0; i < 4; ++i) {
            int j = t + i*256;
            int r = j >> 3;
            int c = (j & 7) << 2;
            *(float4*)&ws[r][c] = *(const float4*)(W + (kb + r)*N + col0 + c);
        }
        __syncthreads();
#pragma unroll 4
        for (int d = 0; d < 128; ++d) {
            float a0 = xs[2*ty][d], a1 = xs[2*ty+1][d];
            float4 w = *(float4*)&ws[d][tx<<2];
            acc[0][0] += a0*w.x; acc[0][1] += a0*w.y; acc[0][2] += a0*w.z; acc[0][3] += a0*w.w;
            acc[1][0] += a1*w.x; acc[1][1] += a1*w.y; acc[1][2] += a1*w.z; acc[1][3] += a1*w.w;
        }
        __syncthreads();
    }
#pragma unroll
    for (int r = 0; r < 2; ++r) {
        int row = row0 + 2*ty + r;
#pragma unroll
        for (int c = 0; c < 4; ++c) {
            int col = col0 + (tx<<2) + c;
            float v = acc[r][c];
            if (EPI == 2 || EPI == 3 || EPI == 4) v += bias[col];
            if (EPI == 2) v = 0.5f * v * (1.0f + erff(v * 0.70710678118654752f));
            if (EPI == 4) v = tanhf(v);
            if (EPI == 1 || EPI == 3) v += resid[row*N + col];
            out[row*N + col] = v;
        }
    }
}

// ---------------------------------------------------------------------------
// MFMA flash attention (bf16 16x16x32), reference-exact FMIN semantics.
// S^T = K·Q^T per 64-key tile; hi/lo bf16 split on Q,K,P,V so every matmul
// carries ~2^-18 relative error (fp32-quality):
//   S   = Khi·Qhi + Khi·Qlo + Klo·Qhi
//   O  += Phi·Vhi + Phi·Vlo + Plo·Vhi
// Softmax/masking in fp32 with finite-FMIN semantics. No 1/sqrt(dk) scaling.
// ---------------------------------------------------------------------------
__global__ __launch_bounds__(256)
void attn_mfma_kernel(const float* __restrict__ q, const float* __restrict__ k,
                      const float* __restrict__ v, const int* __restrict__ mask,
                      float* __restrict__ o)
{
    __shared__ short Khi [64*40];     // [key][dim] stride 40 (80B: 2-way banks)
    __shared__ short Klo [64*40];
    __shared__ short Vthi[32*72];     // [dim][key] stride 72 (144B: 2-way banks)
    __shared__ short Vtlo[32*72];
    __shared__ short Pshi[4][16*72];  // wave-private P [query][key]
    __shared__ short Pslo[4][16*72];
    __shared__ float kmf[64];
    __shared__ float al_ls[4][16];
    __shared__ float l_ls [4][16];

    const int t    = threadIdx.x;
    const int w    = t >> 6;
    const int lane = t & 63;
    const int m    = lane & 15;       // query-in-wave / C-D column index
    const int qd   = lane >> 4;       // quad
    const int qt = blockIdx.x, h = blockIdx.y, b = blockIdx.z;

    // ---- Q fragment (B-operand of S^T MFMA), register-resident hi/lo ----
    const int qrow = qt*64 + 16*w + m;
    const float* qp = q + ((size_t)(b*L_ + qrow))*D_ + h*DK_ + 8*qd;
    float qf[8];
    *(float4*)&qf[0] = *(const float4*)qp;
    *(float4*)&qf[4] = *(const float4*)(qp + 4);
    bf16x8 qhi, qlo;
#pragma unroll
    for (int j = 0; j < 8; ++j) {
        short hs = f2bf(qf[j]);
        qhi[j] = hs;
        qlo[j] = f2bf(qf[j] - bf2f(hs));
    }
    const int qmv = mask[b*L_ + qrow];

    float m_old = -INFINITY, l_run = 0.0f;
    f32x4 o_acc[2] = {{0,0,0,0},{0,0,0,0}};

    for (int kt = 0; kt < L_/64; ++kt) {
        __syncthreads();   // prior iteration's frag reads done
        // ---- stage K tile (hi/lo bf16) ----
        {
            int key = t >> 2, d0 = (t & 3) * 4;
#pragma unroll
            for (int half = 0; half < 2; ++half) {
                int d = d0 + 16*half;
                float4 kv = *(const float4*)(k + ((size_t)(b*L_ + kt*64 + key))*D_ + h*DK_ + d);
                short4 hi, lo;
                hi.x = f2bf(kv.x); lo.x = f2bf(kv.x - bf2f(hi.x));
                hi.y = f2bf(kv.y); lo.y = f2bf(kv.y - bf2f(hi.y));
                hi.z = f2bf(kv.z); lo.z = f2bf(kv.z - bf2f(hi.z));
                hi.w = f2bf(kv.w); lo.w = f2bf(kv.w - bf2f(hi.w));
                *(short4*)&Khi[key*40 + d] = hi;
                *(short4*)&Klo[key*40 + d] = lo;
            }
        }
        // ---- stage V transposed (hi/lo bf16) ----
        {
            int kp2 = t >> 3, d0 = (t & 7) * 4;
            const float* v0 = v + ((size_t)(b*L_ + kt*64 + 2*kp2))*D_ + h*DK_ + d0;
            float4 va = *(const float4*)v0;
            float4 vb2 = *(const float4*)(v0 + D_);
            float e0[4] = {va.x, va.y, va.z, va.w};
            float e1[4] = {vb2.x, vb2.y, vb2.z, vb2.w};
#pragma unroll
            for (int i = 0; i < 4; ++i) {
                short h0 = f2bf(e0[i]), h1 = f2bf(e1[i]);
                short l0 = f2bf(e0[i] - bf2f(h0));
                short l1 = f2bf(e1[i] - bf2f(h1));
                short2 sh; sh.x = h0; sh.y = h1;
                short2 sl; sl.x = l0; sl.y = l1;
                *(short2*)&Vthi[(d0+i)*72 + 2*kp2] = sh;
                *(short2*)&Vtlo[(d0+i)*72 + 2*kp2] = sl;
            }
        }
        if (t < 64) kmf[t] = mask[b*L_ + kt*64 + t] ? 0.0f : FMINV;
        __syncthreads();

        // ---- S^T = K·Q^T  (split-precision, fp32 acc) ----
        f32x4 sf[4];
#pragma unroll
        for (int k4 = 0; k4 < 4; ++k4) {
            bf16x8 ka = *(const bf16x8*)&Khi[(16*k4 + m)*40 + 8*qd];
            bf16x8 kl = *(const bf16x8*)&Klo[(16*k4 + m)*40 + 8*qd];
            f32x4 c = {0,0,0,0};
            c = __builtin_amdgcn_mfma_f32_16x16x32_bf16(ka, qhi, c, 0, 0, 0);
            c = __builtin_amdgcn_mfma_f32_16x16x32_bf16(ka, qlo, c, 0, 0, 0);
            c = __builtin_amdgcn_mfma_f32_16x16x32_bf16(kl, qhi, c, 0, 0, 0);
            sf[k4] = c;
        }

        // ---- mask add (finite FMIN, post-MFMA, fp32) ----
        float sv[16];
#pragma unroll
        for (int k4 = 0; k4 < 4; ++k4) {
            float4 kmv = *(const float4*)&kmf[16*k4 + 4*qd];
            sv[4*k4+0] = sf[k4][0] + (qmv ? kmv.x : FMINV);
            sv[4*k4+1] = sf[k4][1] + (qmv ? kmv.y : FMINV);
            sv[4*k4+2] = sf[k4][2] + (qmv ? kmv.z : FMINV);
            sv[4*k4+3] = sf[k4][3] + (qmv ? kmv.w : FMINV);
        }

        // ---- online softmax: this lane holds 16 of query m's 64 keys ----
        float tmax = sv[0];
#pragma unroll
        for (int j = 1; j < 16; ++j) tmax = fmaxf(tmax, sv[j]);
        tmax = fmaxf(tmax, __shfl_xor(tmax, 16));
        tmax = fmaxf(tmax, __shfl_xor(tmax, 32));
        float mnew  = fmaxf(m_old, tmax);
        float alpha = expf(m_old - mnew);      // exp(-inf)=0 first tile
        float psum = 0.0f;
        short pbh[16], pbl[16];
#pragma unroll
        for (int j = 0; j < 16; ++j) {
            float p = expf(sv[j] - mnew);      // FMIN-FMIN=0 -> uniform row
            psum += p;                         // exact fp32 normalizer
            short ph = f2bf(p);
            pbh[j] = ph;
            pbl[j] = f2bf(p - bf2f(ph));
        }
        psum += __shfl_xor(psum, 16);
        psum += __shfl_xor(psum, 32);
        l_run = l_run * alpha + psum;
        m_old = mnew;

        // ---- P store (C->A transpose), hi/lo ----
#pragma unroll
        for (int k4 = 0; k4 < 4; ++k4) {
            short4 s4h, s4l;
            s4h.x = pbh[4*k4+0]; s4h.y = pbh[4*k4+1]; s4h.z = pbh[4*k4+2]; s4h.w = pbh[4*k4+3];
            s4l.x = pbl[4*k4+0]; s4l.y = pbl[4*k4+1]; s4l.z = pbl[4*k4+2]; s4l.w = pbl[4*k4+3];
            *(short4*)&Pshi[w][m*72 + 16*k4 + 4*qd] = s4h;
            *(short4*)&Pslo[w][m*72 + 16*k4 + 4*qd] = s4l;
        }
        if (lane < 16) al_ls[w][lane] = alpha;   // in-wave LDS ordering

        // ---- O rescale + PV MFMA (split-precision) ----
        {
            float4 alr = *(const float4*)&al_ls[w][4*qd];   // alpha for rows 4qd+r
            o_acc[0][0]*=alr.x; o_acc[0][1]*=alr.y; o_acc[0][2]*=alr.z; o_acc[0][3]*=alr.w;
            o_acc[1][0]*=alr.x; o_acc[1][1]*=alr.y; o_acc[1][2]*=alr.z; o_acc[1][3]*=alr.w;
        }
#pragma unroll
        for (int s = 0; s < 2; ++s) {
            bf16x8 pah = *(const bf16x8*)&Pshi[w][m*72 + 32*s + 8*qd];
            bf16x8 pal = *(const bf16x8*)&Pslo[w][m*72 + 32*s + 8*qd];
#pragma unroll
            for (int tp = 0; tp < 2; ++tp) {
                bf16x8 vh = *(const bf16x8*)&Vthi[(16*tp + m)*72 + 32*s + 8*qd];
                bf16x8 vl = *(const bf16x8*)&Vtlo[(16*tp + m)*72 + 32*s + 8*qd];
                o_acc[tp] = __builtin_amdgcn_mfma_f32_16x16x32_bf16(pah, vh, o_acc[tp], 0, 0, 0);
                o_acc[tp] = __builtin_amdgcn_mfma_f32_16x16x32_bf16(pah, vl, o_acc[tp], 0, 0, 0);
                o_acc[tp] = __builtin_amdgcn_mfma_f32_16x16x32_bf16(pal, vh, o_acc[tp], 0, 0, 0);
            }
        }
    }

    if (lane < 16) l_ls[w][lane] = l_run;
    float4 lr = *(const float4*)&l_ls[w][4*qd];
    float li[4] = {1.0f/lr.x, 1.0f/lr.y, 1.0f/lr.z, 1.0f/lr.w};
#pragma unroll
    for (int tp = 0; tp < 2; ++tp)
#pragma unroll
        for (int r = 0; r < 4; ++r)
            o[((size_t)(b*L_ + qt*64 + 16*w + 4*qd + r))*D_ + h*DK_ + 16*tp + m] =
                o_acc[tp][r] * li[r];
}

// ---------------------------------------------------------------------------
// att[b,l] = tanh(x@Wf+bf) . uf  (+ FMIN mask add). tmp precomputed by gemm<4>.
// ---------------------------------------------------------------------------
__global__ __launch_bounds__(256)
void attdot_kernel(const float* __restrict__ tmp, const float* __restrict__ uf,
                   const int* __restrict__ mask, float* __restrict__ att)
{
    int t   = threadIdx.x;
    int row = blockIdx.x*64 + (t >> 2);
    int sub = t & 3;
    const float* rp = tmp + row*D_ + sub*32;
    const float* up = uf  + sub*32;
    float acc = 0.0f;
#pragma unroll
    for (int j = 0; j < 8; ++j) {
        float4 xv = *(const float4*)(rp + 4*j);
        float4 uv = *(const float4*)(up + 4*j);
        acc += xv.x*uv.x + xv.y*uv.y + xv.z*uv.z + xv.w*uv.w;
    }
    acc += __shfl_xor(acc, 1);
    acc += __shfl_xor(acc, 2);
    if (sub == 0) att[row] = acc + (mask[row] ? 0.0f : FMINV);
}

// ---------------------------------------------------------------------------
// Per-batch softmax pooling: ts[b,d] = sum_l softmax(att)[l] * x[b,l,d]
// ---------------------------------------------------------------------------
__global__ __launch_bounds__(256)
void pool_kernel(const float* __restrict__ att, const float* __restrict__ x,
                 float* __restrict__ ts)
{
    int b = blockIdx.x, t = threadIdx.x;
    __shared__ float red[4];
    __shared__ float p_s[L_];
    __shared__ float part[2][128];

    float m = -INFINITY;
    for (int l = t; l < L_; l += 256) m = fmaxf(m, att[b*L_ + l]);
#pragma unroll
    for (int s = 1; s < 64; s <<= 1) m = fmaxf(m, __shfl_xor(m, s));
    if ((t & 63) == 0) red[t >> 6] = m;
    __syncthreads();
    m = fmaxf(fmaxf(red[0], red[1]), fmaxf(red[2], red[3]));
    __syncthreads();

    float s = 0.0f;
    for (int l = t; l < L_; l += 256) {
        float p = expf(att[b*L_ + l] - m);
        p_s[l] = p;
        s += p;
    }
#pragma unroll
    for (int st = 1; st < 64; st <<= 1) s += __shfl_xor(s, st);
    if ((t & 63) == 0) red[t >> 6] = s;
    __syncthreads();
    s = red[0] + red[1] + red[2] + red[3];
    float inv = 1.0f / s;

    int td = t & 127, half = t >> 7;
    float acc = 0.0f;
    const float* xb = x + ((size_t)(b*L_ + half*1024))*D_ + td;
    for (int i = 0; i < 1024; ++i) acc += p_s[half*1024 + i] * xb[(size_t)i*D_];
    part[half][td] = acc;
    __syncthreads();
    if (t < 128) ts[b*D_ + t] = (part[0][t] + part[1][t]) * inv;
}

// ---------------------------------------------------------------------------
// Demographics MLP: demo = tanh(demog@Wd1+bd1)@Wd2+bd2    (single block)
// ---------------------------------------------------------------------------
__global__ __launch_bounds__(256)
void demo_kernel(const float* __restrict__ demog, const float* __restrict__ Wd1,
                 const float* __restrict__ bd1, const float* __restrict__ Wd2,
                 const float* __restrict__ bd2, float* __restrict__ demo_out)
{
    int t = threadIdx.x;
    __shared__ float dsm[B_][DM_];
    __shared__ float hs[B_][2*D_];
    if (t < B_*DM_) dsm[t >> 4][t & 15] = demog[t];
    __syncthreads();
    {
        int col = t;
#pragma unroll
        for (int r = 0; r < B_; ++r) {
            float acc = bd1[col];
#pragma unroll
            for (int kk = 0; kk < DM_; ++kk) acc += dsm[r][kk]*Wd1[kk*(2*D_)+col];
            hs[r][col] = tanhf(acc);
        }
    }
    __syncthreads();
    {
        int c  = t & (D_-1);
        int r0 = t >> 7;
        for (int r = r0; r < B_; r += 2) {
            float acc = bd2[c];
            for (int kk = 0; kk < 2*D_; ++kk) acc += hs[r][kk]*Wd2[kk*D_+c];
            demo_out[r*D_+c] = acc;
        }
    }
}

// ---------------------------------------------------------------------------
// Head: out[b,f] = concat(ts,demo)[b] @ Wh + bh
// ---------------------------------------------------------------------------
__global__ __launch_bounds__(256)
void head_kernel(const float* __restrict__ ts, const float* __restrict__ demo,
                 const float* __restrict__ Wh, const float* __restrict__ bh,
                 float* __restrict__ out)
{
    int b = blockIdx.x, t = threadIdx.x;
    if (t >= F_OUT) return;
    float acc = bh[t];
    for (int k2 = 0; k2 < D_; ++k2) acc += ts[b*D_ + k2]   * Wh[k2*F_OUT + t];
    for (int k2 = 0; k2 < D_; ++k2) acc += demo[b*D_ + k2] * Wh[(D_+k2)*F_OUT + t];
    out[b*F_OUT + t] = acc;
}

// ---------------------------------------------------------------------------
extern "C" void kernel_launch(void* const* d_in, const int* in_sizes, int n_in,
                              void* d_out, int out_size, void* d_ws, size_t ws_size,
                              hipStream_t stream)
{
    (void)in_sizes; (void)n_in; (void)out_size; (void)ws_size;
    const float* values       = (const float*)d_in[0];
    const float* times        = (const float*)d_in[1];
    const int*   variables    = (const int*)  d_in[2];
    const int*   input_mask   = (const int*)  d_in[3];
    const float* demographics = (const float*)d_in[4];
    const float* W1t = (const float*)d_in[5];
    const float* b1t = (const float*)d_in[6];
    const float* W2t = (const float*)d_in[7];
    const float* W1v = (const float*)d_in[8];
    const float* b1v = (const float*)d_in[9];
    const float* W2v = (const float*)d_in[10];
    const float* var_table = (const float*)d_in[11];
    const float* Wq  = (const float*)d_in[12];
    const float* Wk  = (const float*)d_in[13];
    const float* Wv  = (const float*)d_in[14];
    const float* Wo  = (const float*)d_in[15];
    const float* W1  = (const float*)d_in[16];
    const float* b1  = (const float*)d_in[17];
    const float* W2  = (const float*)d_in[18];
    const float* b2  = (const float*)d_in[19];
    const float* Wf  = (const float*)d_in[20];
    const float* bfv = (const float*)d_in[21];
    const float* uf  = (const float*)d_in[22];
    const float* Wd1 = (const float*)d_in[23];
    const float* bd1 = (const float*)d_in[24];
    const float* Wd2 = (const float*)d_in[25];
    const float* bd2 = (const float*)d_in[26];
    const float* Wh  = (const float*)d_in[27];
    const float* bhv = (const float*)d_in[28];
    float* out = (float*)d_out;

    float* ws    = (float*)d_ws;
    float* x     = ws;
    float* qb    = ws + (size_t)SZ_X;
    float* kb    = ws + (size_t)2*SZ_X;
    float* vb    = ws + (size_t)3*SZ_X;
    float* ob    = qb;                    // alias: block writes only its own q rows
    float* hb    = kb;                    // alias, 2*SZ_X
    float* tmpb  = qb;                    // alias, post-layers
    float* wr    = ws + (size_t)4*SZ_X;
    float* attb  = wr + 3*D_*D_;
    float* tsb   = attb + BL_;
    float* demob = tsb + B_*D_;

    embed_kernel<<<BL_, 128, 0, stream>>>(values, times, variables,
                                          W1t, b1t, W2t, W1v, b1v, W2v,
                                          var_table, x);
    demo_kernel<<<1, 256, 0, stream>>>(demographics, Wd1, bd1, Wd2, bd2, demob);

    for (int i = 0; i < NL_; ++i) {
        repack_kernel<<<192, 256, 0, stream>>>(Wq + (size_t)i*H_*D_*DK_,
                                               Wk + (size_t)i*H_*D_*DK_,
                                               Wv + (size_t)i*H_*D_*DK_, wr);
        gemm_kernel<0><<<dim3(BL_/64, D_/32), 256, 0, stream>>>(x, wr,            nullptr, nullptr, qb, D_, D_);
        gemm_kernel<0><<<dim3(BL_/64, D_/32), 256, 0, stream>>>(x, wr + D_*D_,    nullptr, nullptr, kb, D_, D_);
        gemm_kernel<0><<<dim3(BL_/64, D_/32), 256, 0, stream>>>(x, wr + 2*D_*D_,  nullptr, nullptr, vb, D_, D_);
        attn_mfma_kernel<<<dim3(L_/64, H_, B_), 256, 0, stream>>>(qb, kb, vb, input_mask, ob);
        gemm_kernel<1><<<dim3(BL_/64, D_/32), 256, 0, stream>>>(ob, Wo + (size_t)i*D_*D_, nullptr, x, x, D_, D_);
        gemm_kernel<2><<<dim3(BL_/64, DFF_/32), 256, 0, stream>>>(x, W1 + (size_t)i*D_*DFF_, b1 + i*DFF_, nullptr, hb, DFF_, D_);
        gemm_kernel<3><<<dim3(BL_/64, D_/32), 256, 0, stream>>>(hb, W2 + (size_t)i*DFF_*D_, b2 + i*D_, x, x, D_, DFF_);
    }

    gemm_kernel<4><<<dim3(BL_/64, D_/32), 256, 0, stream>>>(x, Wf, bfv, nullptr, tmpb, D_, D_);
    attdot_kernel<<<BL_/64, 256, 0, stream>>>(tmpb, uf, input_mask, attb);
    pool_kernel<<<B_, 256, 0, stream>>>(attb, x, tsb);
    head_kernel<<<B_, 256, 0, stream>>>(tsb, demob, Wh, bhv, out);
}

// Round 5
// 1671.825 us; speedup vs baseline: 2.0375x; 1.1826x over previous
//
#include <hip/hip_runtime.h>
#include <hip/hip_bf16.h>
#include <math.h>

#define B_   16
#define L_   2048
#define D_   128
#define H_   4
#define NL_  4
#define DK_  32
#define DFF_ 256
#define INTD_ 11
#define F_OUT 129
#define DM_  16
#define FMINV (-3.402823466e38f)

#define BL_  (B_*L_)      // 32768
#define SZ_X (BL_*D_)     // 4194304 floats

#define PSTR 72           // P-scratch row stride in shorts: >=64 keys, 16B-aligned, 2-way banks

typedef __attribute__((ext_vector_type(8))) short bf16x8;
typedef __attribute__((ext_vector_type(4))) float f32x4;

static __device__ __forceinline__ short f2bf(float x) {
    union { __hip_bfloat16 h; short s; } u;
    u.h = __float2bfloat16(x);
    return u.s;
}
static __device__ __forceinline__ float bf2f(short s) {
    union { __hip_bfloat16 h; short t; } u;
    u.t = s;
    return __bfloat162float(u.h);
}

// ---------------------------------------------------------------------------
// Embedding
// ---------------------------------------------------------------------------
__global__ __launch_bounds__(128)
void embed_kernel(const float* __restrict__ values, const float* __restrict__ times,
                  const int* __restrict__ variables,
                  const float* __restrict__ W1t, const float* __restrict__ b1t,
                  const float* __restrict__ W2t,
                  const float* __restrict__ W1v, const float* __restrict__ b1v,
                  const float* __restrict__ W2v,
                  const float* __restrict__ var_table, float* __restrict__ x)
{
    int bl = blockIdx.x;
    int t  = threadIdx.x;
    __shared__ float th[INTD_], vh[INTD_];
    if (t < INTD_)                th[t]    = tanhf(times[bl]  * W1t[t]    + b1t[t]);
    if (t >= 64 && t < 64+INTD_)  vh[t-64] = tanhf(values[bl] * W1v[t-64] + b1v[t-64]);
    __syncthreads();
    int var = variables[bl];
    float acc = var_table[var*D_ + t];
#pragma unroll
    for (int i = 0; i < INTD_; ++i)
        acc += th[i]*W2t[i*D_ + t] + vh[i]*W2v[i*D_ + t];
    x[bl*D_ + t] = acc;
}

// ---------------------------------------------------------------------------
// Repack per-layer QKV weights [3][H][D][DK] -> [3][D][H*DK]
// ---------------------------------------------------------------------------
__global__ __launch_bounds__(256)
void repack_kernel(const float* __restrict__ Wq, const float* __restrict__ Wk,
                   const float* __restrict__ Wv, float* __restrict__ wr)
{
    int idx = blockIdx.x*256 + threadIdx.x;   // 0..49151
    int s = idx >> 14;
    int r = idx & 16383;
    int d = r >> 7;
    int c = r & 127;
    int h = c >> 5;
    int e = c & 31;
    const float* src = (s == 0) ? Wq : (s == 1) ? Wk : Wv;
    wr[idx] = src[(h*D_ + d)*DK_ + e];
}

// ---------------------------------------------------------------------------
// Tiled fp32 GEMM: out[M][N] = A[M][K] @ W[K][N] (+ epilogue)
// EPI: 0=none 1=+resid 2=+bias,gelu(exact) 3=+bias,+resid 4=+bias,tanh
// ---------------------------------------------------------------------------
template<int EPI>
__global__ __launch_bounds__(256)
void gemm_kernel(const float* __restrict__ A, const float* __restrict__ W,
                 const float* __restrict__ bias, const float* __restrict__ resid,
                 float* __restrict__ out, int N, int K)
{
    __shared__ float xs[64][132];
    __shared__ float ws[128][32];
    int t  = threadIdx.x;
    int tx = t & 7, ty = t >> 3;
    int row0 = blockIdx.x * 64;
    int col0 = blockIdx.y * 32;
    float acc[2][4] = {{0,0,0,0},{0,0,0,0}};

    for (int kb = 0; kb < K; kb += 128) {
#pragma unroll
        for (int i = 0; i < 8; ++i) {
            int j = t + i*256;
            int r = j >> 5;
            int c = (j & 31) << 2;
            *(float4*)&xs[r][c] = *(const float4*)(A + (row0 + r)*K + kb + c);
        }
#pragma unroll
        for (int i = 0; i < 4; ++i) {
            int j = t + i*256;
            int r = j >> 3;
            int c = (j & 7) << 2;
            *(float4*)&ws[r][c] = *(const float4*)(W + (kb + r)*N + col0 + c);
        }
        __syncthreads();
#pragma unroll 4
        for (int d = 0; d < 128; ++d) {
            float a0 = xs[2*ty][d], a1 = xs[2*ty+1][d];
            float4 w = *(float4*)&ws[d][tx<<2];
            acc[0][0] += a0*w.x; acc[0][1] += a0*w.y; acc[0][2] += a0*w.z; acc[0][3] += a0*w.w;
            acc[1][0] += a1*w.x; acc[1][1] += a1*w.y; acc[1][2] += a1*w.z; acc[1][3] += a1*w.w;
        }
        __syncthreads();
    }
#pragma unroll
    for (int r = 0; r < 2; ++r) {
        int row = row0 + 2*ty + r;
#pragma unroll
        for (int c = 0; c < 4; ++c) {
            int col = col0 + (tx<<2) + c;
            float v = acc[r][c];
            if (EPI == 2 || EPI == 3 || EPI == 4) v += bias[col];
            if (EPI == 2) v = 0.5f * v * (1.0f + erff(v * 0.70710678118654752f));
            if (EPI == 4) v = tanhf(v);
            if (EPI == 1 || EPI == 3) v += resid[row*N + col];
            out[row*N + col] = v;
        }
    }
}

// ---------------------------------------------------------------------------
// GEMM for K/V projections: same matmul, epilogue splits fp32 -> bf16 hi/lo
// and stores head-major [b][h][l][32] so attention staging is a pure copy.
// ---------------------------------------------------------------------------
__global__ __launch_bounds__(256)
void gemm_kv_kernel(const float* __restrict__ A, const float* __restrict__ W,
                    short* __restrict__ ohi, short* __restrict__ olo)
{
    __shared__ float xs[64][132];
    __shared__ float ws[128][32];
    int t  = threadIdx.x;
    int tx = t & 7, ty = t >> 3;
    int row0 = blockIdx.x * 64;
    int col0 = blockIdx.y * 32;        // head h = blockIdx.y
    float acc[2][4] = {{0,0,0,0},{0,0,0,0}};

#pragma unroll
    for (int i = 0; i < 8; ++i) {
        int j = t + i*256;
        int r = j >> 5;
        int c = (j & 31) << 2;
        *(float4*)&xs[r][c] = *(const float4*)(A + (row0 + r)*D_ + c);
    }
#pragma unroll
    for (int i = 0; i < 4; ++i) {
        int j = t + i*256;
        int r = j >> 3;
        int c = (j & 7) << 2;
        *(float4*)&ws[r][c] = *(const float4*)(W + r*D_ + col0 + c);
    }
    __syncthreads();
#pragma unroll 4
    for (int d = 0; d < 128; ++d) {
        float a0 = xs[2*ty][d], a1 = xs[2*ty+1][d];
        float4 w = *(float4*)&ws[d][tx<<2];
        acc[0][0] += a0*w.x; acc[0][1] += a0*w.y; acc[0][2] += a0*w.z; acc[0][3] += a0*w.w;
        acc[1][0] += a1*w.x; acc[1][1] += a1*w.y; acc[1][2] += a1*w.z; acc[1][3] += a1*w.w;
    }

    const int h = blockIdx.y;
#pragma unroll
    for (int r = 0; r < 2; ++r) {
        int row = row0 + 2*ty + r;            // global b*L+l
        int bb  = row >> 11, l = row & 2047;
        size_t idx = ((size_t)((bb*4 + h)*2048 + l))*32 + (tx<<2);
        short4 hi, lo;
        float v0 = acc[r][0], v1 = acc[r][1], v2 = acc[r][2], v3 = acc[r][3];
        hi.x = f2bf(v0); lo.x = f2bf(v0 - bf2f(hi.x));
        hi.y = f2bf(v1); lo.y = f2bf(v1 - bf2f(hi.y));
        hi.z = f2bf(v2); lo.z = f2bf(v2 - bf2f(hi.z));
        hi.w = f2bf(v3); lo.w = f2bf(v3 - bf2f(hi.w));
        *(short4*)(ohi + idx) = hi;
        *(short4*)(olo + idx) = lo;
    }
}

// ---------------------------------------------------------------------------
// MFMA flash attention (bf16 16x16x32), reference-exact FMIN semantics.
// K/V arrive pre-split (hi/lo bf16, head-major) -> staging is pure copy.
//   S   = Khi·Qhi + Khi·Qlo + Klo·Qhi      (~2^-18 rel)
//   O  += Phi·Vhi + Phi·Vlo + Plo·Vhi
// Softmax in fp32, __expf (native); no 1/sqrt(dk) scaling.
// ---------------------------------------------------------------------------
__global__ __launch_bounds__(256)
void attn_mfma_kernel(const float* __restrict__ q,
                      const short* __restrict__ khi, const short* __restrict__ klo,
                      const short* __restrict__ vhi, const short* __restrict__ vlo,
                      const int* __restrict__ mask, float* __restrict__ o)
{
    __shared__ short KhiS[64*40];      // [key][dim] stride 40 (2-way banks, 16B rows)
    __shared__ short KloS[64*40];
    __shared__ short Vthi[32*72];      // [dim][key] stride 72
    __shared__ short Vtlo[32*72];
    __shared__ short Pshi[4][16*PSTR]; // wave-private P [query][key]: 64 keys + pad
    __shared__ short Pslo[4][16*PSTR];
    __shared__ float kmf[64];
    __shared__ float al_ls[4][16];
    __shared__ float l_ls [4][16];

    const int t    = threadIdx.x;
    const int w    = t >> 6;
    const int lane = t & 63;
    const int m    = lane & 15;
    const int qd   = lane >> 4;
    const int qt = blockIdx.x, h = blockIdx.y, b = blockIdx.z;

    const size_t hd = ((size_t)(b*4 + h))*2048*32;   // head-major K/V base

    // ---- Q fragment (B-operand), register-resident hi/lo ----
    const int qrow = qt*64 + 16*w + m;
    const float* qp = q + ((size_t)(b*L_ + qrow))*D_ + h*DK_ + 8*qd;
    float qf[8];
    *(float4*)&qf[0] = *(const float4*)qp;
    *(float4*)&qf[4] = *(const float4*)(qp + 4);
    bf16x8 qhi, qlo;
#pragma unroll
    for (int j = 0; j < 8; ++j) {
        short hs = f2bf(qf[j]);
        qhi[j] = hs;
        qlo[j] = f2bf(qf[j] - bf2f(hs));
    }
    const int qmv = mask[b*L_ + qrow];

    // staging index precompute
    const int skey = t >> 2, sd0 = (t & 3) * 8;       // K: 8 bf16 per thread
    const int kp2 = t >> 3, vd0 = (t & 7) * 4;        // V: 2 keys x 4 dims

    float m_old = -INFINITY, l_run = 0.0f;
    f32x4 o_acc[2] = {{0,0,0,0},{0,0,0,0}};

    for (int kt = 0; kt < L_/64; ++kt) {
        __syncthreads();
        // ---- stage K tiles: pure 16B copies ----
        {
            const size_t gk = hd + (size_t)kt*64*32 + t*8;
            bf16x8 a = *(const bf16x8*)(khi + gk);
            bf16x8 c = *(const bf16x8*)(klo + gk);
            *(bf16x8*)&KhiS[skey*40 + sd0] = a;
            *(bf16x8*)&KloS[skey*40 + sd0] = c;
        }
        // ---- stage V transposed: 8B loads + short2 repack (no conversion) ----
        {
            const size_t gv = hd + ((size_t)kt*64 + 2*kp2)*32 + vd0;
            short4 h0 = *(const short4*)(vhi + gv);
            short4 h1 = *(const short4*)(vhi + gv + 32);
            short4 l0 = *(const short4*)(vlo + gv);
            short4 l1 = *(const short4*)(vlo + gv + 32);
            short2 s2;
            s2.x=h0.x; s2.y=h1.x; *(short2*)&Vthi[(vd0+0)*72 + 2*kp2] = s2;
            s2.x=h0.y; s2.y=h1.y; *(short2*)&Vthi[(vd0+1)*72 + 2*kp2] = s2;
            s2.x=h0.z; s2.y=h1.z; *(short2*)&Vthi[(vd0+2)*72 + 2*kp2] = s2;
            s2.x=h0.w; s2.y=h1.w; *(short2*)&Vthi[(vd0+3)*72 + 2*kp2] = s2;
            s2.x=l0.x; s2.y=l1.x; *(short2*)&Vtlo[(vd0+0)*72 + 2*kp2] = s2;
            s2.x=l0.y; s2.y=l1.y; *(short2*)&Vtlo[(vd0+1)*72 + 2*kp2] = s2;
            s2.x=l0.z; s2.y=l1.z; *(short2*)&Vtlo[(vd0+2)*72 + 2*kp2] = s2;
            s2.x=l0.w; s2.y=l1.w; *(short2*)&Vtlo[(vd0+3)*72 + 2*kp2] = s2;
        }
        if (t < 64) kmf[t] = mask[b*L_ + kt*64 + t] ? 0.0f : FMINV;
        __syncthreads();

        // ---- S^T = K·Q^T (split-precision, fp32 acc) ----
        f32x4 sf[4];
#pragma unroll
        for (int k4 = 0; k4 < 4; ++k4) {
            bf16x8 ka = *(const bf16x8*)&KhiS[(16*k4 + m)*40 + 8*qd];
            bf16x8 kl = *(const bf16x8*)&KloS[(16*k4 + m)*40 + 8*qd];
            f32x4 c = {0,0,0,0};
            c = __builtin_amdgcn_mfma_f32_16x16x32_bf16(ka, qhi, c, 0, 0, 0);
            c = __builtin_amdgcn_mfma_f32_16x16x32_bf16(ka, qlo, c, 0, 0, 0);
            c = __builtin_amdgcn_mfma_f32_16x16x32_bf16(kl, qhi, c, 0, 0, 0);
            sf[k4] = c;
        }

        // ---- finite-FMIN mask add ----
        float sv[16];
#pragma unroll
        for (int k4 = 0; k4 < 4; ++k4) {
            float4 kmv = *(const float4*)&kmf[16*k4 + 4*qd];
            sv[4*k4+0] = sf[k4][0] + (qmv ? kmv.x : FMINV);
            sv[4*k4+1] = sf[k4][1] + (qmv ? kmv.y : FMINV);
            sv[4*k4+2] = sf[k4][2] + (qmv ? kmv.z : FMINV);
            sv[4*k4+3] = sf[k4][3] + (qmv ? kmv.w : FMINV);
        }

        // ---- online softmax (native exp) ----
        float tmax = sv[0];
#pragma unroll
        for (int j = 1; j < 16; ++j) tmax = fmaxf(tmax, sv[j]);
        tmax = fmaxf(tmax, __shfl_xor(tmax, 16));
        tmax = fmaxf(tmax, __shfl_xor(tmax, 32));
        float mnew  = fmaxf(m_old, tmax);
        float alpha = __expf(m_old - mnew);
        float psum = 0.0f;
        short pbh[16], pbl[16];
#pragma unroll
        for (int j = 0; j < 16; ++j) {
            float p = __expf(sv[j] - mnew);    // FMIN-FMIN=0 -> 1 (uniform row)
            psum += p;
            short ph = f2bf(p);
            pbh[j] = ph;
            pbl[j] = f2bf(p - bf2f(ph));
        }
        psum += __shfl_xor(psum, 16);
        psum += __shfl_xor(psum, 32);
        l_run = l_run * alpha + psum;
        m_old = mnew;

        // ---- P store (C->A transpose), hi/lo ----
#pragma unroll
        for (int k4 = 0; k4 < 4; ++k4) {
            short4 s4h, s4l;
            s4h.x = pbh[4*k4+0]; s4h.y = pbh[4*k4+1]; s4h.z = pbh[4*k4+2]; s4h.w = pbh[4*k4+3];
            s4l.x = pbl[4*k4+0]; s4l.y = pbl[4*k4+1]; s4l.z = pbl[4*k4+2]; s4l.w = pbl[4*k4+3];
            *(short4*)&Pshi[w][m*PSTR + 16*k4 + 4*qd] = s4h;
            *(short4*)&Pslo[w][m*PSTR + 16*k4 + 4*qd] = s4l;
        }
        if (lane < 16) al_ls[w][lane] = alpha;

        // ---- O rescale + PV (split-precision) ----
        {
            float4 alr = *(const float4*)&al_ls[w][4*qd];
            o_acc[0][0]*=alr.x; o_acc[0][1]*=alr.y; o_acc[0][2]*=alr.z; o_acc[0][3]*=alr.w;
            o_acc[1][0]*=alr.x; o_acc[1][1]*=alr.y; o_acc[1][2]*=alr.z; o_acc[1][3]*=alr.w;
        }
#pragma unroll
        for (int s = 0; s < 2; ++s) {
            bf16x8 pah = *(const bf16x8*)&Pshi[w][m*PSTR + 32*s + 8*qd];
            bf16x8 pal = *(const bf16x8*)&Pslo[w][m*PSTR + 32*s + 8*qd];
#pragma unroll
            for (int tp = 0; tp < 2; ++tp) {
                bf16x8 vh = *(const bf16x8*)&Vthi[(16*tp + m)*72 + 32*s + 8*qd];
                bf16x8 vl = *(const bf16x8*)&Vtlo[(16*tp + m)*72 + 32*s + 8*qd];
                o_acc[tp] = __builtin_amdgcn_mfma_f32_16x16x32_bf16(pah, vh, o_acc[tp], 0, 0, 0);
                o_acc[tp] = __builtin_amdgcn_mfma_f32_16x16x32_bf16(pah, vl, o_acc[tp], 0, 0, 0);
                o_acc[tp] = __builtin_amdgcn_mfma_f32_16x16x32_bf16(pal, vh, o_acc[tp], 0, 0, 0);
            }
        }
    }

    if (lane < 16) l_ls[w][lane] = l_run;
    float4 lr = *(const float4*)&l_ls[w][4*qd];
    float li[4] = {1.0f/lr.x, 1.0f/lr.y, 1.0f/lr.z, 1.0f/lr.w};
#pragma unroll
    for (int tp = 0; tp < 2; ++tp)
#pragma unroll
        for (int r = 0; r < 4; ++r)
            o[((size_t)(b*L_ + qt*64 + 16*w + 4*qd + r))*D_ + h*DK_ + 16*tp + m] =
                o_acc[tp][r] * li[r];
}

// ---------------------------------------------------------------------------
// att[b,l] = tanh(x@Wf+bf) . uf  (+ FMIN mask add)
// ---------------------------------------------------------------------------
__global__ __launch_bounds__(256)
void attdot_kernel(const float* __restrict__ tmp, const float* __restrict__ uf,
                   const int* __restrict__ mask, float* __restrict__ att)
{
    int t   = threadIdx.x;
    int row = blockIdx.x*64 + (t >> 2);
    int sub = t & 3;
    const float* rp = tmp + row*D_ + sub*32;
    const float* up = uf  + sub*32;
    float acc = 0.0f;
#pragma unroll
    for (int j = 0; j < 8; ++j) {
        float4 xv = *(const float4*)(rp + 4*j);
        float4 uv = *(const float4*)(up + 4*j);
        acc += xv.x*uv.x + xv.y*uv.y + xv.z*uv.z + xv.w*uv.w;
    }
    acc += __shfl_xor(acc, 1);
    acc += __shfl_xor(acc, 2);
    if (sub == 0) att[row] = acc + (mask[row] ? 0.0f : FMINV);
}

// ---------------------------------------------------------------------------
// Per-batch softmax pooling
// ---------------------------------------------------------------------------
__global__ __launch_bounds__(256)
void pool_kernel(const float* __restrict__ att, const float* __restrict__ x,
                 float* __restrict__ ts)
{
    int b = blockIdx.x, t = threadIdx.x;
    __shared__ float red[4];
    __shared__ float p_s[L_];
    __shared__ float part[2][128];

    float m = -INFINITY;
    for (int l = t; l < L_; l += 256) m = fmaxf(m, att[b*L_ + l]);
#pragma unroll
    for (int s = 1; s < 64; s <<= 1) m = fmaxf(m, __shfl_xor(m, s));
    if ((t & 63) == 0) red[t >> 6] = m;
    __syncthreads();
    m = fmaxf(fmaxf(red[0], red[1]), fmaxf(red[2], red[3]));
    __syncthreads();

    float s = 0.0f;
    for (int l = t; l < L_; l += 256) {
        float p = __expf(att[b*L_ + l] - m);
        p_s[l] = p;
        s += p;
    }
#pragma unroll
    for (int st = 1; st < 64; st <<= 1) s += __shfl_xor(s, st);
    if ((t & 63) == 0) red[t >> 6] = s;
    __syncthreads();
    s = red[0] + red[1] + red[2] + red[3];
    float inv = 1.0f / s;

    int td = t & 127, half = t >> 7;
    float acc = 0.0f;
    const float* xb = x + ((size_t)(b*L_ + half*1024))*D_ + td;
    for (int i = 0; i < 1024; ++i) acc += p_s[half*1024 + i] * xb[(size_t)i*D_];
    part[half][td] = acc;
    __syncthreads();
    if (t < 128) ts[b*D_ + t] = (part[0][t] + part[1][t]) * inv;
}

// ---------------------------------------------------------------------------
// Demographics MLP
// ---------------------------------------------------------------------------
__global__ __launch_bounds__(256)
void demo_kernel(const float* __restrict__ demog, const float* __restrict__ Wd1,
                 const float* __restrict__ bd1, const float* __restrict__ Wd2,
                 const float* __restrict__ bd2, float* __restrict__ demo_out)
{
    int t = threadIdx.x;
    __shared__ float dsm[B_][DM_];
    __shared__ float hs[B_][2*D_];
    if (t < B_*DM_) dsm[t >> 4][t & 15] = demog[t];
    __syncthreads();
    {
        int col = t;
#pragma unroll
        for (int r = 0; r < B_; ++r) {
            float acc = bd1[col];
#pragma unroll
            for (int kk = 0; kk < DM_; ++kk) acc += dsm[r][kk]*Wd1[kk*(2*D_)+col];
            hs[r][col] = tanhf(acc);
        }
    }
    __syncthreads();
    {
        int c  = t & (D_-1);
        int r0 = t >> 7;
        for (int r = r0; r < B_; r += 2) {
            float acc = bd2[c];
            for (int kk = 0; kk < 2*D_; ++kk) acc += hs[r][kk]*Wd2[kk*D_+c];
            demo_out[r*D_+c] = acc;
        }
    }
}

// ---------------------------------------------------------------------------
// Head
// ---------------------------------------------------------------------------
__global__ __launch_bounds__(256)
void head_kernel(const float* __restrict__ ts, const float* __restrict__ demo,
                 const float* __restrict__ Wh, const float* __restrict__ bh,
                 float* __restrict__ out)
{
    int b = blockIdx.x, t = threadIdx.x;
    if (t >= F_OUT) return;
    float acc = bh[t];
    for (int k2 = 0; k2 < D_; ++k2) acc += ts[b*D_ + k2]   * Wh[k2*F_OUT + t];
    for (int k2 = 0; k2 < D_; ++k2) acc += demo[b*D_ + k2] * Wh[(D_+k2)*F_OUT + t];
    out[b*F_OUT + t] = acc;
}

// ---------------------------------------------------------------------------
extern "C" void kernel_launch(void* const* d_in, const int* in_sizes, int n_in,
                              void* d_out, int out_size, void* d_ws, size_t ws_size,
                              hipStream_t stream)
{
    (void)in_sizes; (void)n_in; (void)out_size; (void)ws_size;
    const float* values       = (const float*)d_in[0];
    const float* times        = (const float*)d_in[1];
    const int*   variables    = (const int*)  d_in[2];
    const int*   input_mask   = (const int*)  d_in[3];
    const float* demographics = (const float*)d_in[4];
    const float* W1t = (const float*)d_in[5];
    const float* b1t = (const float*)d_in[6];
    const float* W2t = (const float*)d_in[7];
    const float* W1v = (const float*)d_in[8];
    const float* b1v = (const float*)d_in[9];
    const float* W2v = (const float*)d_in[10];
    const float* var_table = (const float*)d_in[11];
    const float* Wq  = (const float*)d_in[12];
    const float* Wk  = (const float*)d_in[13];
    const float* Wv  = (const float*)d_in[14];
    const float* Wo  = (const float*)d_in[15];
    const float* W1  = (const float*)d_in[16];
    const float* b1  = (const float*)d_in[17];
    const float* W2  = (const float*)d_in[18];
    const float* b2  = (const float*)d_in[19];
    const float* Wf  = (const float*)d_in[20];
    const float* bfv = (const float*)d_in[21];
    const float* uf  = (const float*)d_in[22];
    const float* Wd1 = (const float*)d_in[23];
    const float* bd1 = (const float*)d_in[24];
    const float* Wd2 = (const float*)d_in[25];
    const float* bd2 = (const float*)d_in[26];
    const float* Wh  = (const float*)d_in[27];
    const float* bhv = (const float*)d_in[28];
    float* out = (float*)d_out;

    // Workspace (floats):
    //  [0,SZ_X)      x
    //  [SZ_X,2SZ_X)  qb (attn writes o here; fusion tmp aliases here)
    //  [2SZ_X,4SZ_X) EITHER khi/klo/vhi/vlo (bf16, SZ_X shorts each)
    //                OR hb (FFN hidden, 2*SZ_X floats) — live ranges disjoint
    float* ws    = (float*)d_ws;
    float* x     = ws;
    float* qb    = ws + (size_t)SZ_X;
    float* region = ws + (size_t)2*SZ_X;
    short* khi   = (short*)region;
    short* klo   = khi + (size_t)SZ_X;
    short* vhi   = klo + (size_t)SZ_X;
    short* vlo   = vhi + (size_t)SZ_X;
    float* hb    = region;                // alias
    float* ob    = qb;                    // attn output aliases q
    float* tmpb  = qb;                    // fusion tmp aliases q (post-layers)
    float* wr    = ws + (size_t)4*SZ_X;
    float* attb  = wr + 3*D_*D_;
    float* tsb   = attb + BL_;
    float* demob = tsb + B_*D_;

    embed_kernel<<<BL_, 128, 0, stream>>>(values, times, variables,
                                          W1t, b1t, W2t, W1v, b1v, W2v,
                                          var_table, x);
    demo_kernel<<<1, 256, 0, stream>>>(demographics, Wd1, bd1, Wd2, bd2, demob);

    for (int i = 0; i < NL_; ++i) {
        repack_kernel<<<192, 256, 0, stream>>>(Wq + (size_t)i*H_*D_*DK_,
                                               Wk + (size_t)i*H_*D_*DK_,
                                               Wv + (size_t)i*H_*D_*DK_, wr);
        gemm_kernel<0><<<dim3(BL_/64, D_/32), 256, 0, stream>>>(x, wr, nullptr, nullptr, qb, D_, D_);
        gemm_kv_kernel<<<dim3(BL_/64, H_), 256, 0, stream>>>(x, wr + D_*D_,   khi, klo);
        gemm_kv_kernel<<<dim3(BL_/64, H_), 256, 0, stream>>>(x, wr + 2*D_*D_, vhi, vlo);
        attn_mfma_kernel<<<dim3(L_/64, H_, B_), 256, 0, stream>>>(qb, khi, klo, vhi, vlo, input_mask, ob);
        gemm_kernel<1><<<dim3(BL_/64, D_/32), 256, 0, stream>>>(ob, Wo + (size_t)i*D_*D_, nullptr, x, x, D_, D_);
        gemm_kernel<2><<<dim3(BL_/64, DFF_/32), 256, 0, stream>>>(x, W1 + (size_t)i*D_*DFF_, b1 + i*DFF_, nullptr, hb, DFF_, D_);
        gemm_kernel<3><<<dim3(BL_/64, D_/32), 256, 0, stream>>>(hb, W2 + (size_t)i*DFF_*D_, b2 + i*D_, x, x, D_, DFF_);
    }

    gemm_kernel<4><<<dim3(BL_/64, D_/32), 256, 0, stream>>>(x, Wf, bfv, nullptr, tmpb, D_, D_);
    attdot_kernel<<<BL_/64, 256, 0, stream>>>(tmpb, uf, input_mask, attb);
    pool_kernel<<<B_, 256, 0, stream>>>(attb, x, tsb);
    head_kernel<<<B_, 256, 0, stream>>>(tsb, demob, Wh, bhv, out);
}

// Round 6
// 1380.372 us; speedup vs baseline: 2.4677x; 1.2111x over previous
//
#include <hip/hip_runtime.h>
#include <hip/hip_bf16.h>
#include <math.h>

#define B_   16
#define L_   2048
#define D_   128
#define H_   4
#define NL_  4
#define DK_  32
#define DFF_ 256
#define INTD_ 11
#define F_OUT 129
#define DM_  16
#define FMINV (-3.402823466e38f)

#define BL_  (B_*L_)      // 32768
#define SZ_X (BL_*D_)     // 4194304 floats

#define PSTR 72           // attn P-scratch stride (>=64 keys, 16B-aligned, 2-way banks)

// per-layer pre-split weight offsets (in shorts), layout [col][K]
#define WT_Q 0
#define WT_K 16384
#define WT_V 32768
#define WT_O 49152
#define WT_1 65536        // 256 cols x 128
#define WT_2 98304        // 128 cols x 256
#define WT_TOT 131072

typedef __attribute__((ext_vector_type(8))) short bf16x8;
typedef __attribute__((ext_vector_type(4))) float f32x4;

static __device__ __forceinline__ short f2bf(float x) {
    union { __hip_bfloat16 h; short s; } u;
    u.h = __float2bfloat16(x);
    return u.s;
}
static __device__ __forceinline__ float bf2f(short s) {
    union { __hip_bfloat16 h; short t; } u;
    u.t = s;
    return __bfloat162float(u.h);
}
static __device__ __forceinline__ void split2(float v, short& h, short& l) {
    h = f2bf(v); l = f2bf(v - bf2f(h));
}

// ---------------------------------------------------------------------------
// Embedding
// ---------------------------------------------------------------------------
__global__ __launch_bounds__(128)
void embed_kernel(const float* __restrict__ values, const float* __restrict__ times,
                  const int* __restrict__ variables,
                  const float* __restrict__ W1t, const float* __restrict__ b1t,
                  const float* __restrict__ W2t,
                  const float* __restrict__ W1v, const float* __restrict__ b1v,
                  const float* __restrict__ W2v,
                  const float* __restrict__ var_table, float* __restrict__ x)
{
    int bl = blockIdx.x;
    int t  = threadIdx.x;
    __shared__ float th[INTD_], vh[INTD_];
    if (t < INTD_)                th[t]    = tanhf(times[bl]  * W1t[t]    + b1t[t]);
    if (t >= 64 && t < 64+INTD_)  vh[t-64] = tanhf(values[bl] * W1v[t-64] + b1v[t-64]);
    __syncthreads();
    int var = variables[bl];
    float acc = var_table[var*D_ + t];
#pragma unroll
    for (int i = 0; i < INTD_; ++i)
        acc += th[i]*W2t[i*D_ + t] + vh[i]*W2v[i*D_ + t];
    x[bl*D_ + t] = acc;
}

// ---------------------------------------------------------------------------
// Per-layer weight pre-split: fp32 -> bf16 hi/lo, transposed to [col][K].
// QKV from [H][D][DK]; Wo [128][128]; W1 [128][256]; W2 [256][128].
// ---------------------------------------------------------------------------
__global__ __launch_bounds__(256)
void split_layer_kernel(const float* __restrict__ Wq, const float* __restrict__ Wk,
                        const float* __restrict__ Wv, const float* __restrict__ Wo,
                        const float* __restrict__ W1, const float* __restrict__ W2,
                        short* __restrict__ hi, short* __restrict__ lo)
{
    int idx = blockIdx.x*256 + threadIdx.x;   // 0..131071
    float v;
    if (idx < 49152) {                        // Q/K/V
        int which = idx >> 14;
        int r = idx & 16383;
        int col = r >> 7, k = r & 127;        // col = h*32+e
        int h = col >> 5, e = col & 31;
        const float* src = (which == 0) ? Wq : (which == 1) ? Wk : Wv;
        v = src[(h*D_ + k)*DK_ + e];
    } else if (idx < 65536) {                 // Wo
        int r = idx - 49152;
        int col = r >> 7, k = r & 127;
        v = Wo[k*D_ + col];
    } else if (idx < 98304) {                 // W1
        int r = idx - 65536;
        int col = r >> 7, k = r & 127;        // col 0..255
        v = W1[k*DFF_ + col];
    } else {                                  // W2
        int r = idx - 98304;
        int col = r >> 8, k = r & 255;        // k 0..255
        v = W2[k*D_ + col];
    }
    short h2, l2; split2(v, h2, l2);
    hi[idx] = h2; lo[idx] = l2;
}

// Generic K x N fp32 -> [col][K] hi/lo (for Wf)
__global__ __launch_bounds__(256)
void split_nk_kernel(const float* __restrict__ W, short* __restrict__ hi,
                     short* __restrict__ lo, int N, int K)
{
    int idx = blockIdx.x*256 + threadIdx.x;
    int col = idx / K, k = idx - col*K;
    float v = W[k*N + col];
    short h2, l2; split2(v, h2, l2);
    hi[idx] = h2; lo[idx] = l2;
}

// ---------------------------------------------------------------------------
// MFMA GEMM: C[M][N] = A[M][K] @ W[K][N], W pre-split bf16 hi/lo in [col][K].
// hi/lo 3-term split => ~fp32 accuracy. Block: 64 rows x 128 cols, 4 waves
// (wave w owns cols 32w..32w+31). W is the MFMA A-operand (C^T orientation):
// lane's 4 acc regs = 4 consecutive C-cols -> float4 stores.
// EPI: 0=none 1=+resid 2=+bias,gelu 3=+bias,+resid 4=+bias,tanh
//      5=KV: split hi/lo, head-major [b][h][l][32]
// ---------------------------------------------------------------------------
template<int EPI>
__global__ __launch_bounds__(256)
void gemm_mfma(const float* __restrict__ A, const short* __restrict__ Whi,
               const short* __restrict__ Wlo, const float* __restrict__ bias,
               const float* __restrict__ resid, float* __restrict__ out,
               short* __restrict__ ohi, short* __restrict__ olo,
               int N, int K)
{
    __shared__ short Ahi[64*136];
    __shared__ short Alo[64*136];
    const int t = threadIdx.x;
    const int w = t >> 6, lane = t & 63;
    const int m = lane & 15, qd = lane >> 4;
    const int row0 = blockIdx.x * 64;
    const int col0 = blockIdx.y * 128;

    f32x4 acc[4][2];
#pragma unroll
    for (int r4 = 0; r4 < 4; ++r4)
#pragma unroll
        for (int j = 0; j < 2; ++j) acc[r4][j] = (f32x4){0,0,0,0};

    for (int kb = 0; kb < K; kb += 128) {
        if (kb) __syncthreads();
        // stage A chunk 64x128 as hi/lo bf16 (rows x k, stride 136 shorts)
#pragma unroll
        for (int i = 0; i < 8; ++i) {
            int r = (t >> 5) + 8*i;
            int c = (t & 31) * 4;
            float4 av = *(const float4*)(A + (size_t)(row0 + r)*K + kb + c);
            short4 hi4, lo4;
            split2(av.x, hi4.x, lo4.x);
            split2(av.y, hi4.y, lo4.y);
            split2(av.z, hi4.z, lo4.z);
            split2(av.w, hi4.w, lo4.w);
            *(short4*)&Ahi[r*136 + c] = hi4;
            *(short4*)&Alo[r*136 + c] = lo4;
        }
        __syncthreads();

#pragma unroll
        for (int ks = 0; ks < 4; ++ks) {
            bf16x8 wh[2], wl[2];
#pragma unroll
            for (int j = 0; j < 2; ++j) {
                size_t wi = (size_t)(col0 + 32*w + 16*j + m)*K + kb + 32*ks + 8*qd;
                wh[j] = *(const bf16x8*)(Whi + wi);
                wl[j] = *(const bf16x8*)(Wlo + wi);
            }
#pragma unroll
            for (int r4 = 0; r4 < 4; ++r4) {
                bf16x8 ah = *(const bf16x8*)&Ahi[(16*r4 + m)*136 + 32*ks + 8*qd];
                bf16x8 al = *(const bf16x8*)&Alo[(16*r4 + m)*136 + 32*ks + 8*qd];
#pragma unroll
                for (int j = 0; j < 2; ++j) {
                    acc[r4][j] = __builtin_amdgcn_mfma_f32_16x16x32_bf16(wh[j], ah, acc[r4][j], 0, 0, 0);
                    acc[r4][j] = __builtin_amdgcn_mfma_f32_16x16x32_bf16(wh[j], al, acc[r4][j], 0, 0, 0);
                    acc[r4][j] = __builtin_amdgcn_mfma_f32_16x16x32_bf16(wl[j], ah, acc[r4][j], 0, 0, 0);
                }
            }
        }
    }

    // epilogue: lane (m,qd), acc[r4][j] = C[row0+16r4+m][col0+32w+16j+4qd+{0..3}]
#pragma unroll
    for (int r4 = 0; r4 < 4; ++r4) {
        int row = row0 + 16*r4 + m;
#pragma unroll
        for (int j = 0; j < 2; ++j) {
            int col = col0 + 32*w + 16*j + 4*qd;
            f32x4 v = acc[r4][j];
            if (EPI == 2 || EPI == 3 || EPI == 4) {
                float4 bv = *(const float4*)(bias + col);
                v[0] += bv.x; v[1] += bv.y; v[2] += bv.z; v[3] += bv.w;
            }
            if (EPI == 2) {
#pragma unroll
                for (int e = 0; e < 4; ++e)
                    v[e] = 0.5f * v[e] * (1.0f + erff(v[e] * 0.70710678118654752f));
            }
            if (EPI == 4) {
#pragma unroll
                for (int e = 0; e < 4; ++e) v[e] = tanhf(v[e]);
            }
            if (EPI == 1 || EPI == 3) {
                float4 rv = *(const float4*)(resid + (size_t)row*N + col);
                v[0] += rv.x; v[1] += rv.y; v[2] += rv.z; v[3] += rv.w;
            }
            if (EPI == 5) {
                int bb = row >> 11, l = row & 2047;
                size_t idx = ((size_t)((bb*4 + w)*2048 + l))*32 + (col & 31);
                short4 hi4, lo4;
                split2(v[0], hi4.x, lo4.x);
                split2(v[1], hi4.y, lo4.y);
                split2(v[2], hi4.z, lo4.z);
                split2(v[3], hi4.w, lo4.w);
                *(short4*)(ohi + idx) = hi4;
                *(short4*)(olo + idx) = lo4;
            } else {
                float4 sv = {v[0], v[1], v[2], v[3]};
                *(float4*)(out + (size_t)row*N + col) = sv;
            }
        }
    }
}

// ---------------------------------------------------------------------------
// MFMA flash attention (unchanged from R5): hi/lo split, pre-split K/V,
// native exp, reference-exact FMIN semantics, no 1/sqrt(dk).
// ---------------------------------------------------------------------------
__global__ __launch_bounds__(256)
void attn_mfma_kernel(const float* __restrict__ q,
                      const short* __restrict__ khi, const short* __restrict__ klo,
                      const short* __restrict__ vhi, const short* __restrict__ vlo,
                      const int* __restrict__ mask, float* __restrict__ o)
{
    __shared__ short KhiS[64*40];
    __shared__ short KloS[64*40];
    __shared__ short Vthi[32*72];
    __shared__ short Vtlo[32*72];
    __shared__ short Pshi[4][16*PSTR];
    __shared__ short Pslo[4][16*PSTR];
    __shared__ float kmf[64];
    __shared__ float al_ls[4][16];
    __shared__ float l_ls [4][16];

    const int t    = threadIdx.x;
    const int w    = t >> 6;
    const int lane = t & 63;
    const int m    = lane & 15;
    const int qd   = lane >> 4;
    const int qt = blockIdx.x, h = blockIdx.y, b = blockIdx.z;

    const size_t hd = ((size_t)(b*4 + h))*2048*32;

    const int qrow = qt*64 + 16*w + m;
    const float* qp = q + ((size_t)(b*L_ + qrow))*D_ + h*DK_ + 8*qd;
    float qf[8];
    *(float4*)&qf[0] = *(const float4*)qp;
    *(float4*)&qf[4] = *(const float4*)(qp + 4);
    bf16x8 qhi, qlo;
#pragma unroll
    for (int j = 0; j < 8; ++j) {
        short hs = f2bf(qf[j]);
        qhi[j] = hs;
        qlo[j] = f2bf(qf[j] - bf2f(hs));
    }
    const int qmv = mask[b*L_ + qrow];

    const int skey = t >> 2, sd0 = (t & 3) * 8;
    const int kp2 = t >> 3, vd0 = (t & 7) * 4;

    float m_old = -INFINITY, l_run = 0.0f;
    f32x4 o_acc[2] = {{0,0,0,0},{0,0,0,0}};

    for (int kt = 0; kt < L_/64; ++kt) {
        __syncthreads();
        {
            const size_t gk = hd + (size_t)kt*64*32 + t*8;
            bf16x8 a = *(const bf16x8*)(khi + gk);
            bf16x8 c = *(const bf16x8*)(klo + gk);
            *(bf16x8*)&KhiS[skey*40 + sd0] = a;
            *(bf16x8*)&KloS[skey*40 + sd0] = c;
        }
        {
            const size_t gv = hd + ((size_t)kt*64 + 2*kp2)*32 + vd0;
            short4 h0 = *(const short4*)(vhi + gv);
            short4 h1 = *(const short4*)(vhi + gv + 32);
            short4 l0 = *(const short4*)(vlo + gv);
            short4 l1 = *(const short4*)(vlo + gv + 32);
            short2 s2;
            s2.x=h0.x; s2.y=h1.x; *(short2*)&Vthi[(vd0+0)*72 + 2*kp2] = s2;
            s2.x=h0.y; s2.y=h1.y; *(short2*)&Vthi[(vd0+1)*72 + 2*kp2] = s2;
            s2.x=h0.z; s2.y=h1.z; *(short2*)&Vthi[(vd0+2)*72 + 2*kp2] = s2;
            s2.x=h0.w; s2.y=h1.w; *(short2*)&Vthi[(vd0+3)*72 + 2*kp2] = s2;
            s2.x=l0.x; s2.y=l1.x; *(short2*)&Vtlo[(vd0+0)*72 + 2*kp2] = s2;
            s2.x=l0.y; s2.y=l1.y; *(short2*)&Vtlo[(vd0+1)*72 + 2*kp2] = s2;
            s2.x=l0.z; s2.y=l1.z; *(short2*)&Vtlo[(vd0+2)*72 + 2*kp2] = s2;
            s2.x=l0.w; s2.y=l1.w; *(short2*)&Vtlo[(vd0+3)*72 + 2*kp2] = s2;
        }
        if (t < 64) kmf[t] = mask[b*L_ + kt*64 + t] ? 0.0f : FMINV;
        __syncthreads();

        f32x4 sf[4];
#pragma unroll
        for (int k4 = 0; k4 < 4; ++k4) {
            bf16x8 ka = *(const bf16x8*)&KhiS[(16*k4 + m)*40 + 8*qd];
            bf16x8 kl = *(const bf16x8*)&KloS[(16*k4 + m)*40 + 8*qd];
            f32x4 c = {0,0,0,0};
            c = __builtin_amdgcn_mfma_f32_16x16x32_bf16(ka, qhi, c, 0, 0, 0);
            c = __builtin_amdgcn_mfma_f32_16x16x32_bf16(ka, qlo, c, 0, 0, 0);
            c = __builtin_amdgcn_mfma_f32_16x16x32_bf16(kl, qhi, c, 0, 0, 0);
            sf[k4] = c;
        }

        float sv[16];
#pragma unroll
        for (int k4 = 0; k4 < 4; ++k4) {
            float4 kmv = *(const float4*)&kmf[16*k4 + 4*qd];
            sv[4*k4+0] = sf[k4][0] + (qmv ? kmv.x : FMINV);
            sv[4*k4+1] = sf[k4][1] + (qmv ? kmv.y : FMINV);
            sv[4*k4+2] = sf[k4][2] + (qmv ? kmv.z : FMINV);
            sv[4*k4+3] = sf[k4][3] + (qmv ? kmv.w : FMINV);
        }

        float tmax = sv[0];
#pragma unroll
        for (int j = 1; j < 16; ++j) tmax = fmaxf(tmax, sv[j]);
        tmax = fmaxf(tmax, __shfl_xor(tmax, 16));
        tmax = fmaxf(tmax, __shfl_xor(tmax, 32));
        float mnew  = fmaxf(m_old, tmax);
        float alpha = __expf(m_old - mnew);
        float psum = 0.0f;
        short pbh[16], pbl[16];
#pragma unroll
        for (int j = 0; j < 16; ++j) {
            float p = __expf(sv[j] - mnew);
            psum += p;
            short ph = f2bf(p);
            pbh[j] = ph;
            pbl[j] = f2bf(p - bf2f(ph));
        }
        psum += __shfl_xor(psum, 16);
        psum += __shfl_xor(psum, 32);
        l_run = l_run * alpha + psum;
        m_old = mnew;

#pragma unroll
        for (int k4 = 0; k4 < 4; ++k4) {
            short4 s4h, s4l;
            s4h.x = pbh[4*k4+0]; s4h.y = pbh[4*k4+1]; s4h.z = pbh[4*k4+2]; s4h.w = pbh[4*k4+3];
            s4l.x = pbl[4*k4+0]; s4l.y = pbl[4*k4+1]; s4l.z = pbl[4*k4+2]; s4l.w = pbl[4*k4+3];
            *(short4*)&Pshi[w][m*PSTR + 16*k4 + 4*qd] = s4h;
            *(short4*)&Pslo[w][m*PSTR + 16*k4 + 4*qd] = s4l;
        }
        if (lane < 16) al_ls[w][lane] = alpha;

        {
            float4 alr = *(const float4*)&al_ls[w][4*qd];
            o_acc[0][0]*=alr.x; o_acc[0][1]*=alr.y; o_acc[0][2]*=alr.z; o_acc[0][3]*=alr.w;
            o_acc[1][0]*=alr.x; o_acc[1][1]*=alr.y; o_acc[1][2]*=alr.z; o_acc[1][3]*=alr.w;
        }
#pragma unroll
        for (int s = 0; s < 2; ++s) {
            bf16x8 pah = *(const bf16x8*)&Pshi[w][m*PSTR + 32*s + 8*qd];
            bf16x8 pal = *(const bf16x8*)&Pslo[w][m*PSTR + 32*s + 8*qd];
#pragma unroll
            for (int tp = 0; tp < 2; ++tp) {
                bf16x8 vh = *(const bf16x8*)&Vthi[(16*tp + m)*72 + 32*s + 8*qd];
                bf16x8 vl = *(const bf16x8*)&Vtlo[(16*tp + m)*72 + 32*s + 8*qd];
                o_acc[tp] = __builtin_amdgcn_mfma_f32_16x16x32_bf16(pah, vh, o_acc[tp], 0, 0, 0);
                o_acc[tp] = __builtin_amdgcn_mfma_f32_16x16x32_bf16(pah, vl, o_acc[tp], 0, 0, 0);
                o_acc[tp] = __builtin_amdgcn_mfma_f32_16x16x32_bf16(pal, vh, o_acc[tp], 0, 0, 0);
            }
        }
    }

    if (lane < 16) l_ls[w][lane] = l_run;
    float4 lr = *(const float4*)&l_ls[w][4*qd];
    float li[4] = {1.0f/lr.x, 1.0f/lr.y, 1.0f/lr.z, 1.0f/lr.w};
#pragma unroll
    for (int tp = 0; tp < 2; ++tp)
#pragma unroll
        for (int r = 0; r < 4; ++r)
            o[((size_t)(b*L_ + qt*64 + 16*w + 4*qd + r))*D_ + h*DK_ + 16*tp + m] =
                o_acc[tp][r] * li[r];
}

// ---------------------------------------------------------------------------
// att[b,l] = tanh(x@Wf+bf) . uf  (+ FMIN mask add)
// ---------------------------------------------------------------------------
__global__ __launch_bounds__(256)
void attdot_kernel(const float* __restrict__ tmp, const float* __restrict__ uf,
                   const int* __restrict__ mask, float* __restrict__ att)
{
    int t   = threadIdx.x;
    int row = blockIdx.x*64 + (t >> 2);
    int sub = t & 3;
    const float* rp = tmp + row*D_ + sub*32;
    const float* up = uf  + sub*32;
    float acc = 0.0f;
#pragma unroll
    for (int j = 0; j < 8; ++j) {
        float4 xv = *(const float4*)(rp + 4*j);
        float4 uv = *(const float4*)(up + 4*j);
        acc += xv.x*uv.x + xv.y*uv.y + xv.z*uv.z + xv.w*uv.w;
    }
    acc += __shfl_xor(acc, 1);
    acc += __shfl_xor(acc, 2);
    if (sub == 0) att[row] = acc + (mask[row] ? 0.0f : FMINV);
}

// ---------------------------------------------------------------------------
// Per-batch softmax pooling
// ---------------------------------------------------------------------------
__global__ __launch_bounds__(256)
void pool_kernel(const float* __restrict__ att, const float* __restrict__ x,
                 float* __restrict__ ts)
{
    int b = blockIdx.x, t = threadIdx.x;
    __shared__ float red[4];
    __shared__ float p_s[L_];
    __shared__ float part[2][128];

    float m = -INFINITY;
    for (int l = t; l < L_; l += 256) m = fmaxf(m, att[b*L_ + l]);
#pragma unroll
    for (int s = 1; s < 64; s <<= 1) m = fmaxf(m, __shfl_xor(m, s));
    if ((t & 63) == 0) red[t >> 6] = m;
    __syncthreads();
    m = fmaxf(fmaxf(red[0], red[1]), fmaxf(red[2], red[3]));
    __syncthreads();

    float s = 0.0f;
    for (int l = t; l < L_; l += 256) {
        float p = __expf(att[b*L_ + l] - m);
        p_s[l] = p;
        s += p;
    }
#pragma unroll
    for (int st = 1; st < 64; st <<= 1) s += __shfl_xor(s, st);
    if ((t & 63) == 0) red[t >> 6] = s;
    __syncthreads();
    s = red[0] + red[1] + red[2] + red[3];
    float inv = 1.0f / s;

    int td = t & 127, half = t >> 7;
    float acc = 0.0f;
    const float* xb = x + ((size_t)(b*L_ + half*1024))*D_ + td;
    for (int i = 0; i < 1024; ++i) acc += p_s[half*1024 + i] * xb[(size_t)i*D_];
    part[half][td] = acc;
    __syncthreads();
    if (t < 128) ts[b*D_ + t] = (part[0][t] + part[1][t]) * inv;
}

// ---------------------------------------------------------------------------
// Demographics MLP
// ---------------------------------------------------------------------------
__global__ __launch_bounds__(256)
void demo_kernel(const float* __restrict__ demog, const float* __restrict__ Wd1,
                 const float* __restrict__ bd1, const float* __restrict__ Wd2,
                 const float* __restrict__ bd2, float* __restrict__ demo_out)
{
    int t = threadIdx.x;
    __shared__ float dsm[B_][DM_];
    __shared__ float hs[B_][2*D_];
    if (t < B_*DM_) dsm[t >> 4][t & 15] = demog[t];
    __syncthreads();
    {
        int col = t;
#pragma unroll
        for (int r = 0; r < B_; ++r) {
            float acc = bd1[col];
#pragma unroll
            for (int kk = 0; kk < DM_; ++kk) acc += dsm[r][kk]*Wd1[kk*(2*D_)+col];
            hs[r][col] = tanhf(acc);
        }
    }
    __syncthreads();
    {
        int c  = t & (D_-1);
        int r0 = t >> 7;
        for (int r = r0; r < B_; r += 2) {
            float acc = bd2[c];
            for (int kk = 0; kk < 2*D_; ++kk) acc += hs[r][kk]*Wd2[kk*D_+c];
            demo_out[r*D_+c] = acc;
        }
    }
}

// ---------------------------------------------------------------------------
// Head
// ---------------------------------------------------------------------------
__global__ __launch_bounds__(256)
void head_kernel(const float* __restrict__ ts, const float* __restrict__ demo,
                 const float* __restrict__ Wh, const float* __restrict__ bh,
                 float* __restrict__ out)
{
    int b = blockIdx.x, t = threadIdx.x;
    if (t >= F_OUT) return;
    float acc = bh[t];
    for (int k2 = 0; k2 < D_; ++k2) acc += ts[b*D_ + k2]   * Wh[k2*F_OUT + t];
    for (int k2 = 0; k2 < D_; ++k2) acc += demo[b*D_ + k2] * Wh[(D_+k2)*F_OUT + t];
    out[b*F_OUT + t] = acc;
}

// ---------------------------------------------------------------------------
extern "C" void kernel_launch(void* const* d_in, const int* in_sizes, int n_in,
                              void* d_out, int out_size, void* d_ws, size_t ws_size,
                              hipStream_t stream)
{
    (void)in_sizes; (void)n_in; (void)out_size; (void)ws_size;
    const float* values       = (const float*)d_in[0];
    const float* times        = (const float*)d_in[1];
    const int*   variables    = (const int*)  d_in[2];
    const int*   input_mask   = (const int*)  d_in[3];
    const float* demographics = (const float*)d_in[4];
    const float* W1t = (const float*)d_in[5];
    const float* b1t = (const float*)d_in[6];
    const float* W2t = (const float*)d_in[7];
    const float* W1v = (const float*)d_in[8];
    const float* b1v = (const float*)d_in[9];
    const float* W2v = (const float*)d_in[10];
    const float* var_table = (const float*)d_in[11];
    const float* Wq  = (const float*)d_in[12];
    const float* Wk  = (const float*)d_in[13];
    const float* Wv  = (const float*)d_in[14];
    const float* Wo  = (const float*)d_in[15];
    const float* W1  = (const float*)d_in[16];
    const float* b1  = (const float*)d_in[17];
    const float* W2  = (const float*)d_in[18];
    const float* b2  = (const float*)d_in[19];
    const float* Wf  = (const float*)d_in[20];
    const float* bfv = (const float*)d_in[21];
    const float* uf  = (const float*)d_in[22];
    const float* Wd1 = (const float*)d_in[23];
    const float* bd1 = (const float*)d_in[24];
    const float* Wd2 = (const float*)d_in[25];
    const float* bd2 = (const float*)d_in[26];
    const float* Wh  = (const float*)d_in[27];
    const float* bhv = (const float*)d_in[28];
    float* out = (float*)d_out;

    // Workspace (floats):
    //  [0,SZ_X)      x
    //  [SZ_X,2SZ_X)  qb (attn o aliases; fusion tmp aliases)
    //  [2SZ_X,4SZ_X) khi/klo/vhi/vlo (bf16)  OR  hb (FFN hidden) — disjoint lives
    //  then wr-area: attb, tsb, demob, per-layer split weights (bf16)
    float* ws     = (float*)d_ws;
    float* x      = ws;
    float* qb     = ws + (size_t)SZ_X;
    float* region = ws + (size_t)2*SZ_X;
    short* khi    = (short*)region;
    short* klo    = khi + (size_t)SZ_X;
    short* vhi    = klo + (size_t)SZ_X;
    short* vlo    = vhi + (size_t)SZ_X;
    float* hb     = region;               // alias
    float* ob     = qb;                   // attn output aliases q
    float* tmpb   = qb;                   // fusion tmp aliases q (post-layers)
    float* attb   = ws + (size_t)4*SZ_X;  // BL_
    float* tsb    = attb + BL_;           // B_*D_
    float* demob  = tsb + B_*D_;          // B_*D_
    short* wt_hi  = (short*)(demob + B_*D_);   // WT_TOT shorts (16B-aligned)
    short* wt_lo  = wt_hi + WT_TOT;
    short* wfhi   = wt_lo + WT_TOT;            // 16384
    short* wflo   = wfhi + 16384;

    embed_kernel<<<BL_, 128, 0, stream>>>(values, times, variables,
                                          W1t, b1t, W2t, W1v, b1v, W2v,
                                          var_table, x);
    demo_kernel<<<1, 256, 0, stream>>>(demographics, Wd1, bd1, Wd2, bd2, demob);
    split_nk_kernel<<<64, 256, 0, stream>>>(Wf, wfhi, wflo, D_, D_);

    for (int i = 0; i < NL_; ++i) {
        split_layer_kernel<<<512, 256, 0, stream>>>(
            Wq + (size_t)i*H_*D_*DK_, Wk + (size_t)i*H_*D_*DK_,
            Wv + (size_t)i*H_*D_*DK_, Wo + (size_t)i*D_*D_,
            W1 + (size_t)i*D_*DFF_,  W2 + (size_t)i*DFF_*D_, wt_hi, wt_lo);

        gemm_mfma<0><<<dim3(BL_/64, 1), 256, 0, stream>>>(x, wt_hi+WT_Q, wt_lo+WT_Q,
            nullptr, nullptr, qb, nullptr, nullptr, D_, D_);
        gemm_mfma<5><<<dim3(BL_/64, 1), 256, 0, stream>>>(x, wt_hi+WT_K, wt_lo+WT_K,
            nullptr, nullptr, nullptr, khi, klo, D_, D_);
        gemm_mfma<5><<<dim3(BL_/64, 1), 256, 0, stream>>>(x, wt_hi+WT_V, wt_lo+WT_V,
            nullptr, nullptr, nullptr, vhi, vlo, D_, D_);
        attn_mfma_kernel<<<dim3(L_/64, H_, B_), 256, 0, stream>>>(qb, khi, klo, vhi, vlo,
                                                                  input_mask, ob);
        gemm_mfma<1><<<dim3(BL_/64, 1), 256, 0, stream>>>(ob, wt_hi+WT_O, wt_lo+WT_O,
            nullptr, x, x, nullptr, nullptr, D_, D_);
        gemm_mfma<2><<<dim3(BL_/64, 2), 256, 0, stream>>>(x, wt_hi+WT_1, wt_lo+WT_1,
            b1 + i*DFF_, nullptr, hb, nullptr, nullptr, DFF_, D_);
        gemm_mfma<3><<<dim3(BL_/64, 1), 256, 0, stream>>>(hb, wt_hi+WT_2, wt_lo+WT_2,
            b2 + i*D_, x, x, nullptr, nullptr, D_, DFF_);
    }

    gemm_mfma<4><<<dim3(BL_/64, 1), 256, 0, stream>>>(x, wfhi, wflo,
        bfv, nullptr, tmpb, nullptr, nullptr, D_, D_);
    attdot_kernel<<<BL_/64, 256, 0, stream>>>(tmpb, uf, input_mask, attb);
    pool_kernel<<<B_, 256, 0, stream>>>(attb, x, tsb);
    head_kernel<<<B_, 256, 0, stream>>>(tsb, demob, Wh, bhv, out);
}

// Round 7
// 1273.915 us; speedup vs baseline: 2.6740x; 1.0836x over previous
//
#include <hip/hip_runtime.h>
#include <hip/hip_bf16.h>
#include <math.h>

#define B_   16
#define L_   2048
#define D_   128
#define H_   4
#define NL_  4
#define DK_  32
#define DFF_ 256
#define INTD_ 11
#define F_OUT 129
#define DM_  16
#define FMINV (-3.402823466e38f)
#define LOG2E 1.4426950408889634f

#define BL_  (B_*L_)      // 32768
#define SZ_X (BL_*D_)     // 4194304 floats

#define PSTR 72           // attn P-scratch stride (>=64 keys, 16B-aligned)

// per-layer pre-split weight offsets (in shorts), layout [col][K]
#define WT_Q 0
#define WT_K 16384
#define WT_V 32768
#define WT_O 49152
#define WT_1 65536        // 256 cols x 128
#define WT_2 98304        // 128 cols x 256
#define WT_TOT 131072

typedef __attribute__((ext_vector_type(8))) short bf16x8;
typedef __attribute__((ext_vector_type(4))) float f32x4;

#if __has_builtin(__builtin_amdgcn_exp2f)
#define EXP2F(x) __builtin_amdgcn_exp2f(x)
#else
#define EXP2F(x) __expf(0.69314718055994531f*(x))
#endif

static __device__ __forceinline__ short f2bf(float x) {
    union { __hip_bfloat16 h; short s; } u;
    u.h = __float2bfloat16(x);
    return u.s;
}
static __device__ __forceinline__ float bf2f(short s) {
    union { __hip_bfloat16 h; short t; } u;
    u.t = s;
    return __bfloat162float(u.h);
}
static __device__ __forceinline__ void split2(float v, short& h, short& l) {
    h = f2bf(v); l = f2bf(v - bf2f(h));
}
// truncation split: h = high 16 bits, residual exact, lo truncated (~2^-16 rel)
static __device__ __forceinline__ void split_trunc(float v, short& h, short& l) {
    unsigned u = __float_as_uint(v);
    h = (short)(u >> 16);
    float r = v - __uint_as_float(u & 0xffff0000u);
    l = (short)(__float_as_uint(r) >> 16);
}

// ---------------------------------------------------------------------------
// Embedding
// ---------------------------------------------------------------------------
__global__ __launch_bounds__(128)
void embed_kernel(const float* __restrict__ values, const float* __restrict__ times,
                  const int* __restrict__ variables,
                  const float* __restrict__ W1t, const float* __restrict__ b1t,
                  const float* __restrict__ W2t,
                  const float* __restrict__ W1v, const float* __restrict__ b1v,
                  const float* __restrict__ W2v,
                  const float* __restrict__ var_table, float* __restrict__ x)
{
    int bl = blockIdx.x;
    int t  = threadIdx.x;
    __shared__ float th[INTD_], vh[INTD_];
    if (t < INTD_)                th[t]    = tanhf(times[bl]  * W1t[t]    + b1t[t]);
    if (t >= 64 && t < 64+INTD_)  vh[t-64] = tanhf(values[bl] * W1v[t-64] + b1v[t-64]);
    __syncthreads();
    int var = variables[bl];
    float acc = var_table[var*D_ + t];
#pragma unroll
    for (int i = 0; i < INTD_; ++i)
        acc += th[i]*W2t[i*D_ + t] + vh[i]*W2v[i*D_ + t];
    x[bl*D_ + t] = acc;
}

// mask -> additive fp32 mask (0 or FMIN), once per launch
__global__ __launch_bounds__(256)
void maskprep_kernel(const int* __restrict__ mask, float* __restrict__ fm)
{
    int i = blockIdx.x*256 + threadIdx.x;
    fm[i] = mask[i] ? 0.0f : FMINV;
}

// ---------------------------------------------------------------------------
// Per-layer weight pre-split: fp32 -> bf16 hi/lo (RNE), transposed to [col][K].
// ---------------------------------------------------------------------------
__global__ __launch_bounds__(256)
void split_layer_kernel(const float* __restrict__ Wq, const float* __restrict__ Wk,
                        const float* __restrict__ Wv, const float* __restrict__ Wo,
                        const float* __restrict__ W1, const float* __restrict__ W2,
                        short* __restrict__ hi, short* __restrict__ lo)
{
    int idx = blockIdx.x*256 + threadIdx.x;   // 0..131071
    float v;
    if (idx < 49152) {                        // Q/K/V
        int which = idx >> 14;
        int r = idx & 16383;
        int col = r >> 7, k = r & 127;
        int h = col >> 5, e = col & 31;
        const float* src = (which == 0) ? Wq : (which == 1) ? Wk : Wv;
        v = src[(h*D_ + k)*DK_ + e];
    } else if (idx < 65536) {                 // Wo
        int r = idx - 49152;
        int col = r >> 7, k = r & 127;
        v = Wo[k*D_ + col];
    } else if (idx < 98304) {                 // W1
        int r = idx - 65536;
        int col = r >> 7, k = r & 127;
        v = W1[k*DFF_ + col];
    } else {                                  // W2
        int r = idx - 98304;
        int col = r >> 8, k = r & 255;
        v = W2[k*D_ + col];
    }
    short h2, l2; split2(v, h2, l2);
    hi[idx] = h2; lo[idx] = l2;
}

__global__ __launch_bounds__(256)
void split_nk_kernel(const float* __restrict__ W, short* __restrict__ hi,
                     short* __restrict__ lo, int N, int K)
{
    int idx = blockIdx.x*256 + threadIdx.x;
    int col = idx / K, k = idx - col*K;
    float v = W[k*N + col];
    short h2, l2; split2(v, h2, l2);
    hi[idx] = h2; lo[idx] = l2;
}

// ---------------------------------------------------------------------------
// MFMA GEMM: C[M][N] = A[M][K] @ W[K][N], W pre-split bf16 hi/lo in [col][K].
// Block: 64 rows x 128 cols, 4 waves. EPI: 0=none 1=+resid 2=+bias,gelu
// 3=+bias,+resid 4=+bias,tanh 5=K: hi/lo head-major [b][h][l][32]
// 6=V: hi/lo transposed head-major [b][h][d(32)][l]
// ---------------------------------------------------------------------------
template<int EPI>
__global__ __launch_bounds__(256)
void gemm_mfma(const float* __restrict__ A, const short* __restrict__ Whi,
               const short* __restrict__ Wlo, const float* __restrict__ bias,
               const float* __restrict__ resid, float* __restrict__ out,
               short* __restrict__ ohi, short* __restrict__ olo,
               int N, int K)
{
    __shared__ short Ahi[64*136];
    __shared__ short Alo[64*136];
    const int t = threadIdx.x;
    const int w = t >> 6, lane = t & 63;
    const int m = lane & 15, qd = lane >> 4;
    const int row0 = blockIdx.x * 64;
    const int col0 = blockIdx.y * 128;

    f32x4 acc[4][2];
#pragma unroll
    for (int r4 = 0; r4 < 4; ++r4)
#pragma unroll
        for (int j = 0; j < 2; ++j) acc[r4][j] = (f32x4){0,0,0,0};

    for (int kb = 0; kb < K; kb += 128) {
        if (kb) __syncthreads();
#pragma unroll
        for (int i = 0; i < 8; ++i) {
            int r = (t >> 5) + 8*i;
            int c = (t & 31) * 4;
            float4 av = *(const float4*)(A + (size_t)(row0 + r)*K + kb + c);
            short4 hi4, lo4;
            split2(av.x, hi4.x, lo4.x);
            split2(av.y, hi4.y, lo4.y);
            split2(av.z, hi4.z, lo4.z);
            split2(av.w, hi4.w, lo4.w);
            *(short4*)&Ahi[r*136 + c] = hi4;
            *(short4*)&Alo[r*136 + c] = lo4;
        }
        __syncthreads();

#pragma unroll
        for (int ks = 0; ks < 4; ++ks) {
            bf16x8 wh[2], wl[2];
#pragma unroll
            for (int j = 0; j < 2; ++j) {
                size_t wi = (size_t)(col0 + 32*w + 16*j + m)*K + kb + 32*ks + 8*qd;
                wh[j] = *(const bf16x8*)(Whi + wi);
                wl[j] = *(const bf16x8*)(Wlo + wi);
            }
#pragma unroll
            for (int r4 = 0; r4 < 4; ++r4) {
                bf16x8 ah = *(const bf16x8*)&Ahi[(16*r4 + m)*136 + 32*ks + 8*qd];
                bf16x8 al = *(const bf16x8*)&Alo[(16*r4 + m)*136 + 32*ks + 8*qd];
#pragma unroll
                for (int j = 0; j < 2; ++j) {
                    acc[r4][j] = __builtin_amdgcn_mfma_f32_16x16x32_bf16(wh[j], ah, acc[r4][j], 0, 0, 0);
                    acc[r4][j] = __builtin_amdgcn_mfma_f32_16x16x32_bf16(wh[j], al, acc[r4][j], 0, 0, 0);
                    acc[r4][j] = __builtin_amdgcn_mfma_f32_16x16x32_bf16(wl[j], ah, acc[r4][j], 0, 0, 0);
                }
            }
        }
    }

#pragma unroll
    for (int r4 = 0; r4 < 4; ++r4) {
        int row = row0 + 16*r4 + m;
#pragma unroll
        for (int j = 0; j < 2; ++j) {
            int col = col0 + 32*w + 16*j + 4*qd;
            f32x4 v = acc[r4][j];
            if (EPI == 2 || EPI == 3 || EPI == 4) {
                float4 bv = *(const float4*)(bias + col);
                v[0] += bv.x; v[1] += bv.y; v[2] += bv.z; v[3] += bv.w;
            }
            if (EPI == 2) {
#pragma unroll
                for (int e = 0; e < 4; ++e)
                    v[e] = 0.5f * v[e] * (1.0f + erff(v[e] * 0.70710678118654752f));
            }
            if (EPI == 4) {
#pragma unroll
                for (int e = 0; e < 4; ++e) v[e] = tanhf(v[e]);
            }
            if (EPI == 1 || EPI == 3) {
                float4 rv = *(const float4*)(resid + (size_t)row*N + col);
                v[0] += rv.x; v[1] += rv.y; v[2] += rv.z; v[3] += rv.w;
            }
            if (EPI == 5) {
                int bb = row >> 11, l = row & 2047;
                size_t idx = ((size_t)((bb*4 + w)*2048 + l))*32 + (col & 31);
                short4 hi4, lo4;
                split2(v[0], hi4.x, lo4.x);
                split2(v[1], hi4.y, lo4.y);
                split2(v[2], hi4.z, lo4.z);
                split2(v[3], hi4.w, lo4.w);
                *(short4*)(ohi + idx) = hi4;
                *(short4*)(olo + idx) = lo4;
            } else if (EPI == 6) {
                int bb = row >> 11, l = row & 2047;
                size_t basep = (size_t)(bb*4 + w)*32;
#pragma unroll
                for (int e = 0; e < 4; ++e) {
                    int d = 16*j + 4*qd + e;
                    short hh, ll; split2(v[e], hh, ll);
                    ohi[(basep + d)*2048 + l] = hh;
                    olo[(basep + d)*2048 + l] = ll;
                }
            } else {
                float4 sv = {v[0], v[1], v[2], v[3]};
                *(float4*)(out + (size_t)row*N + col) = sv;
            }
        }
    }
}

// ---------------------------------------------------------------------------
// MFMA flash attention. K head-major [b,h,l,32]; V TRANSPOSED [b,h,d,l].
// Q scaled by log2e at load -> exp2 softmax (identical FMIN semantics).
// Mask row selected by per-lane pointer (kmf vs constant-FMIN row).
// S = Khi·Qhi + Khi·Qlo + Klo·Qhi ; O += Phi·Vhi + Phi·Vlo + Plo·Vhi.
// ---------------------------------------------------------------------------
__global__ __launch_bounds__(256)
void attn_mfma_kernel(const float* __restrict__ q,
                      const short* __restrict__ khi, const short* __restrict__ klo,
                      const short* __restrict__ vhiT, const short* __restrict__ vloT,
                      const int* __restrict__ mask, const float* __restrict__ fm,
                      float* __restrict__ o)
{
    __shared__ short KhiS[64*32];      // [key][dim] unpadded (conflict-free both ways)
    __shared__ short KloS[64*32];
    __shared__ short Vthi[32*72];      // [dim][key] stride 72
    __shared__ short Vtlo[32*72];
    __shared__ short Pshi[4][16*PSTR];
    __shared__ short Pslo[4][16*PSTR];
    __shared__ float kmf[64];
    __shared__ float kfin[64];
    __shared__ float al_ls[4][16];
    __shared__ float l_ls [4][16];

    const int t    = threadIdx.x;
    const int w    = t >> 6;
    const int lane = t & 63;
    const int m    = lane & 15;
    const int qd   = lane >> 4;
    const int qt = blockIdx.x, h = blockIdx.y, b = blockIdx.z;

    const size_t hd = ((size_t)(b*4 + h))*2048*32;   // K base (head-major)

    // ---- Q fragment (B-operand), scaled by log2e, register-resident hi/lo ----
    const int qrow = qt*64 + 16*w + m;
    const float* qp = q + ((size_t)(b*L_ + qrow))*D_ + h*DK_ + 8*qd;
    float qf[8];
    *(float4*)&qf[0] = *(const float4*)qp;
    *(float4*)&qf[4] = *(const float4*)(qp + 4);
    bf16x8 qhi, qlo;
#pragma unroll
    for (int j = 0; j < 8; ++j) {
        float qs = qf[j] * LOG2E;
        short hs = f2bf(qs);
        qhi[j] = hs;
        qlo[j] = f2bf(qs - bf2f(hs));
    }
    const int qmv = mask[b*L_ + qrow];
    if (t < 64) kfin[t] = FMINV;
    const float* mrow = qmv ? kmf : kfin;   // fixed for whole loop

    const int vd = t >> 3;                  // V stage: dim row 0..31
    const int vk = (t & 7) * 8;             // keys 0,8..56

    float m_old = -INFINITY, l_run = 0.0f;
    f32x4 o_acc[2] = {{0,0,0,0},{0,0,0,0}};

    for (int kt = 0; kt < L_/64; ++kt) {
        __syncthreads();
        // ---- stage K: pure 16B copies, sequential LDS (conflict-free) ----
        {
            const size_t gk = hd + (size_t)kt*64*32 + t*8;
            bf16x8 a = *(const bf16x8*)(khi + gk);
            bf16x8 c = *(const bf16x8*)(klo + gk);
            *(bf16x8*)&KhiS[t*8] = a;
            *(bf16x8*)&KloS[t*8] = c;
        }
        // ---- stage V^T: pure 16B copies (conflict-free pattern) ----
        {
            const size_t gvT = ((size_t)(b*4 + h)*32 + vd)*2048 + (size_t)kt*64 + vk;
            bf16x8 a = *(const bf16x8*)(vhiT + gvT);
            bf16x8 c = *(const bf16x8*)(vloT + gvT);
            *(bf16x8*)&Vthi[vd*72 + vk] = a;
            *(bf16x8*)&Vtlo[vd*72 + vk] = c;
        }
        if (t < 16) ((float4*)kmf)[t] = ((const float4*)(fm + (size_t)b*L_ + (size_t)kt*64))[t];
        __syncthreads();

        // ---- S^T = K·Q^T (split-precision, fp32 acc, log2 domain) ----
        f32x4 sf[4];
#pragma unroll
        for (int k4 = 0; k4 < 4; ++k4) {
            bf16x8 ka = *(const bf16x8*)&KhiS[(16*k4 + m)*32 + 8*qd];
            bf16x8 kl = *(const bf16x8*)&KloS[(16*k4 + m)*32 + 8*qd];
            f32x4 c = {0,0,0,0};
            c = __builtin_amdgcn_mfma_f32_16x16x32_bf16(ka, qhi, c, 0, 0, 0);
            c = __builtin_amdgcn_mfma_f32_16x16x32_bf16(ka, qlo, c, 0, 0, 0);
            c = __builtin_amdgcn_mfma_f32_16x16x32_bf16(kl, qhi, c, 0, 0, 0);
            sf[k4] = c;
        }

        // ---- finite-FMIN mask add (pointer-selected row) ----
        float sv[16];
#pragma unroll
        for (int k4 = 0; k4 < 4; ++k4) {
            float4 kmv = *(const float4*)&mrow[16*k4 + 4*qd];
            sv[4*k4+0] = sf[k4][0] + kmv.x;
            sv[4*k4+1] = sf[k4][1] + kmv.y;
            sv[4*k4+2] = sf[k4][2] + kmv.z;
            sv[4*k4+3] = sf[k4][3] + kmv.w;
        }

        // ---- online softmax (exp2 domain) ----
        float tmax = sv[0];
#pragma unroll
        for (int j = 1; j < 16; ++j) tmax = fmaxf(tmax, sv[j]);
        tmax = fmaxf(tmax, __shfl_xor(tmax, 16));
        tmax = fmaxf(tmax, __shfl_xor(tmax, 32));
        float mnew  = fmaxf(m_old, tmax);
        float alpha = EXP2F(m_old - mnew);
        float psum = 0.0f;
        short pbh[16], pbl[16];
#pragma unroll
        for (int j = 0; j < 16; ++j) {
            float p = EXP2F(sv[j] - mnew);   // FMIN-FMIN=0 -> 1 (uniform row)
            psum += p;
            split_trunc(p, pbh[j], pbl[j]);
        }
        psum += __shfl_xor(psum, 16);
        psum += __shfl_xor(psum, 32);
        l_run = l_run * alpha + psum;
        m_old = mnew;

        // ---- P store (C->A transpose), hi/lo ----
#pragma unroll
        for (int k4 = 0; k4 < 4; ++k4) {
            short4 s4h, s4l;
            s4h.x = pbh[4*k4+0]; s4h.y = pbh[4*k4+1]; s4h.z = pbh[4*k4+2]; s4h.w = pbh[4*k4+3];
            s4l.x = pbl[4*k4+0]; s4l.y = pbl[4*k4+1]; s4l.z = pbl[4*k4+2]; s4l.w = pbl[4*k4+3];
            *(short4*)&Pshi[w][m*PSTR + 16*k4 + 4*qd] = s4h;
            *(short4*)&Pslo[w][m*PSTR + 16*k4 + 4*qd] = s4l;
        }
        if (lane < 16) al_ls[w][lane] = alpha;

        // ---- O rescale + PV (split-precision) ----
        {
            float4 alr = *(const float4*)&al_ls[w][4*qd];
            o_acc[0][0]*=alr.x; o_acc[0][1]*=alr.y; o_acc[0][2]*=alr.z; o_acc[0][3]*=alr.w;
            o_acc[1][0]*=alr.x; o_acc[1][1]*=alr.y; o_acc[1][2]*=alr.z; o_acc[1][3]*=alr.w;
        }
#pragma unroll
        for (int s = 0; s < 2; ++s) {
            bf16x8 pah = *(const bf16x8*)&Pshi[w][m*PSTR + 32*s + 8*qd];
            bf16x8 pal = *(const bf16x8*)&Pslo[w][m*PSTR + 32*s + 8*qd];
#pragma unroll
            for (int tp = 0; tp < 2; ++tp) {
                bf16x8 vh = *(const bf16x8*)&Vthi[(16*tp + m)*72 + 32*s + 8*qd];
                bf16x8 vl = *(const bf16x8*)&Vtlo[(16*tp + m)*72 + 32*s + 8*qd];
                o_acc[tp] = __builtin_amdgcn_mfma_f32_16x16x32_bf16(pah, vh, o_acc[tp], 0, 0, 0);
                o_acc[tp] = __builtin_amdgcn_mfma_f32_16x16x32_bf16(pah, vl, o_acc[tp], 0, 0, 0);
                o_acc[tp] = __builtin_amdgcn_mfma_f32_16x16x32_bf16(pal, vh, o_acc[tp], 0, 0, 0);
            }
        }
    }

    if (lane < 16) l_ls[w][lane] = l_run;
    float4 lr = *(const float4*)&l_ls[w][4*qd];
    float li[4] = {1.0f/lr.x, 1.0f/lr.y, 1.0f/lr.z, 1.0f/lr.w};
#pragma unroll
    for (int tp = 0; tp < 2; ++tp)
#pragma unroll
        for (int r = 0; r < 4; ++r)
            o[((size_t)(b*L_ + qt*64 + 16*w + 4*qd + r))*D_ + h*DK_ + 16*tp + m] =
                o_acc[tp][r] * li[r];
}

// ---------------------------------------------------------------------------
// att[b,l] = tanh(x@Wf+bf) . uf  (+ FMIN mask add)
// ---------------------------------------------------------------------------
__global__ __launch_bounds__(256)
void attdot_kernel(const float* __restrict__ tmp, const float* __restrict__ uf,
                   const int* __restrict__ mask, float* __restrict__ att)
{
    int t   = threadIdx.x;
    int row = blockIdx.x*64 + (t >> 2);
    int sub = t & 3;
    const float* rp = tmp + row*D_ + sub*32;
    const float* up = uf  + sub*32;
    float acc = 0.0f;
#pragma unroll
    for (int j = 0; j < 8; ++j) {
        float4 xv = *(const float4*)(rp + 4*j);
        float4 uv = *(const float4*)(up + 4*j);
        acc += xv.x*uv.x + xv.y*uv.y + xv.z*uv.z + xv.w*uv.w;
    }
    acc += __shfl_xor(acc, 1);
    acc += __shfl_xor(acc, 2);
    if (sub == 0) att[row] = acc + (mask[row] ? 0.0f : FMINV);
}

// ---------------------------------------------------------------------------
// Per-batch softmax pooling
// ---------------------------------------------------------------------------
__global__ __launch_bounds__(256)
void pool_kernel(const float* __restrict__ att, const float* __restrict__ x,
                 float* __restrict__ ts)
{
    int b = blockIdx.x, t = threadIdx.x;
    __shared__ float red[4];
    __shared__ float p_s[L_];
    __shared__ float part[2][128];

    float m = -INFINITY;
    for (int l = t; l < L_; l += 256) m = fmaxf(m, att[b*L_ + l]);
#pragma unroll
    for (int s = 1; s < 64; s <<= 1) m = fmaxf(m, __shfl_xor(m, s));
    if ((t & 63) == 0) red[t >> 6] = m;
    __syncthreads();
    m = fmaxf(fmaxf(red[0], red[1]), fmaxf(red[2], red[3]));
    __syncthreads();

    float s = 0.0f;
    for (int l = t; l < L_; l += 256) {
        float p = __expf(att[b*L_ + l] - m);
        p_s[l] = p;
        s += p;
    }
#pragma unroll
    for (int st = 1; st < 64; st <<= 1) s += __shfl_xor(s, st);
    if ((t & 63) == 0) red[t >> 6] = s;
    __syncthreads();
    s = red[0] + red[1] + red[2] + red[3];
    float inv = 1.0f / s;

    int td = t & 127, half = t >> 7;
    float acc = 0.0f;
    const float* xb = x + ((size_t)(b*L_ + half*1024))*D_ + td;
    for (int i = 0; i < 1024; ++i) acc += p_s[half*1024 + i] * xb[(size_t)i*D_];
    part[half][td] = acc;
    __syncthreads();
    if (t < 128) ts[b*D_ + t] = (part[0][t] + part[1][t]) * inv;
}

// ---------------------------------------------------------------------------
// Demographics MLP
// ---------------------------------------------------------------------------
__global__ __launch_bounds__(256)
void demo_kernel(const float* __restrict__ demog, const float* __restrict__ Wd1,
                 const float* __restrict__ bd1, const float* __restrict__ Wd2,
                 const float* __restrict__ bd2, float* __restrict__ demo_out)
{
    int t = threadIdx.x;
    __shared__ float dsm[B_][DM_];
    __shared__ float hs[B_][2*D_];
    if (t < B_*DM_) dsm[t >> 4][t & 15] = demog[t];
    __syncthreads();
    {
        int col = t;
#pragma unroll
        for (int r = 0; r < B_; ++r) {
            float acc = bd1[col];
#pragma unroll
            for (int kk = 0; kk < DM_; ++kk) acc += dsm[r][kk]*Wd1[kk*(2*D_)+col];
            hs[r][col] = tanhf(acc);
        }
    }
    __syncthreads();
    {
        int c  = t & (D_-1);
        int r0 = t >> 7;
        for (int r = r0; r < B_; r += 2) {
            float acc = bd2[c];
            for (int kk = 0; kk < 2*D_; ++kk) acc += hs[r][kk]*Wd2[kk*D_+c];
            demo_out[r*D_+c] = acc;
        }
    }
}

// ---------------------------------------------------------------------------
// Head
// ---------------------------------------------------------------------------
__global__ __launch_bounds__(256)
void head_kernel(const float* __restrict__ ts, const float* __restrict__ demo,
                 const float* __restrict__ Wh, const float* __restrict__ bh,
                 float* __restrict__ out)
{
    int b = blockIdx.x, t = threadIdx.x;
    if (t >= F_OUT) return;
    float acc = bh[t];
    for (int k2 = 0; k2 < D_; ++k2) acc += ts[b*D_ + k2]   * Wh[k2*F_OUT + t];
    for (int k2 = 0; k2 < D_; ++k2) acc += demo[b*D_ + k2] * Wh[(D_+k2)*F_OUT + t];
    out[b*F_OUT + t] = acc;
}

// ---------------------------------------------------------------------------
extern "C" void kernel_launch(void* const* d_in, const int* in_sizes, int n_in,
                              void* d_out, int out_size, void* d_ws, size_t ws_size,
                              hipStream_t stream)
{
    (void)in_sizes; (void)n_in; (void)out_size; (void)ws_size;
    const float* values       = (const float*)d_in[0];
    const float* times        = (const float*)d_in[1];
    const int*   variables    = (const int*)  d_in[2];
    const int*   input_mask   = (const int*)  d_in[3];
    const float* demographics = (const float*)d_in[4];
    const float* W1t = (const float*)d_in[5];
    const float* b1t = (const float*)d_in[6];
    const float* W2t = (const float*)d_in[7];
    const float* W1v = (const float*)d_in[8];
    const float* b1v = (const float*)d_in[9];
    const float* W2v = (const float*)d_in[10];
    const float* var_table = (const float*)d_in[11];
    const float* Wq  = (const float*)d_in[12];
    const float* Wk  = (const float*)d_in[13];
    const float* Wv  = (const float*)d_in[14];
    const float* Wo  = (const float*)d_in[15];
    const float* W1  = (const float*)d_in[16];
    const float* b1  = (const float*)d_in[17];
    const float* W2  = (const float*)d_in[18];
    const float* b2  = (const float*)d_in[19];
    const float* Wf  = (const float*)d_in[20];
    const float* bfv = (const float*)d_in[21];
    const float* uf  = (const float*)d_in[22];
    const float* Wd1 = (const float*)d_in[23];
    const float* bd1 = (const float*)d_in[24];
    const float* Wd2 = (const float*)d_in[25];
    const float* bd2 = (const float*)d_in[26];
    const float* Wh  = (const float*)d_in[27];
    const float* bhv = (const float*)d_in[28];
    float* out = (float*)d_out;

    float* ws     = (float*)d_ws;
    float* x      = ws;
    float* qb     = ws + (size_t)SZ_X;
    float* region = ws + (size_t)2*SZ_X;
    short* khi    = (short*)region;
    short* klo    = khi + (size_t)SZ_X;
    short* vhiT   = klo + (size_t)SZ_X;
    short* vloT   = vhiT + (size_t)SZ_X;
    float* hb     = region;               // alias (FFN hidden)
    float* ob     = qb;                   // attn output aliases q
    float* tmpb   = qb;                   // fusion tmp aliases q (post-layers)
    float* attb   = ws + (size_t)4*SZ_X;  // BL_
    float* tsb    = attb + BL_;
    float* demob  = tsb + B_*D_;
    short* wt_hi  = (short*)(demob + B_*D_);
    short* wt_lo  = wt_hi + WT_TOT;
    short* wfhi   = wt_lo + WT_TOT;       // 16384
    short* wflo   = wfhi + 16384;
    float* fm     = (float*)(wflo + 16384); // BL_ floats (additive mask)

    embed_kernel<<<BL_, 128, 0, stream>>>(values, times, variables,
                                          W1t, b1t, W2t, W1v, b1v, W2v,
                                          var_table, x);
    maskprep_kernel<<<BL_/256, 256, 0, stream>>>(input_mask, fm);
    demo_kernel<<<1, 256, 0, stream>>>(demographics, Wd1, bd1, Wd2, bd2, demob);
    split_nk_kernel<<<64, 256, 0, stream>>>(Wf, wfhi, wflo, D_, D_);

    for (int i = 0; i < NL_; ++i) {
        split_layer_kernel<<<512, 256, 0, stream>>>(
            Wq + (size_t)i*H_*D_*DK_, Wk + (size_t)i*H_*D_*DK_,
            Wv + (size_t)i*H_*D_*DK_, Wo + (size_t)i*D_*D_,
            W1 + (size_t)i*D_*DFF_,  W2 + (size_t)i*DFF_*D_, wt_hi, wt_lo);

        gemm_mfma<0><<<dim3(BL_/64, 1), 256, 0, stream>>>(x, wt_hi+WT_Q, wt_lo+WT_Q,
            nullptr, nullptr, qb, nullptr, nullptr, D_, D_);
        gemm_mfma<5><<<dim3(BL_/64, 1), 256, 0, stream>>>(x, wt_hi+WT_K, wt_lo+WT_K,
            nullptr, nullptr, nullptr, khi, klo, D_, D_);
        gemm_mfma<6><<<dim3(BL_/64, 1), 256, 0, stream>>>(x, wt_hi+WT_V, wt_lo+WT_V,
            nullptr, nullptr, nullptr, vhiT, vloT, D_, D_);
        attn_mfma_kernel<<<dim3(L_/64, H_, B_), 256, 0, stream>>>(qb, khi, klo, vhiT, vloT,
                                                                  input_mask, fm, ob);
        gemm_mfma<1><<<dim3(BL_/64, 1), 256, 0, stream>>>(ob, wt_hi+WT_O, wt_lo+WT_O,
            nullptr, x, x, nullptr, nullptr, D_, D_);
        gemm_mfma<2><<<dim3(BL_/64, 2), 256, 0, stream>>>(x, wt_hi+WT_1, wt_lo+WT_1,
            b1 + i*DFF_, nullptr, hb, nullptr, nullptr, DFF_, D_);
        gemm_mfma<3><<<dim3(BL_/64, 1), 256, 0, stream>>>(hb, wt_hi+WT_2, wt_lo+WT_2,
            b2 + i*D_, x, x, nullptr, nullptr, D_, DFF_);
    }

    gemm_mfma<4><<<dim3(BL_/64, 1), 256, 0, stream>>>(x, wfhi, wflo,
        bfv, nullptr, tmpb, nullptr, nullptr, D_, D_);
    attdot_kernel<<<BL_/64, 256, 0, stream>>>(tmpb, uf, input_mask, attb);
    pool_kernel<<<B_, 256, 0, stream>>>(attb, x, tsb);
    head_kernel<<<B_, 256, 0, stream>>>(tsb, demob, Wh, bhv, out);
}

// Round 8
// 1228.013 us; speedup vs baseline: 2.7739x; 1.0374x over previous
//
#include <hip/hip_runtime.h>
#include <hip/hip_bf16.h>
#include <math.h>

#define B_   16
#define L_   2048
#define D_   128
#define H_   4
#define NL_  4
#define DK_  32
#define DFF_ 256
#define INTD_ 11
#define F_OUT 129
#define DM_  16
#define FMINV (-3.402823466e38f)
#define LOG2E 1.4426950408889634f

#define BL_  (B_*L_)      // 32768
#define SZ_X (BL_*D_)     // 4194304 floats

#define PSTR 72           // attn P-scratch stride (>=64 keys, 16B-aligned)
#define KSTR 40           // attn K-tile stride: 20 words -> 2-way banks (free)

// per-layer pre-split weight offsets (in shorts), layout [col][K]
#define WT_Q 0
#define WT_K 16384
#define WT_V 32768
#define WT_O 49152
#define WT_1 65536        // 256 cols x 128
#define WT_2 98304        // 128 cols x 256
#define WT_TOT 131072

typedef __attribute__((ext_vector_type(8))) short bf16x8;
typedef __attribute__((ext_vector_type(4))) float f32x4;

#if __has_builtin(__builtin_amdgcn_exp2f)
#define EXP2F(x) __builtin_amdgcn_exp2f(x)
#else
#define EXP2F(x) __expf(0.69314718055994531f*(x))
#endif

static __device__ __forceinline__ short f2bf(float x) {
    union { __hip_bfloat16 h; short s; } u;
    u.h = __float2bfloat16(x);
    return u.s;
}
static __device__ __forceinline__ float bf2f(short s) {
    union { __hip_bfloat16 h; short t; } u;
    u.t = s;
    return __bfloat162float(u.h);
}
static __device__ __forceinline__ void split2(float v, short& h, short& l) {
    h = f2bf(v); l = f2bf(v - bf2f(h));
}
// truncation split: h = high 16 bits, residual exact, lo truncated (~2^-16 rel)
static __device__ __forceinline__ void split_trunc(float v, short& h, short& l) {
    unsigned u = __float_as_uint(v);
    h = (short)(u >> 16);
    float r = v - __uint_as_float(u & 0xffff0000u);
    l = (short)(__float_as_uint(r) >> 16);
}

// ---------------------------------------------------------------------------
// Embedding
// ---------------------------------------------------------------------------
__global__ __launch_bounds__(128)
void embed_kernel(const float* __restrict__ values, const float* __restrict__ times,
                  const int* __restrict__ variables,
                  const float* __restrict__ W1t, const float* __restrict__ b1t,
                  const float* __restrict__ W2t,
                  const float* __restrict__ W1v, const float* __restrict__ b1v,
                  const float* __restrict__ W2v,
                  const float* __restrict__ var_table, float* __restrict__ x)
{
    int bl = blockIdx.x;
    int t  = threadIdx.x;
    __shared__ float th[INTD_], vh[INTD_];
    if (t < INTD_)                th[t]    = tanhf(times[bl]  * W1t[t]    + b1t[t]);
    if (t >= 64 && t < 64+INTD_)  vh[t-64] = tanhf(values[bl] * W1v[t-64] + b1v[t-64]);
    __syncthreads();
    int var = variables[bl];
    float acc = var_table[var*D_ + t];
#pragma unroll
    for (int i = 0; i < INTD_; ++i)
        acc += th[i]*W2t[i*D_ + t] + vh[i]*W2v[i*D_ + t];
    x[bl*D_ + t] = acc;
}

// mask -> additive fp32 mask (0 or FMIN), once per launch
__global__ __launch_bounds__(256)
void maskprep_kernel(const int* __restrict__ mask, float* __restrict__ fm)
{
    int i = blockIdx.x*256 + threadIdx.x;
    fm[i] = mask[i] ? 0.0f : FMINV;
}

// ---------------------------------------------------------------------------
// Per-layer weight pre-split: fp32 -> bf16 hi/lo (RNE), transposed to [col][K].
// ---------------------------------------------------------------------------
__global__ __launch_bounds__(256)
void split_layer_kernel(const float* __restrict__ Wq, const float* __restrict__ Wk,
                        const float* __restrict__ Wv, const float* __restrict__ Wo,
                        const float* __restrict__ W1, const float* __restrict__ W2,
                        short* __restrict__ hi, short* __restrict__ lo)
{
    int idx = blockIdx.x*256 + threadIdx.x;   // 0..131071
    float v;
    if (idx < 49152) {                        // Q/K/V
        int which = idx >> 14;
        int r = idx & 16383;
        int col = r >> 7, k = r & 127;
        int h = col >> 5, e = col & 31;
        const float* src = (which == 0) ? Wq : (which == 1) ? Wk : Wv;
        v = src[(h*D_ + k)*DK_ + e];
    } else if (idx < 65536) {                 // Wo
        int r = idx - 49152;
        int col = r >> 7, k = r & 127;
        v = Wo[k*D_ + col];
    } else if (idx < 98304) {                 // W1
        int r = idx - 65536;
        int col = r >> 7, k = r & 127;
        v = W1[k*DFF_ + col];
    } else {                                  // W2
        int r = idx - 98304;
        int col = r >> 8, k = r & 255;
        v = W2[k*D_ + col];
    }
    short h2, l2; split2(v, h2, l2);
    hi[idx] = h2; lo[idx] = l2;
}

__global__ __launch_bounds__(256)
void split_nk_kernel(const float* __restrict__ W, short* __restrict__ hi,
                     short* __restrict__ lo, int N, int K)
{
    int idx = blockIdx.x*256 + threadIdx.x;
    int col = idx / K, k = idx - col*K;
    float v = W[k*N + col];
    short h2, l2; split2(v, h2, l2);
    hi[idx] = h2; lo[idx] = l2;
}

// ---------------------------------------------------------------------------
// MFMA GEMM: C[M][N] = A[M][K] @ W[K][N], W pre-split bf16 hi/lo in [col][K].
// Block: 64 rows x 128 cols, 4 waves. EPI: 0=none 1=+resid 2=+bias,gelu
// 3=+bias,+resid 4=+bias,tanh 5=K-split 6=V^T-split
// 7=fusion att: att[row] = tanh(acc+bias).uf + fm[row]  (uf in resid, fm in ohi)
// ---------------------------------------------------------------------------
template<int EPI>
__global__ __launch_bounds__(256)
void gemm_mfma(const float* __restrict__ A, const short* __restrict__ Whi,
               const short* __restrict__ Wlo, const float* __restrict__ bias,
               const float* __restrict__ resid, float* __restrict__ out,
               short* __restrict__ ohi, short* __restrict__ olo,
               int N, int K)
{
    __shared__ short Ahi[64*136];
    __shared__ short Alo[64*136];
    __shared__ float part[64][16];     // EPI7 only
    const int t = threadIdx.x;
    const int w = t >> 6, lane = t & 63;
    const int m = lane & 15, qd = lane >> 4;
    const int row0 = blockIdx.x * 64;
    const int col0 = blockIdx.y * 128;

    f32x4 acc[4][2];
#pragma unroll
    for (int r4 = 0; r4 < 4; ++r4)
#pragma unroll
        for (int j = 0; j < 2; ++j) acc[r4][j] = (f32x4){0,0,0,0};

    for (int kb = 0; kb < K; kb += 128) {
        if (kb) __syncthreads();
#pragma unroll
        for (int i = 0; i < 8; ++i) {
            int r = (t >> 5) + 8*i;
            int c = (t & 31) * 4;
            float4 av = *(const float4*)(A + (size_t)(row0 + r)*K + kb + c);
            short4 hi4, lo4;
            split2(av.x, hi4.x, lo4.x);
            split2(av.y, hi4.y, lo4.y);
            split2(av.z, hi4.z, lo4.z);
            split2(av.w, hi4.w, lo4.w);
            *(short4*)&Ahi[r*136 + c] = hi4;
            *(short4*)&Alo[r*136 + c] = lo4;
        }
        __syncthreads();

#pragma unroll
        for (int ks = 0; ks < 4; ++ks) {
            bf16x8 wh[2], wl[2];
#pragma unroll
            for (int j = 0; j < 2; ++j) {
                size_t wi = (size_t)(col0 + 32*w + 16*j + m)*K + kb + 32*ks + 8*qd;
                wh[j] = *(const bf16x8*)(Whi + wi);
                wl[j] = *(const bf16x8*)(Wlo + wi);
            }
#pragma unroll
            for (int r4 = 0; r4 < 4; ++r4) {
                bf16x8 ah = *(const bf16x8*)&Ahi[(16*r4 + m)*136 + 32*ks + 8*qd];
                bf16x8 al = *(const bf16x8*)&Alo[(16*r4 + m)*136 + 32*ks + 8*qd];
#pragma unroll
                for (int j = 0; j < 2; ++j) {
                    acc[r4][j] = __builtin_amdgcn_mfma_f32_16x16x32_bf16(wh[j], ah, acc[r4][j], 0, 0, 0);
                    acc[r4][j] = __builtin_amdgcn_mfma_f32_16x16x32_bf16(wh[j], al, acc[r4][j], 0, 0, 0);
                    acc[r4][j] = __builtin_amdgcn_mfma_f32_16x16x32_bf16(wl[j], ah, acc[r4][j], 0, 0, 0);
                }
            }
        }
    }

#pragma unroll
    for (int r4 = 0; r4 < 4; ++r4) {
        int row = row0 + 16*r4 + m;
        float dotp = 0.0f;                 // EPI7 partial
#pragma unroll
        for (int j = 0; j < 2; ++j) {
            int col = col0 + 32*w + 16*j + 4*qd;
            f32x4 v = acc[r4][j];
            if (EPI == 2 || EPI == 3 || EPI == 4 || EPI == 7) {
                float4 bv = *(const float4*)(bias + col);
                v[0] += bv.x; v[1] += bv.y; v[2] += bv.z; v[3] += bv.w;
            }
            if (EPI == 2) {
#pragma unroll
                for (int e = 0; e < 4; ++e)
                    v[e] = 0.5f * v[e] * (1.0f + erff(v[e] * 0.70710678118654752f));
            }
            if (EPI == 4 || EPI == 7) {
#pragma unroll
                for (int e = 0; e < 4; ++e) v[e] = tanhf(v[e]);
            }
            if (EPI == 1 || EPI == 3) {
                float4 rv = *(const float4*)(resid + (size_t)row*N + col);
                v[0] += rv.x; v[1] += rv.y; v[2] += rv.z; v[3] += rv.w;
            }
            if (EPI == 5) {
                int bb = row >> 11, l = row & 2047;
                size_t idx = ((size_t)((bb*4 + w)*2048 + l))*32 + (col & 31);
                short4 hi4, lo4;
                split2(v[0], hi4.x, lo4.x);
                split2(v[1], hi4.y, lo4.y);
                split2(v[2], hi4.z, lo4.z);
                split2(v[3], hi4.w, lo4.w);
                *(short4*)(ohi + idx) = hi4;
                *(short4*)(olo + idx) = lo4;
            } else if (EPI == 6) {
                int bb = row >> 11, l = row & 2047;
                size_t basep = (size_t)(bb*4 + w)*32;
#pragma unroll
                for (int e = 0; e < 4; ++e) {
                    int d = 16*j + 4*qd + e;
                    short hh, ll; split2(v[e], hh, ll);
                    ohi[(basep + d)*2048 + l] = hh;
                    olo[(basep + d)*2048 + l] = ll;
                }
            } else if (EPI == 7) {
                float4 uv = *(const float4*)(resid + col);   // uf
                dotp += v[0]*uv.x + v[1]*uv.y + v[2]*uv.z + v[3]*uv.w;
            } else {
                float4 sv = {v[0], v[1], v[2], v[3]};
                *(float4*)(out + (size_t)row*N + col) = sv;
            }
        }
        if (EPI == 7) part[16*r4 + m][4*w + qd] = dotp;
    }
    if (EPI == 7) {
        __syncthreads();
        if (t < 64) {
            const float* fm = (const float*)ohi;
            float s = 0.0f;
#pragma unroll
            for (int i = 0; i < 16; ++i) s += part[t][i];
            out[row0 + t] = s + fm[row0 + t];
        }
    }
}

// ---------------------------------------------------------------------------
// Fused QKV GEMM: stage x hi/lo once, run 3 weight streams.
// Q -> fp32 [row][128]; K -> hi/lo head-major; V -> hi/lo transposed head-major.
// ---------------------------------------------------------------------------
__global__ __launch_bounds__(256)
void gemm_qkv_fused(const float* __restrict__ A, const short* __restrict__ Whi,
                    const short* __restrict__ Wlo, float* __restrict__ qout,
                    short* __restrict__ khi, short* __restrict__ klo,
                    short* __restrict__ vhiT, short* __restrict__ vloT)
{
    __shared__ short Ahi[64*136];
    __shared__ short Alo[64*136];
    const int t = threadIdx.x;
    const int w = t >> 6, lane = t & 63;
    const int m = lane & 15, qd = lane >> 4;
    const int row0 = blockIdx.x * 64;

    // stage A once
#pragma unroll
    for (int i = 0; i < 8; ++i) {
        int r = (t >> 5) + 8*i;
        int c = (t & 31) * 4;
        float4 av = *(const float4*)(A + (size_t)(row0 + r)*D_ + c);
        short4 hi4, lo4;
        split2(av.x, hi4.x, lo4.x);
        split2(av.y, hi4.y, lo4.y);
        split2(av.z, hi4.z, lo4.z);
        split2(av.w, hi4.w, lo4.w);
        *(short4*)&Ahi[r*136 + c] = hi4;
        *(short4*)&Alo[r*136 + c] = lo4;
    }
    __syncthreads();

#pragma unroll
    for (int sec = 0; sec < 3; ++sec) {
        const short* Wh = Whi + sec*16384;
        const short* Wl = Wlo + sec*16384;
        f32x4 acc[4][2];
#pragma unroll
        for (int r4 = 0; r4 < 4; ++r4)
#pragma unroll
            for (int j = 0; j < 2; ++j) acc[r4][j] = (f32x4){0,0,0,0};

#pragma unroll
        for (int ks = 0; ks < 4; ++ks) {
            bf16x8 wh[2], wl[2];
#pragma unroll
            for (int j = 0; j < 2; ++j) {
                size_t wi = (size_t)(32*w + 16*j + m)*D_ + 32*ks + 8*qd;
                wh[j] = *(const bf16x8*)(Wh + wi);
                wl[j] = *(const bf16x8*)(Wl + wi);
            }
#pragma unroll
            for (int r4 = 0; r4 < 4; ++r4) {
                bf16x8 ah = *(const bf16x8*)&Ahi[(16*r4 + m)*136 + 32*ks + 8*qd];
                bf16x8 al = *(const bf16x8*)&Alo[(16*r4 + m)*136 + 32*ks + 8*qd];
#pragma unroll
                for (int j = 0; j < 2; ++j) {
                    acc[r4][j] = __builtin_amdgcn_mfma_f32_16x16x32_bf16(wh[j], ah, acc[r4][j], 0, 0, 0);
                    acc[r4][j] = __builtin_amdgcn_mfma_f32_16x16x32_bf16(wh[j], al, acc[r4][j], 0, 0, 0);
                    acc[r4][j] = __builtin_amdgcn_mfma_f32_16x16x32_bf16(wl[j], ah, acc[r4][j], 0, 0, 0);
                }
            }
        }

#pragma unroll
        for (int r4 = 0; r4 < 4; ++r4) {
            int row = row0 + 16*r4 + m;
            int bb = row >> 11, l = row & 2047;
#pragma unroll
            for (int j = 0; j < 2; ++j) {
                int col = 32*w + 16*j + 4*qd;
                f32x4 v = acc[r4][j];
                if (sec == 0) {
                    float4 sv = {v[0], v[1], v[2], v[3]};
                    *(float4*)(qout + (size_t)row*D_ + col) = sv;
                } else if (sec == 1) {
                    size_t idx = ((size_t)((bb*4 + w)*2048 + l))*32 + (col & 31);
                    short4 hi4, lo4;
                    split2(v[0], hi4.x, lo4.x);
                    split2(v[1], hi4.y, lo4.y);
                    split2(v[2], hi4.z, lo4.z);
                    split2(v[3], hi4.w, lo4.w);
                    *(short4*)(khi + idx) = hi4;
                    *(short4*)(klo + idx) = lo4;
                } else {
                    size_t basep = (size_t)(bb*4 + w)*32;
#pragma unroll
                    for (int e = 0; e < 4; ++e) {
                        int d = 16*j + 4*qd + e;
                        short hh, ll; split2(v[e], hh, ll);
                        vhiT[(basep + d)*2048 + l] = hh;
                        vloT[(basep + d)*2048 + l] = ll;
                    }
                }
            }
        }
    }
}

// ---------------------------------------------------------------------------
// MFMA flash attention. K head-major [b,h,l,32]; V transposed [b,h,d,l].
// K LDS stride 40 (2-way banks on both stage-write and compute-read).
// exp2 softmax; pointer-selected mask row; split-precision QK & PV.
// ---------------------------------------------------------------------------
__global__ __launch_bounds__(256)
void attn_mfma_kernel(const float* __restrict__ q,
                      const short* __restrict__ khi, const short* __restrict__ klo,
                      const short* __restrict__ vhiT, const short* __restrict__ vloT,
                      const int* __restrict__ mask, const float* __restrict__ fm,
                      float* __restrict__ o)
{
    __shared__ short KhiS[64*KSTR];
    __shared__ short KloS[64*KSTR];
    __shared__ short Vthi[32*72];
    __shared__ short Vtlo[32*72];
    __shared__ short Pshi[4][16*PSTR];
    __shared__ short Pslo[4][16*PSTR];
    __shared__ float kmf[64];
    __shared__ float kfin[64];
    __shared__ float al_ls[4][16];
    __shared__ float l_ls [4][16];

    const int t    = threadIdx.x;
    const int w    = t >> 6;
    const int lane = t & 63;
    const int m    = lane & 15;
    const int qd   = lane >> 4;
    const int qt = blockIdx.x, h = blockIdx.y, b = blockIdx.z;

    const size_t hd = ((size_t)(b*4 + h))*2048*32;   // K base (head-major)

    // ---- Q fragment (B-operand), scaled by log2e, register-resident hi/lo ----
    const int qrow = qt*64 + 16*w + m;
    const float* qp = q + ((size_t)(b*L_ + qrow))*D_ + h*DK_ + 8*qd;
    float qf[8];
    *(float4*)&qf[0] = *(const float4*)qp;
    *(float4*)&qf[4] = *(const float4*)(qp + 4);
    bf16x8 qhi, qlo;
#pragma unroll
    for (int j = 0; j < 8; ++j) {
        float qs = qf[j] * LOG2E;
        short hs = f2bf(qs);
        qhi[j] = hs;
        qlo[j] = f2bf(qs - bf2f(hs));
    }
    const int qmv = mask[b*L_ + qrow];
    if (t < 64) kfin[t] = FMINV;
    const float* mrow = qmv ? kmf : kfin;   // fixed for whole loop

    const int skey = t >> 2, sd0 = (t & 3) * 8;  // K stage mapping
    const int vd = t >> 3;                  // V stage: dim row 0..31
    const int vk = (t & 7) * 8;             // keys 0,8..56

    float m_old = -INFINITY, l_run = 0.0f;
    f32x4 o_acc[2] = {{0,0,0,0},{0,0,0,0}};

    for (int kt = 0; kt < L_/64; ++kt) {
        __syncthreads();
        // ---- stage K: 16B copies, stride-40 rows (2-way banks) ----
        {
            const size_t gk = hd + (size_t)kt*64*32 + t*8;
            bf16x8 a = *(const bf16x8*)(khi + gk);
            bf16x8 c = *(const bf16x8*)(klo + gk);
            *(bf16x8*)&KhiS[skey*KSTR + sd0] = a;
            *(bf16x8*)&KloS[skey*KSTR + sd0] = c;
        }
        // ---- stage V^T: 16B copies ----
        {
            const size_t gvT = ((size_t)(b*4 + h)*32 + vd)*2048 + (size_t)kt*64 + vk;
            bf16x8 a = *(const bf16x8*)(vhiT + gvT);
            bf16x8 c = *(const bf16x8*)(vloT + gvT);
            *(bf16x8*)&Vthi[vd*72 + vk] = a;
            *(bf16x8*)&Vtlo[vd*72 + vk] = c;
        }
        if (t < 16) ((float4*)kmf)[t] = ((const float4*)(fm + (size_t)b*L_ + (size_t)kt*64))[t];
        __syncthreads();

        // ---- S^T = K·Q^T (split-precision, fp32 acc, log2 domain) ----
        f32x4 sf[4];
#pragma unroll
        for (int k4 = 0; k4 < 4; ++k4) {
            bf16x8 ka = *(const bf16x8*)&KhiS[(16*k4 + m)*KSTR + 8*qd];
            bf16x8 kl = *(const bf16x8*)&KloS[(16*k4 + m)*KSTR + 8*qd];
            f32x4 c = {0,0,0,0};
            c = __builtin_amdgcn_mfma_f32_16x16x32_bf16(ka, qhi, c, 0, 0, 0);
            c = __builtin_amdgcn_mfma_f32_16x16x32_bf16(ka, qlo, c, 0, 0, 0);
            c = __builtin_amdgcn_mfma_f32_16x16x32_bf16(kl, qhi, c, 0, 0, 0);
            sf[k4] = c;
        }

        // ---- finite-FMIN mask add (pointer-selected row) ----
        float sv[16];
#pragma unroll
        for (int k4 = 0; k4 < 4; ++k4) {
            float4 kmv = *(const float4*)&mrow[16*k4 + 4*qd];
            sv[4*k4+0] = sf[k4][0] + kmv.x;
            sv[4*k4+1] = sf[k4][1] + kmv.y;
            sv[4*k4+2] = sf[k4][2] + kmv.z;
            sv[4*k4+3] = sf[k4][3] + kmv.w;
        }

        // ---- online softmax (exp2 domain) ----
        float tmax = sv[0];
#pragma unroll
        for (int j = 1; j < 16; ++j) tmax = fmaxf(tmax, sv[j]);
        tmax = fmaxf(tmax, __shfl_xor(tmax, 16));
        tmax = fmaxf(tmax, __shfl_xor(tmax, 32));
        float mnew  = fmaxf(m_old, tmax);
        float alpha = EXP2F(m_old - mnew);
        float psum = 0.0f;
        short pbh[16], pbl[16];
#pragma unroll
        for (int j = 0; j < 16; ++j) {
            float p = EXP2F(sv[j] - mnew);   // FMIN-FMIN=0 -> 1 (uniform row)
            psum += p;
            split_trunc(p, pbh[j], pbl[j]);
        }
        psum += __shfl_xor(psum, 16);
        psum += __shfl_xor(psum, 32);
        l_run = l_run * alpha + psum;
        m_old = mnew;

        // ---- P store (C->A transpose), hi/lo ----
#pragma unroll
        for (int k4 = 0; k4 < 4; ++k4) {
            short4 s4h, s4l;
            s4h.x = pbh[4*k4+0]; s4h.y = pbh[4*k4+1]; s4h.z = pbh[4*k4+2]; s4h.w = pbh[4*k4+3];
            s4l.x = pbl[4*k4+0]; s4l.y = pbl[4*k4+1]; s4l.z = pbl[4*k4+2]; s4l.w = pbl[4*k4+3];
            *(short4*)&Pshi[w][m*PSTR + 16*k4 + 4*qd] = s4h;
            *(short4*)&Pslo[w][m*PSTR + 16*k4 + 4*qd] = s4l;
        }
        if (lane < 16) al_ls[w][lane] = alpha;

        // ---- O rescale + PV (split-precision) ----
        {
            float4 alr = *(const float4*)&al_ls[w][4*qd];
            o_acc[0][0]*=alr.x; o_acc[0][1]*=alr.y; o_acc[0][2]*=alr.z; o_acc[0][3]*=alr.w;
            o_acc[1][0]*=alr.x; o_acc[1][1]*=alr.y; o_acc[1][2]*=alr.z; o_acc[1][3]*=alr.w;
        }
#pragma unroll
        for (int s = 0; s < 2; ++s) {
            bf16x8 pah = *(const bf16x8*)&Pshi[w][m*PSTR + 32*s + 8*qd];
            bf16x8 pal = *(const bf16x8*)&Pslo[w][m*PSTR + 32*s + 8*qd];
#pragma unroll
            for (int tp = 0; tp < 2; ++tp) {
                bf16x8 vh = *(const bf16x8*)&Vthi[(16*tp + m)*72 + 32*s + 8*qd];
                bf16x8 vl = *(const bf16x8*)&Vtlo[(16*tp + m)*72 + 32*s + 8*qd];
                o_acc[tp] = __builtin_amdgcn_mfma_f32_16x16x32_bf16(pah, vh, o_acc[tp], 0, 0, 0);
                o_acc[tp] = __builtin_amdgcn_mfma_f32_16x16x32_bf16(pah, vl, o_acc[tp], 0, 0, 0);
                o_acc[tp] = __builtin_amdgcn_mfma_f32_16x16x32_bf16(pal, vh, o_acc[tp], 0, 0, 0);
            }
        }
    }

    if (lane < 16) l_ls[w][lane] = l_run;
    float4 lr = *(const float4*)&l_ls[w][4*qd];
    float li[4] = {1.0f/lr.x, 1.0f/lr.y, 1.0f/lr.z, 1.0f/lr.w};
#pragma unroll
    for (int tp = 0; tp < 2; ++tp)
#pragma unroll
        for (int r = 0; r < 4; ++r)
            o[((size_t)(b*L_ + qt*64 + 16*w + 4*qd + r))*D_ + h*DK_ + 16*tp + m] =
                o_acc[tp][r] * li[r];
}

// ---------------------------------------------------------------------------
// Per-batch softmax pooling
// ---------------------------------------------------------------------------
__global__ __launch_bounds__(256)
void pool_kernel(const float* __restrict__ att, const float* __restrict__ x,
                 float* __restrict__ ts)
{
    int b = blockIdx.x, t = threadIdx.x;
    __shared__ float red[4];
    __shared__ float p_s[L_];
    __shared__ float part[2][128];

    float m = -INFINITY;
    for (int l = t; l < L_; l += 256) m = fmaxf(m, att[b*L_ + l]);
#pragma unroll
    for (int s = 1; s < 64; s <<= 1) m = fmaxf(m, __shfl_xor(m, s));
    if ((t & 63) == 0) red[t >> 6] = m;
    __syncthreads();
    m = fmaxf(fmaxf(red[0], red[1]), fmaxf(red[2], red[3]));
    __syncthreads();

    float s = 0.0f;
    for (int l = t; l < L_; l += 256) {
        float p = __expf(att[b*L_ + l] - m);
        p_s[l] = p;
        s += p;
    }
#pragma unroll
    for (int st = 1; st < 64; st <<= 1) s += __shfl_xor(s, st);
    if ((t & 63) == 0) red[t >> 6] = s;
    __syncthreads();
    s = red[0] + red[1] + red[2] + red[3];
    float inv = 1.0f / s;

    int td = t & 127, half = t >> 7;
    float acc = 0.0f;
    const float* xb = x + ((size_t)(b*L_ + half*1024))*D_ + td;
    for (int i = 0; i < 1024; ++i) acc += p_s[half*1024 + i] * xb[(size_t)i*D_];
    part[half][td] = acc;
    __syncthreads();
    if (t < 128) ts[b*D_ + t] = (part[0][t] + part[1][t]) * inv;
}

// ---------------------------------------------------------------------------
// Demographics MLP
// ---------------------------------------------------------------------------
__global__ __launch_bounds__(256)
void demo_kernel(const float* __restrict__ demog, const float* __restrict__ Wd1,
                 const float* __restrict__ bd1, const float* __restrict__ Wd2,
                 const float* __restrict__ bd2, float* __restrict__ demo_out)
{
    int t = threadIdx.x;
    __shared__ float dsm[B_][DM_];
    __shared__ float hs[B_][2*D_];
    if (t < B_*DM_) dsm[t >> 4][t & 15] = demog[t];
    __syncthreads();
    {
        int col = t;
#pragma unroll
        for (int r = 0; r < B_; ++r) {
            float acc = bd1[col];
#pragma unroll
            for (int kk = 0; kk < DM_; ++kk) acc += dsm[r][kk]*Wd1[kk*(2*D_)+col];
            hs[r][col] = tanhf(acc);
        }
    }
    __syncthreads();
    {
        int c  = t & (D_-1);
        int r0 = t >> 7;
        for (int r = r0; r < B_; r += 2) {
            float acc = bd2[c];
            for (int kk = 0; kk < 2*D_; ++kk) acc += hs[r][kk]*Wd2[kk*D_+c];
            demo_out[r*D_+c] = acc;
        }
    }
}

// ---------------------------------------------------------------------------
// Head
// ---------------------------------------------------------------------------
__global__ __launch_bounds__(256)
void head_kernel(const float* __restrict__ ts, const float* __restrict__ demo,
                 const float* __restrict__ Wh, const float* __restrict__ bh,
                 float* __restrict__ out)
{
    int b = blockIdx.x, t = threadIdx.x;
    if (t >= F_OUT) return;
    float acc = bh[t];
    for (int k2 = 0; k2 < D_; ++k2) acc += ts[b*D_ + k2]   * Wh[k2*F_OUT + t];
    for (int k2 = 0; k2 < D_; ++k2) acc += demo[b*D_ + k2] * Wh[(D_+k2)*F_OUT + t];
    out[b*F_OUT + t] = acc;
}

// ---------------------------------------------------------------------------
extern "C" void kernel_launch(void* const* d_in, const int* in_sizes, int n_in,
                              void* d_out, int out_size, void* d_ws, size_t ws_size,
                              hipStream_t stream)
{
    (void)in_sizes; (void)n_in; (void)out_size; (void)ws_size;
    const float* values       = (const float*)d_in[0];
    const float* times        = (const float*)d_in[1];
    const int*   variables    = (const int*)  d_in[2];
    const int*   input_mask   = (const int*)  d_in[3];
    const float* demographics = (const float*)d_in[4];
    const float* W1t = (const float*)d_in[5];
    const float* b1t = (const float*)d_in[6];
    const float* W2t = (const float*)d_in[7];
    const float* W1v = (const float*)d_in[8];
    const float* b1v = (const float*)d_in[9];
    const float* W2v = (const float*)d_in[10];
    const float* var_table = (const float*)d_in[11];
    const float* Wq  = (const float*)d_in[12];
    const float* Wk  = (const float*)d_in[13];
    const float* Wv  = (const float*)d_in[14];
    const float* Wo  = (const float*)d_in[15];
    const float* W1  = (const float*)d_in[16];
    const float* b1  = (const float*)d_in[17];
    const float* W2  = (const float*)d_in[18];
    const float* b2  = (const float*)d_in[19];
    const float* Wf  = (const float*)d_in[20];
    const float* bfv = (const float*)d_in[21];
    const float* uf  = (const float*)d_in[22];
    const float* Wd1 = (const float*)d_in[23];
    const float* bd1 = (const float*)d_in[24];
    const float* Wd2 = (const float*)d_in[25];
    const float* bd2 = (const float*)d_in[26];
    const float* Wh  = (const float*)d_in[27];
    const float* bhv = (const float*)d_in[28];
    float* out = (float*)d_out;

    float* ws     = (float*)d_ws;
    float* x      = ws;
    float* qb     = ws + (size_t)SZ_X;
    float* region = ws + (size_t)2*SZ_X;
    short* khi    = (short*)region;
    short* klo    = khi + (size_t)SZ_X;
    short* vhiT   = klo + (size_t)SZ_X;
    short* vloT   = vhiT + (size_t)SZ_X;
    float* hb     = region;               // alias (FFN hidden)
    float* ob     = qb;                   // attn output aliases q
    float* attb   = ws + (size_t)4*SZ_X;  // BL_
    float* tsb    = attb + BL_;
    float* demob  = tsb + B_*D_;
    short* wt_hi  = (short*)(demob + B_*D_);
    short* wt_lo  = wt_hi + WT_TOT;
    short* wfhi   = wt_lo + WT_TOT;       // 16384
    short* wflo   = wfhi + 16384;
    float* fm     = (float*)(wflo + 16384); // BL_ floats (additive mask)

    embed_kernel<<<BL_, 128, 0, stream>>>(values, times, variables,
                                          W1t, b1t, W2t, W1v, b1v, W2v,
                                          var_table, x);
    maskprep_kernel<<<BL_/256, 256, 0, stream>>>(input_mask, fm);
    demo_kernel<<<1, 256, 0, stream>>>(demographics, Wd1, bd1, Wd2, bd2, demob);
    split_nk_kernel<<<64, 256, 0, stream>>>(Wf, wfhi, wflo, D_, D_);

    for (int i = 0; i < NL_; ++i) {
        split_layer_kernel<<<512, 256, 0, stream>>>(
            Wq + (size_t)i*H_*D_*DK_, Wk + (size_t)i*H_*D_*DK_,
            Wv + (size_t)i*H_*D_*DK_, Wo + (size_t)i*D_*D_,
            W1 + (size_t)i*D_*DFF_,  W2 + (size_t)i*DFF_*D_, wt_hi, wt_lo);

        gemm_qkv_fused<<<BL_/64, 256, 0, stream>>>(x, wt_hi, wt_lo,
            qb, khi, klo, vhiT, vloT);
        attn_mfma_kernel<<<dim3(L_/64, H_, B_), 256, 0, stream>>>(qb, khi, klo, vhiT, vloT,
                                                                  input_mask, fm, ob);
        gemm_mfma<1><<<dim3(BL_/64, 1), 256, 0, stream>>>(ob, wt_hi+WT_O, wt_lo+WT_O,
            nullptr, x, x, nullptr, nullptr, D_, D_);
        gemm_mfma<2><<<dim3(BL_/64, 2), 256, 0, stream>>>(x, wt_hi+WT_1, wt_lo+WT_1,
            b1 + i*DFF_, nullptr, hb, nullptr, nullptr, DFF_, D_);
        gemm_mfma<3><<<dim3(BL_/64, 1), 256, 0, stream>>>(hb, wt_hi+WT_2, wt_lo+WT_2,
            b2 + i*D_, x, x, nullptr, nullptr, D_, DFF_);
    }

    // fused fusion-attention: att = tanh(x@Wf+bf).uf + fm
    gemm_mfma<7><<<dim3(BL_/64, 1), 256, 0, stream>>>(x, wfhi, wflo,
        bfv, uf, attb, (short*)fm, nullptr, D_, D_);
    pool_kernel<<<B_, 256, 0, stream>>>(attb, x, tsb);
    head_kernel<<<B_, 256, 0, stream>>>(tsb, demob, Wh, bhv, out);
}

// Round 9
// 1175.700 us; speedup vs baseline: 2.8973x; 1.0445x over previous
//
#include <hip/hip_runtime.h>
#include <hip/hip_bf16.h>
#include <math.h>

#define B_   16
#define L_   2048
#define D_   128
#define H_   4
#define NL_  4
#define DK_  32
#define DFF_ 256
#define INTD_ 11
#define F_OUT 129
#define DM_  16
#define FMINV (-3.402823466e38f)
#define LOG2E 1.4426950408889634f

#define BL_  (B_*L_)      // 32768
#define SZ_X (BL_*D_)     // 4194304 floats

#define PSTR 72           // attn P-scratch stride (>=64 keys, 16B-aligned)

// per-layer pre-split weight offsets (in shorts), layout [col][K]
#define WT_Q 0
#define WT_K 16384
#define WT_V 32768
#define WT_O 49152
#define WT_1 65536        // 256 cols x 128
#define WT_2 98304        // 128 cols x 256
#define WT_TOT 131072

typedef __attribute__((ext_vector_type(8))) short bf16x8;
typedef __attribute__((ext_vector_type(4))) float f32x4;

#if __has_builtin(__builtin_amdgcn_exp2f)
#define EXP2F(x) __builtin_amdgcn_exp2f(x)
#else
#define EXP2F(x) __expf(0.69314718055994531f*(x))
#endif

static __device__ __forceinline__ short f2bf(float x) {
    union { __hip_bfloat16 h; short s; } u;
    u.h = __float2bfloat16(x);
    return u.s;
}
static __device__ __forceinline__ float bf2f(short s) {
    union { __hip_bfloat16 h; short t; } u;
    u.t = s;
    return __bfloat162float(u.h);
}
static __device__ __forceinline__ void split2(float v, short& h, short& l) {
    h = f2bf(v); l = f2bf(v - bf2f(h));
}
// truncation split: h = high 16 bits, residual exact, lo truncated (~2^-16 rel)
static __device__ __forceinline__ void split_trunc(float v, short& h, short& l) {
    unsigned u = __float_as_uint(v);
    h = (short)(u >> 16);
    float r = v - __uint_as_float(u & 0xffff0000u);
    l = (short)(__float_as_uint(r) >> 16);
}

// ---------------------------------------------------------------------------
// Embedding
// ---------------------------------------------------------------------------
__global__ __launch_bounds__(128)
void embed_kernel(const float* __restrict__ values, const float* __restrict__ times,
                  const int* __restrict__ variables,
                  const float* __restrict__ W1t, const float* __restrict__ b1t,
                  const float* __restrict__ W2t,
                  const float* __restrict__ W1v, const float* __restrict__ b1v,
                  const float* __restrict__ W2v,
                  const float* __restrict__ var_table, float* __restrict__ x)
{
    int bl = blockIdx.x;
    int t  = threadIdx.x;
    __shared__ float th[INTD_], vh[INTD_];
    if (t < INTD_)                th[t]    = tanhf(times[bl]  * W1t[t]    + b1t[t]);
    if (t >= 64 && t < 64+INTD_)  vh[t-64] = tanhf(values[bl] * W1v[t-64] + b1v[t-64]);
    __syncthreads();
    int var = variables[bl];
    float acc = var_table[var*D_ + t];
#pragma unroll
    for (int i = 0; i < INTD_; ++i)
        acc += th[i]*W2t[i*D_ + t] + vh[i]*W2v[i*D_ + t];
    x[bl*D_ + t] = acc;
}

// mask -> additive fp32 mask (0 or FMIN), once per launch
__global__ __launch_bounds__(256)
void maskprep_kernel(const int* __restrict__ mask, float* __restrict__ fm)
{
    int i = blockIdx.x*256 + threadIdx.x;
    fm[i] = mask[i] ? 0.0f : FMINV;
}

// ---------------------------------------------------------------------------
// ALL-layer weight pre-split: fp32 -> bf16 hi/lo (RNE), transposed to [col][K].
// grid covers NL_*131072 elements; layer = idx >> 17.
// ---------------------------------------------------------------------------
__global__ __launch_bounds__(256)
void split_all_kernel(const float* __restrict__ Wq, const float* __restrict__ Wk,
                      const float* __restrict__ Wv, const float* __restrict__ Wo,
                      const float* __restrict__ W1, const float* __restrict__ W2,
                      short* __restrict__ hi, short* __restrict__ lo)
{
    int gidx = blockIdx.x*256 + threadIdx.x;   // 0..4*131071
    int layer = gidx >> 17;
    int idx   = gidx & 131071;
    float v;
    if (idx < 49152) {                        // Q/K/V
        int which = idx >> 14;
        int r = idx & 16383;
        int col = r >> 7, k = r & 127;
        int h = col >> 5, e = col & 31;
        const float* src = ((which == 0) ? Wq : (which == 1) ? Wk : Wv)
                           + (size_t)layer*H_*D_*DK_;
        v = src[(h*D_ + k)*DK_ + e];
    } else if (idx < 65536) {                 // Wo
        int r = idx - 49152;
        int col = r >> 7, k = r & 127;
        v = Wo[(size_t)layer*D_*D_ + k*D_ + col];
    } else if (idx < 98304) {                 // W1
        int r = idx - 65536;
        int col = r >> 7, k = r & 127;
        v = W1[(size_t)layer*D_*DFF_ + k*DFF_ + col];
    } else {                                  // W2
        int r = idx - 98304;
        int col = r >> 8, k = r & 255;
        v = W2[(size_t)layer*DFF_*D_ + k*D_ + col];
    }
    short h2, l2; split2(v, h2, l2);
    hi[gidx] = h2; lo[gidx] = l2;
}

__global__ __launch_bounds__(256)
void split_nk_kernel(const float* __restrict__ W, short* __restrict__ hi,
                     short* __restrict__ lo, int N, int K)
{
    int idx = blockIdx.x*256 + threadIdx.x;
    int col = idx / K, k = idx - col*K;
    float v = W[k*N + col];
    short h2, l2; split2(v, h2, l2);
    hi[idx] = h2; lo[idx] = l2;
}

// ---------------------------------------------------------------------------
// MFMA GEMM: C[M][N] = A[M][K] @ W[K][N], W pre-split bf16 hi/lo in [col][K].
// Block: 64 rows x 128 cols, 4 waves. EPI: 0=none 1=+resid 2=+bias,gelu
// 3=+bias,+resid 4=+bias,tanh
// 7=fusion att: att[row] = tanh(acc+bias).uf + fm[row]  (uf in resid, fm in ohi)
// ---------------------------------------------------------------------------
template<int EPI>
__global__ __launch_bounds__(256)
void gemm_mfma(const float* __restrict__ A, const short* __restrict__ Whi,
               const short* __restrict__ Wlo, const float* __restrict__ bias,
               const float* __restrict__ resid, float* __restrict__ out,
               short* __restrict__ ohi, short* __restrict__ olo,
               int N, int K)
{
    __shared__ short Ahi[64*136];
    __shared__ short Alo[64*136];
    __shared__ float part[64][16];     // EPI7 only
    const int t = threadIdx.x;
    const int w = t >> 6, lane = t & 63;
    const int m = lane & 15, qd = lane >> 4;
    const int row0 = blockIdx.x * 64;
    const int col0 = blockIdx.y * 128;

    f32x4 acc[4][2];
#pragma unroll
    for (int r4 = 0; r4 < 4; ++r4)
#pragma unroll
        for (int j = 0; j < 2; ++j) acc[r4][j] = (f32x4){0,0,0,0};

    for (int kb = 0; kb < K; kb += 128) {
        if (kb) __syncthreads();
#pragma unroll
        for (int i = 0; i < 8; ++i) {
            int r = (t >> 5) + 8*i;
            int c = (t & 31) * 4;
            float4 av = *(const float4*)(A + (size_t)(row0 + r)*K + kb + c);
            short4 hi4, lo4;
            split2(av.x, hi4.x, lo4.x);
            split2(av.y, hi4.y, lo4.y);
            split2(av.z, hi4.z, lo4.z);
            split2(av.w, hi4.w, lo4.w);
            *(short4*)&Ahi[r*136 + c] = hi4;
            *(short4*)&Alo[r*136 + c] = lo4;
        }
        __syncthreads();

#pragma unroll
        for (int ks = 0; ks < 4; ++ks) {
            bf16x8 wh[2], wl[2];
#pragma unroll
            for (int j = 0; j < 2; ++j) {
                size_t wi = (size_t)(col0 + 32*w + 16*j + m)*K + kb + 32*ks + 8*qd;
                wh[j] = *(const bf16x8*)(Whi + wi);
                wl[j] = *(const bf16x8*)(Wlo + wi);
            }
#pragma unroll
            for (int r4 = 0; r4 < 4; ++r4) {
                bf16x8 ah = *(const bf16x8*)&Ahi[(16*r4 + m)*136 + 32*ks + 8*qd];
                bf16x8 al = *(const bf16x8*)&Alo[(16*r4 + m)*136 + 32*ks + 8*qd];
#pragma unroll
                for (int j = 0; j < 2; ++j) {
                    acc[r4][j] = __builtin_amdgcn_mfma_f32_16x16x32_bf16(wh[j], ah, acc[r4][j], 0, 0, 0);
                    acc[r4][j] = __builtin_amdgcn_mfma_f32_16x16x32_bf16(wh[j], al, acc[r4][j], 0, 0, 0);
                    acc[r4][j] = __builtin_amdgcn_mfma_f32_16x16x32_bf16(wl[j], ah, acc[r4][j], 0, 0, 0);
                }
            }
        }
    }

#pragma unroll
    for (int r4 = 0; r4 < 4; ++r4) {
        int row = row0 + 16*r4 + m;
        float dotp = 0.0f;                 // EPI7 partial
#pragma unroll
        for (int j = 0; j < 2; ++j) {
            int col = col0 + 32*w + 16*j + 4*qd;
            f32x4 v = acc[r4][j];
            if (EPI == 2 || EPI == 3 || EPI == 4 || EPI == 7) {
                float4 bv = *(const float4*)(bias + col);
                v[0] += bv.x; v[1] += bv.y; v[2] += bv.z; v[3] += bv.w;
            }
            if (EPI == 2) {
#pragma unroll
                for (int e = 0; e < 4; ++e)
                    v[e] = 0.5f * v[e] * (1.0f + erff(v[e] * 0.70710678118654752f));
            }
            if (EPI == 4 || EPI == 7) {
#pragma unroll
                for (int e = 0; e < 4; ++e) v[e] = tanhf(v[e]);
            }
            if (EPI == 1 || EPI == 3) {
                float4 rv = *(const float4*)(resid + (size_t)row*N + col);
                v[0] += rv.x; v[1] += rv.y; v[2] += rv.z; v[3] += rv.w;
            }
            if (EPI == 7) {
                float4 uv = *(const float4*)(resid + col);   // uf
                dotp += v[0]*uv.x + v[1]*uv.y + v[2]*uv.z + v[3]*uv.w;
            } else {
                float4 sv = {v[0], v[1], v[2], v[3]};
                *(float4*)(out + (size_t)row*N + col) = sv;
            }
        }
        if (EPI == 7) part[16*r4 + m][4*w + qd] = dotp;
    }
    if (EPI == 7) {
        __syncthreads();
        if (t < 64) {
            const float* fm = (const float*)ohi;
            float s = 0.0f;
#pragma unroll
            for (int i = 0; i < 16; ++i) s += part[t][i];
            out[row0 + t] = s + fm[row0 + t];
        }
    }
}

// ---------------------------------------------------------------------------
// Fused QKV GEMM: stage x hi/lo once, run 3 weight streams.
// Q -> fp32 [row][128]; K -> hi/lo head-major; V -> hi/lo transposed head-major.
// ---------------------------------------------------------------------------
__global__ __launch_bounds__(256)
void gemm_qkv_fused(const float* __restrict__ A, const short* __restrict__ Whi,
                    const short* __restrict__ Wlo, float* __restrict__ qout,
                    short* __restrict__ khi, short* __restrict__ klo,
                    short* __restrict__ vhiT, short* __restrict__ vloT)
{
    __shared__ short Ahi[64*136];
    __shared__ short Alo[64*136];
    const int t = threadIdx.x;
    const int w = t >> 6, lane = t & 63;
    const int m = lane & 15, qd = lane >> 4;
    const int row0 = blockIdx.x * 64;

    // stage A once
#pragma unroll
    for (int i = 0; i < 8; ++i) {
        int r = (t >> 5) + 8*i;
        int c = (t & 31) * 4;
        float4 av = *(const float4*)(A + (size_t)(row0 + r)*D_ + c);
        short4 hi4, lo4;
        split2(av.x, hi4.x, lo4.x);
        split2(av.y, hi4.y, lo4.y);
        split2(av.z, hi4.z, lo4.z);
        split2(av.w, hi4.w, lo4.w);
        *(short4*)&Ahi[r*136 + c] = hi4;
        *(short4*)&Alo[r*136 + c] = lo4;
    }
    __syncthreads();

#pragma unroll
    for (int sec = 0; sec < 3; ++sec) {
        const short* Wh = Whi + sec*16384;
        const short* Wl = Wlo + sec*16384;
        f32x4 acc[4][2];
#pragma unroll
        for (int r4 = 0; r4 < 4; ++r4)
#pragma unroll
            for (int j = 0; j < 2; ++j) acc[r4][j] = (f32x4){0,0,0,0};

#pragma unroll
        for (int ks = 0; ks < 4; ++ks) {
            bf16x8 wh[2], wl[2];
#pragma unroll
            for (int j = 0; j < 2; ++j) {
                size_t wi = (size_t)(32*w + 16*j + m)*D_ + 32*ks + 8*qd;
                wh[j] = *(const bf16x8*)(Wh + wi);
                wl[j] = *(const bf16x8*)(Wl + wi);
            }
#pragma unroll
            for (int r4 = 0; r4 < 4; ++r4) {
                bf16x8 ah = *(const bf16x8*)&Ahi[(16*r4 + m)*136 + 32*ks + 8*qd];
                bf16x8 al = *(const bf16x8*)&Alo[(16*r4 + m)*136 + 32*ks + 8*qd];
#pragma unroll
                for (int j = 0; j < 2; ++j) {
                    acc[r4][j] = __builtin_amdgcn_mfma_f32_16x16x32_bf16(wh[j], ah, acc[r4][j], 0, 0, 0);
                    acc[r4][j] = __builtin_amdgcn_mfma_f32_16x16x32_bf16(wh[j], al, acc[r4][j], 0, 0, 0);
                    acc[r4][j] = __builtin_amdgcn_mfma_f32_16x16x32_bf16(wl[j], ah, acc[r4][j], 0, 0, 0);
                }
            }
        }

#pragma unroll
        for (int r4 = 0; r4 < 4; ++r4) {
            int row = row0 + 16*r4 + m;
            int bb = row >> 11, l = row & 2047;
#pragma unroll
            for (int j = 0; j < 2; ++j) {
                int col = 32*w + 16*j + 4*qd;
                f32x4 v = acc[r4][j];
                if (sec == 0) {
                    float4 sv = {v[0], v[1], v[2], v[3]};
                    *(float4*)(qout + (size_t)row*D_ + col) = sv;
                } else if (sec == 1) {
                    size_t idx = ((size_t)((bb*4 + w)*2048 + l))*32 + (col & 31);
                    short4 hi4, lo4;
                    split2(v[0], hi4.x, lo4.x);
                    split2(v[1], hi4.y, lo4.y);
                    split2(v[2], hi4.z, lo4.z);
                    split2(v[3], hi4.w, lo4.w);
                    *(short4*)(khi + idx) = hi4;
                    *(short4*)(klo + idx) = lo4;
                } else {
                    size_t basep = (size_t)(bb*4 + w)*32;
#pragma unroll
                    for (int e = 0; e < 4; ++e) {
                        int d = 16*j + 4*qd + e;
                        short hh, ll; split2(v[e], hh, ll);
                        vhiT[(basep + d)*2048 + l] = hh;
                        vloT[(basep + d)*2048 + l] = ll;
                    }
                }
            }
        }
    }
}

// ---------------------------------------------------------------------------
// MFMA flash attention, software-pipelined staging:
// prefetch kt+1's K/V/mask into REGISTERS right after the post-write barrier,
// so the reg->LDS write next iteration waits on loads issued a compute-phase
// earlier (hides global latency behind MFMA+softmax).
// K unpadded [64][32] (measured-best); V [32][72]; exp2 softmax; hi/lo splits.
// ---------------------------------------------------------------------------
__global__ __launch_bounds__(256)
void attn_mfma_kernel(const float* __restrict__ q,
                      const short* __restrict__ khi, const short* __restrict__ klo,
                      const short* __restrict__ vhiT, const short* __restrict__ vloT,
                      const float* __restrict__ fm, float* __restrict__ o)
{
    __shared__ short KhiS[64*32];
    __shared__ short KloS[64*32];
    __shared__ short Vthi[32*72];
    __shared__ short Vtlo[32*72];
    __shared__ short Pshi[4][16*PSTR];
    __shared__ short Pslo[4][16*PSTR];
    __shared__ float kmf[64];
    __shared__ float kfin[64];
    __shared__ float al_ls[4][16];
    __shared__ float l_ls [4][16];

    const int t    = threadIdx.x;
    const int w    = t >> 6;
    const int lane = t & 63;
    const int m    = lane & 15;
    const int qd   = lane >> 4;
    const int qt = blockIdx.x, h = blockIdx.y, b = blockIdx.z;

    const size_t hd = ((size_t)(b*4 + h))*2048*32;   // K base (head-major)
    const int vd = t >> 3;                  // V stage: dim row 0..31
    const int vk = (t & 7) * 8;             // keys 0,8..56
    const size_t vbase = ((size_t)(b*4 + h)*32 + vd)*2048 + vk;

    // ---- Q fragment (B-operand), scaled by log2e, register-resident hi/lo ----
    const int qrow = qt*64 + 16*w + m;
    const float* qp = q + ((size_t)(b*L_ + qrow))*D_ + h*DK_ + 8*qd;
    float qf[8];
    *(float4*)&qf[0] = *(const float4*)qp;
    *(float4*)&qf[4] = *(const float4*)(qp + 4);
    bf16x8 qhi, qlo;
#pragma unroll
    for (int j = 0; j < 8; ++j) {
        float qs = qf[j] * LOG2E;
        short hs = f2bf(qs);
        qhi[j] = hs;
        qlo[j] = f2bf(qs - bf2f(hs));
    }
    const int qmv = (fm[b*L_ + qrow] == 0.0f);
    if (t < 64) kfin[t] = FMINV;
    const float* mrow = qmv ? kmf : kfin;   // fixed for whole loop

    // ---- prefetch registers for tile kt=0 ----
    bf16x8 pkh, pkl, pvh, pvl;
    float4 pmask = {0,0,0,0};
    {
        const size_t gk = hd + (size_t)t*8;
        pkh = *(const bf16x8*)(khi + gk);
        pkl = *(const bf16x8*)(klo + gk);
        pvh = *(const bf16x8*)(vhiT + vbase);
        pvl = *(const bf16x8*)(vloT + vbase);
        if (t < 16) pmask = ((const float4*)(fm + (size_t)b*L_))[t];
    }

    float m_old = -INFINITY, l_run = 0.0f;
    f32x4 o_acc[2] = {{0,0,0,0},{0,0,0,0}};

    for (int kt = 0; kt < L_/64; ++kt) {
        __syncthreads();                 // prior compute's LDS reads done
        // ---- write prefetched tile to LDS ----
        *(bf16x8*)&KhiS[t*8] = pkh;
        *(bf16x8*)&KloS[t*8] = pkl;
        *(bf16x8*)&Vthi[vd*72 + vk] = pvh;
        *(bf16x8*)&Vtlo[vd*72 + vk] = pvl;
        if (t < 16) ((float4*)kmf)[t] = pmask;
        __syncthreads();
        // ---- issue prefetch for kt+1 (overlaps with compute below) ----
        if (kt + 1 < L_/64) {
            const size_t gk = hd + (size_t)(kt+1)*64*32 + t*8;
            pkh = *(const bf16x8*)(khi + gk);
            pkl = *(const bf16x8*)(klo + gk);
            pvh = *(const bf16x8*)(vhiT + vbase + (size_t)(kt+1)*64);
            pvl = *(const bf16x8*)(vloT + vbase + (size_t)(kt+1)*64);
            if (t < 16) pmask = ((const float4*)(fm + (size_t)b*L_ + (size_t)(kt+1)*64))[t];
        }

        // ---- S^T = K·Q^T (split-precision, fp32 acc, log2 domain) ----
        f32x4 sf[4];
#pragma unroll
        for (int k4 = 0; k4 < 4; ++k4) {
            bf16x8 ka = *(const bf16x8*)&KhiS[(16*k4 + m)*32 + 8*qd];
            bf16x8 kl = *(const bf16x8*)&KloS[(16*k4 + m)*32 + 8*qd];
            f32x4 c = {0,0,0,0};
            c = __builtin_amdgcn_mfma_f32_16x16x32_bf16(ka, qhi, c, 0, 0, 0);
            c = __builtin_amdgcn_mfma_f32_16x16x32_bf16(ka, qlo, c, 0, 0, 0);
            c = __builtin_amdgcn_mfma_f32_16x16x32_bf16(kl, qhi, c, 0, 0, 0);
            sf[k4] = c;
        }

        // ---- finite-FMIN mask add (pointer-selected row) ----
        float sv[16];
#pragma unroll
        for (int k4 = 0; k4 < 4; ++k4) {
            float4 kmv = *(const float4*)&mrow[16*k4 + 4*qd];
            sv[4*k4+0] = sf[k4][0] + kmv.x;
            sv[4*k4+1] = sf[k4][1] + kmv.y;
            sv[4*k4+2] = sf[k4][2] + kmv.z;
            sv[4*k4+3] = sf[k4][3] + kmv.w;
        }

        // ---- online softmax (exp2 domain) ----
        float tmax = sv[0];
#pragma unroll
        for (int j = 1; j < 16; ++j) tmax = fmaxf(tmax, sv[j]);
        tmax = fmaxf(tmax, __shfl_xor(tmax, 16));
        tmax = fmaxf(tmax, __shfl_xor(tmax, 32));
        float mnew  = fmaxf(m_old, tmax);
        float alpha = EXP2F(m_old - mnew);
        float psum = 0.0f;
        short pbh[16], pbl[16];
#pragma unroll
        for (int j = 0; j < 16; ++j) {
            float p = EXP2F(sv[j] - mnew);   // FMIN-FMIN=0 -> 1 (uniform row)
            psum += p;
            split_trunc(p, pbh[j], pbl[j]);
        }
        psum += __shfl_xor(psum, 16);
        psum += __shfl_xor(psum, 32);
        l_run = l_run * alpha + psum;
        m_old = mnew;

        // ---- P store (C->A transpose), hi/lo ----
#pragma unroll
        for (int k4 = 0; k4 < 4; ++k4) {
            short4 s4h, s4l;
            s4h.x = pbh[4*k4+0]; s4h.y = pbh[4*k4+1]; s4h.z = pbh[4*k4+2]; s4h.w = pbh[4*k4+3];
            s4l.x = pbl[4*k4+0]; s4l.y = pbl[4*k4+1]; s4l.z = pbl[4*k4+2]; s4l.w = pbl[4*k4+3];
            *(short4*)&Pshi[w][m*PSTR + 16*k4 + 4*qd] = s4h;
            *(short4*)&Pslo[w][m*PSTR + 16*k4 + 4*qd] = s4l;
        }
        if (lane < 16) al_ls[w][lane] = alpha;

        // ---- O rescale + PV (split-precision) ----
        {
            float4 alr = *(const float4*)&al_ls[w][4*qd];
            o_acc[0][0]*=alr.x; o_acc[0][1]*=alr.y; o_acc[0][2]*=alr.z; o_acc[0][3]*=alr.w;
            o_acc[1][0]*=alr.x; o_acc[1][1]*=alr.y; o_acc[1][2]*=alr.z; o_acc[1][3]*=alr.w;
        }
#pragma unroll
        for (int s = 0; s < 2; ++s) {
            bf16x8 pah = *(const bf16x8*)&Pshi[w][m*PSTR + 32*s + 8*qd];
            bf16x8 pal = *(const bf16x8*)&Pslo[w][m*PSTR + 32*s + 8*qd];
#pragma unroll
            for (int tp = 0; tp < 2; ++tp) {
                bf16x8 vh = *(const bf16x8*)&Vthi[(16*tp + m)*72 + 32*s + 8*qd];
                bf16x8 vl = *(const bf16x8*)&Vtlo[(16*tp + m)*72 + 32*s + 8*qd];
                o_acc[tp] = __builtin_amdgcn_mfma_f32_16x16x32_bf16(pah, vh, o_acc[tp], 0, 0, 0);
                o_acc[tp] = __builtin_amdgcn_mfma_f32_16x16x32_bf16(pah, vl, o_acc[tp], 0, 0, 0);
                o_acc[tp] = __builtin_amdgcn_mfma_f32_16x16x32_bf16(pal, vh, o_acc[tp], 0, 0, 0);
            }
        }
    }

    if (lane < 16) l_ls[w][lane] = l_run;
    float4 lr = *(const float4*)&l_ls[w][4*qd];
    float li[4] = {1.0f/lr.x, 1.0f/lr.y, 1.0f/lr.z, 1.0f/lr.w};
#pragma unroll
    for (int tp = 0; tp < 2; ++tp)
#pragma unroll
        for (int r = 0; r < 4; ++r)
            o[((size_t)(b*L_ + qt*64 + 16*w + 4*qd + r))*D_ + h*DK_ + 16*tp + m] =
                o_acc[tp][r] * li[r];
}

// ---------------------------------------------------------------------------
// Pooling stage A: per-batch softmax over att, write normalized p
// ---------------------------------------------------------------------------
__global__ __launch_bounds__(256)
void pool_stats_kernel(const float* __restrict__ att, float* __restrict__ p)
{
    int b = blockIdx.x, t = threadIdx.x;
    __shared__ float red[4];
    __shared__ float a_s[L_];

    float m = -INFINITY;
    for (int l = t; l < L_; l += 256) {
        float a = att[b*L_ + l];
        a_s[l] = a;
        m = fmaxf(m, a);
    }
#pragma unroll
    for (int s = 1; s < 64; s <<= 1) m = fmaxf(m, __shfl_xor(m, s));
    if ((t & 63) == 0) red[t >> 6] = m;
    __syncthreads();
    m = fmaxf(fmaxf(red[0], red[1]), fmaxf(red[2], red[3]));
    __syncthreads();

    float s = 0.0f;
    for (int l = t; l < L_; l += 256) s += __expf(a_s[l] - m);
#pragma unroll
    for (int st = 1; st < 64; st <<= 1) s += __shfl_xor(s, st);
    if ((t & 63) == 0) red[t >> 6] = s;
    __syncthreads();
    s = red[0] + red[1] + red[2] + red[3];
    float inv = 1.0f / s;
    for (int l = t; l < L_; l += 256) p[b*L_ + l] = __expf(a_s[l] - m) * inv;
}

// ---------------------------------------------------------------------------
// Pooling stage B: partial weighted sums over L-chunks (full-GPU grid)
// part[b][c][d] = sum_{l in chunk c} p[b,l] * x[b,l,d]
// ---------------------------------------------------------------------------
__global__ __launch_bounds__(128)
void pool_partial_kernel(const float* __restrict__ p, const float* __restrict__ x,
                         float* __restrict__ part)
{
    int c = blockIdx.x, b = blockIdx.y, d = threadIdx.x;
    const float* xb = x + ((size_t)(b*L_ + c*128))*D_ + d;
    const float* pb = p + b*L_ + c*128;
    float acc = 0.0f;
#pragma unroll 4
    for (int i = 0; i < 128; ++i) acc += pb[i] * xb[(size_t)i*D_];
    part[((size_t)b*16 + c)*D_ + d] = acc;
}

// ---------------------------------------------------------------------------
// Demographics MLP
// ---------------------------------------------------------------------------
__global__ __launch_bounds__(256)
void demo_kernel(const float* __restrict__ demog, const float* __restrict__ Wd1,
                 const float* __restrict__ bd1, const float* __restrict__ Wd2,
                 const float* __restrict__ bd2, float* __restrict__ demo_out)
{
    int t = threadIdx.x;
    __shared__ float dsm[B_][DM_];
    __shared__ float hs[B_][2*D_];
    if (t < B_*DM_) dsm[t >> 4][t & 15] = demog[t];
    __syncthreads();
    {
        int col = t;
#pragma unroll
        for (int r = 0; r < B_; ++r) {
            float acc = bd1[col];
#pragma unroll
            for (int kk = 0; kk < DM_; ++kk) acc += dsm[r][kk]*Wd1[kk*(2*D_)+col];
            hs[r][col] = tanhf(acc);
        }
    }
    __syncthreads();
    {
        int c  = t & (D_-1);
        int r0 = t >> 7;
        for (int r = r0; r < B_; r += 2) {
            float acc = bd2[c];
            for (int kk = 0; kk < 2*D_; ++kk) acc += hs[r][kk]*Wd2[kk*D_+c];
            demo_out[r*D_+c] = acc;
        }
    }
}

// ---------------------------------------------------------------------------
// Head: reduces 16 pooling partials then out[b,f] = concat(ts,demo)@Wh + bh
// ---------------------------------------------------------------------------
__global__ __launch_bounds__(256)
void head_kernel(const float* __restrict__ part, const float* __restrict__ demo,
                 const float* __restrict__ Wh, const float* __restrict__ bh,
                 float* __restrict__ out)
{
    int b = blockIdx.x, t = threadIdx.x;
    __shared__ float tss[128];
    if (t < 128) {
        float s = 0.0f;
#pragma unroll
        for (int c = 0; c < 16; ++c) s += part[((size_t)b*16 + c)*D_ + t];
        tss[t] = s;
    }
    __syncthreads();
    if (t >= F_OUT) return;
    float acc = bh[t];
    for (int k2 = 0; k2 < D_; ++k2) acc += tss[k2]        * Wh[k2*F_OUT + t];
    for (int k2 = 0; k2 < D_; ++k2) acc += demo[b*D_ + k2] * Wh[(D_+k2)*F_OUT + t];
    out[b*F_OUT + t] = acc;
}

// ---------------------------------------------------------------------------
extern "C" void kernel_launch(void* const* d_in, const int* in_sizes, int n_in,
                              void* d_out, int out_size, void* d_ws, size_t ws_size,
                              hipStream_t stream)
{
    (void)in_sizes; (void)n_in; (void)out_size; (void)ws_size;
    const float* values       = (const float*)d_in[0];
    const float* times        = (const float*)d_in[1];
    const int*   variables    = (const int*)  d_in[2];
    const int*   input_mask   = (const int*)  d_in[3];
    const float* demographics = (const float*)d_in[4];
    const float* W1t = (const float*)d_in[5];
    const float* b1t = (const float*)d_in[6];
    const float* W2t = (const float*)d_in[7];
    const float* W1v = (const float*)d_in[8];
    const float* b1v = (const float*)d_in[9];
    const float* W2v = (const float*)d_in[10];
    const float* var_table = (const float*)d_in[11];
    const float* Wq  = (const float*)d_in[12];
    const float* Wk  = (const float*)d_in[13];
    const float* Wv  = (const float*)d_in[14];
    const float* Wo  = (const float*)d_in[15];
    const float* W1  = (const float*)d_in[16];
    const float* b1  = (const float*)d_in[17];
    const float* W2  = (const float*)d_in[18];
    const float* b2  = (const float*)d_in[19];
    const float* Wf  = (const float*)d_in[20];
    const float* bfv = (const float*)d_in[21];
    const float* uf  = (const float*)d_in[22];
    const float* Wd1 = (const float*)d_in[23];
    const float* bd1 = (const float*)d_in[24];
    const float* Wd2 = (const float*)d_in[25];
    const float* bd2 = (const float*)d_in[26];
    const float* Wh  = (const float*)d_in[27];
    const float* bhv = (const float*)d_in[28];
    float* out = (float*)d_out;

    float* ws     = (float*)d_ws;
    float* x      = ws;
    float* qb     = ws + (size_t)SZ_X;
    float* region = ws + (size_t)2*SZ_X;
    short* khi    = (short*)region;
    short* klo    = khi + (size_t)SZ_X;
    short* vhiT   = klo + (size_t)SZ_X;
    short* vloT   = vhiT + (size_t)SZ_X;
    float* hb     = region;               // alias (FFN hidden)
    float* ob     = qb;                   // attn output aliases q
    float* attb   = ws + (size_t)4*SZ_X;  // BL_
    float* attp   = attb + BL_;           // BL_  (normalized p)
    float* partb  = attp + BL_;           // B_*16*D_
    float* demob  = partb + B_*16*D_;     // B_*D_
    short* wt_hi  = (short*)(demob + B_*D_);   // NL_*WT_TOT shorts
    short* wt_lo  = wt_hi + (size_t)NL_*WT_TOT;
    short* wfhi   = wt_lo + (size_t)NL_*WT_TOT; // 16384
    short* wflo   = wfhi + 16384;
    float* fm     = (float*)(wflo + 16384);     // BL_ floats (additive mask)

    embed_kernel<<<BL_, 128, 0, stream>>>(values, times, variables,
                                          W1t, b1t, W2t, W1v, b1v, W2v,
                                          var_table, x);
    maskprep_kernel<<<BL_/256, 256, 0, stream>>>(input_mask, fm);
    demo_kernel<<<1, 256, 0, stream>>>(demographics, Wd1, bd1, Wd2, bd2, demob);
    split_nk_kernel<<<64, 256, 0, stream>>>(Wf, wfhi, wflo, D_, D_);
    split_all_kernel<<<NL_*512, 256, 0, stream>>>(Wq, Wk, Wv, Wo, W1, W2, wt_hi, wt_lo);

    for (int i = 0; i < NL_; ++i) {
        short* whL = wt_hi + (size_t)i*WT_TOT;
        short* wlL = wt_lo + (size_t)i*WT_TOT;
        gemm_qkv_fused<<<BL_/64, 256, 0, stream>>>(x, whL, wlL,
            qb, khi, klo, vhiT, vloT);
        attn_mfma_kernel<<<dim3(L_/64, H_, B_), 256, 0, stream>>>(qb, khi, klo, vhiT, vloT,
                                                                  fm, ob);
        gemm_mfma<1><<<dim3(BL_/64, 1), 256, 0, stream>>>(ob, whL+WT_O, wlL+WT_O,
            nullptr, x, x, nullptr, nullptr, D_, D_);
        gemm_mfma<2><<<dim3(BL_/64, 2), 256, 0, stream>>>(x, whL+WT_1, wlL+WT_1,
            b1 + i*DFF_, nullptr, hb, nullptr, nullptr, DFF_, D_);
        gemm_mfma<3><<<dim3(BL_/64, 1), 256, 0, stream>>>(hb, whL+WT_2, wlL+WT_2,
            b2 + i*D_, x, x, nullptr, nullptr, D_, DFF_);
    }

    // fused fusion-attention: att = tanh(x@Wf+bf).uf + fm
    gemm_mfma<7><<<dim3(BL_/64, 1), 256, 0, stream>>>(x, wfhi, wflo,
        bfv, uf, attb, (short*)fm, nullptr, D_, D_);
    pool_stats_kernel<<<B_, 256, 0, stream>>>(attb, attp);
    pool_partial_kernel<<<dim3(16, B_), 128, 0, stream>>>(attp, x, partb);
    head_kernel<<<B_, 256, 0, stream>>>(partb, demob, Wh, bhv, out);
}

// Round 10
// 892.914 us; speedup vs baseline: 3.8149x; 1.3167x over previous
//
#include <hip/hip_runtime.h>
#include <hip/hip_bf16.h>
#include <math.h>

#define B_   16
#define L_   2048
#define D_   128
#define H_   4
#define NL_  4
#define DK_  32
#define DFF_ 256
#define INTD_ 11
#define F_OUT 129
#define DM_  16
#define FMINV (-3.402823466e38f)
#define LOG2E 1.4426950408889634f

#define BL_  (B_*L_)      // 32768
#define SZ_X (BL_*D_)     // 4194304 floats

#define PSTR 72           // attn P-scratch stride

#define WT_Q 0
#define WT_K 16384
#define WT_V 32768
#define WT_O 49152
#define WT_1 65536
#define WT_2 98304
#define WT_TOT 131072

typedef __attribute__((ext_vector_type(8))) short bf16x8;
typedef __attribute__((ext_vector_type(4))) float f32x4;

#if __has_builtin(__builtin_amdgcn_exp2f)
#define EXP2F(x) __builtin_amdgcn_exp2f(x)
#else
#define EXP2F(x) __expf(0.69314718055994531f*(x))
#endif

static __device__ __forceinline__ short f2bf(float x) {
    union { __hip_bfloat16 h; short s; } u;
    u.h = __float2bfloat16(x);
    return u.s;
}
static __device__ __forceinline__ float bf2f(short s) {
    union { __hip_bfloat16 h; short t; } u;
    u.t = s;
    return __bfloat162float(u.h);
}
static __device__ __forceinline__ void split2(float v, short& h, short& l) {
    h = f2bf(v); l = f2bf(v - bf2f(h));
}
static __device__ __forceinline__ void split_trunc(float v, short& h, short& l) {
    unsigned u = __float_as_uint(v);
    h = (short)(u >> 16);
    float r = v - __uint_as_float(u & 0xffff0000u);
    l = (short)(__float_as_uint(r) >> 16);
}

// ---------------------------------------------------------------------------
// Embedding
// ---------------------------------------------------------------------------
__global__ __launch_bounds__(128)
void embed_kernel(const float* __restrict__ values, const float* __restrict__ times,
                  const int* __restrict__ variables,
                  const float* __restrict__ W1t, const float* __restrict__ b1t,
                  const float* __restrict__ W2t,
                  const float* __restrict__ W1v, const float* __restrict__ b1v,
                  const float* __restrict__ W2v,
                  const float* __restrict__ var_table, float* __restrict__ x)
{
    int bl = blockIdx.x;
    int t  = threadIdx.x;
    __shared__ float th[INTD_], vh[INTD_];
    if (t < INTD_)                th[t]    = tanhf(times[bl]  * W1t[t]    + b1t[t]);
    if (t >= 64 && t < 64+INTD_)  vh[t-64] = tanhf(values[bl] * W1v[t-64] + b1v[t-64]);
    __syncthreads();
    int var = variables[bl];
    float acc = var_table[var*D_ + t];
#pragma unroll
    for (int i = 0; i < INTD_; ++i)
        acc += th[i]*W2t[i*D_ + t] + vh[i]*W2v[i*D_ + t];
    x[bl*D_ + t] = acc;
}

// mask -> additive fp32 mask (0 or FMIN) for fusion attention
__global__ __launch_bounds__(256)
void maskprep_kernel(const int* __restrict__ mask, float* __restrict__ fm)
{
    int i = blockIdx.x*256 + threadIdx.x;
    fm[i] = mask[i] ? 0.0f : FMINV;
}

// ---------------------------------------------------------------------------
// Mask compaction: per batch, stable prefix-scan of valid (mask=1) rows.
// pos[b,l] = compact index or -1; kcount[b] = #valid; cfm[b,j] = 0 (j<Kb) else FMIN.
// ---------------------------------------------------------------------------
__global__ __launch_bounds__(256)
void compact_kernel(const int* __restrict__ mask, int* __restrict__ pos,
                    int* __restrict__ kcount, float* __restrict__ cfm)
{
    int b = blockIdx.x, t = threadIdx.x;
    int lane = t & 63, w = t >> 6;
    __shared__ int wsum[4];
    __shared__ int tot_s;
    int mv[8], loc[8], s = 0;
#pragma unroll
    for (int i = 0; i < 8; ++i) {
        mv[i] = mask[b*L_ + t*8 + i];
        loc[i] = s;
        s += mv[i];
    }
    int v = s;
#pragma unroll
    for (int d = 1; d < 64; d <<= 1) {
        int y = __shfl_up(v, d);
        if (lane >= d) v += y;
    }
    int excl = v - s;
    if (lane == 63) wsum[w] = v;
    __syncthreads();
    int wbase = 0;
    for (int i = 0; i < w; ++i) wbase += wsum[i];
    int base = wbase + excl;
#pragma unroll
    for (int i = 0; i < 8; ++i)
        pos[b*L_ + t*8 + i] = mv[i] ? (base + loc[i]) : -1;
    if (t == 255) { kcount[b] = base + s; tot_s = base + s; }
    __syncthreads();
    int tot = tot_s;
    for (int l = t; l < L_; l += 256) cfm[b*L_ + l] = (l < tot) ? 0.0f : FMINV;
}

// ---------------------------------------------------------------------------
// Per-layer: zero compact K/V tail slots [Kb, ceil64(Kb)) and meanV.
// (FFN aliases the K/V region each layer, so re-zero every layer.)
// ---------------------------------------------------------------------------
__global__ __launch_bounds__(256)
void tailzero_kernel(const int* __restrict__ kcount, short* __restrict__ khi,
                     short* __restrict__ klo, short* __restrict__ vhiT,
                     short* __restrict__ vloT, float* __restrict__ meanV)
{
    int b = blockIdx.x, t = threadIdx.x;
    int Kb = kcount[b];
    int end = (Kb + 63) & ~63;
    int tail = end - Kb;
    int tot = tail * H_ * DK_;
    int per_h = tail * 32;
    for (int i = t; i < tot; i += 256) {
        int h = i / per_h;
        int rem = i - h*per_h;
        int jj = rem >> 5, d = rem & 31;
        int j = Kb + jj;
        size_t ki = ((size_t)((b*4 + h)*2048 + j))*32 + d;
        khi[ki] = 0; klo[ki] = 0;
        size_t vi = ((size_t)(b*4 + h)*32 + d)*2048 + j;
        vhiT[vi] = 0; vloT[vi] = 0;
    }
    if (t < 128) meanV[b*128 + t] = 0.0f;
}

// ---------------------------------------------------------------------------
// ALL-layer weight pre-split
// ---------------------------------------------------------------------------
__global__ __launch_bounds__(256)
void split_all_kernel(const float* __restrict__ Wq, const float* __restrict__ Wk,
                      const float* __restrict__ Wv, const float* __restrict__ Wo,
                      const float* __restrict__ W1, const float* __restrict__ W2,
                      short* __restrict__ hi, short* __restrict__ lo)
{
    int gidx = blockIdx.x*256 + threadIdx.x;
    int layer = gidx >> 17;
    int idx   = gidx & 131071;
    float v;
    if (idx < 49152) {
        int which = idx >> 14;
        int r = idx & 16383;
        int col = r >> 7, k = r & 127;
        int h = col >> 5, e = col & 31;
        const float* src = ((which == 0) ? Wq : (which == 1) ? Wk : Wv)
                           + (size_t)layer*H_*D_*DK_;
        v = src[(h*D_ + k)*DK_ + e];
    } else if (idx < 65536) {
        int r = idx - 49152;
        int col = r >> 7, k = r & 127;
        v = Wo[(size_t)layer*D_*D_ + k*D_ + col];
    } else if (idx < 98304) {
        int r = idx - 65536;
        int col = r >> 7, k = r & 127;
        v = W1[(size_t)layer*D_*DFF_ + k*DFF_ + col];
    } else {
        int r = idx - 98304;
        int col = r >> 8, k = r & 255;
        v = W2[(size_t)layer*DFF_*D_ + k*D_ + col];
    }
    short h2, l2; split2(v, h2, l2);
    hi[gidx] = h2; lo[gidx] = l2;
}

__global__ __launch_bounds__(256)
void split_nk_kernel(const float* __restrict__ W, short* __restrict__ hi,
                     short* __restrict__ lo, int N, int K)
{
    int idx = blockIdx.x*256 + threadIdx.x;
    int col = idx / K, k = idx - col*K;
    float v = W[k*N + col];
    short h2, l2; split2(v, h2, l2);
    hi[idx] = h2; lo[idx] = l2;
}

// ---------------------------------------------------------------------------
// MFMA GEMM (EPI 2=+bias,gelu 3=+bias,+resid 7=fusion att dot)
// ---------------------------------------------------------------------------
template<int EPI>
__global__ __launch_bounds__(256)
void gemm_mfma(const float* __restrict__ A, const short* __restrict__ Whi,
               const short* __restrict__ Wlo, const float* __restrict__ bias,
               const float* __restrict__ resid, float* __restrict__ out,
               short* __restrict__ ohi, short* __restrict__ olo,
               int N, int K)
{
    __shared__ short Ahi[64*136];
    __shared__ short Alo[64*136];
    __shared__ float part[64][16];
    const int t = threadIdx.x;
    const int w = t >> 6, lane = t & 63;
    const int m = lane & 15, qd = lane >> 4;
    const int row0 = blockIdx.x * 64;
    const int col0 = blockIdx.y * 128;

    f32x4 acc[4][2];
#pragma unroll
    for (int r4 = 0; r4 < 4; ++r4)
#pragma unroll
        for (int j = 0; j < 2; ++j) acc[r4][j] = (f32x4){0,0,0,0};

    for (int kb = 0; kb < K; kb += 128) {
        if (kb) __syncthreads();
#pragma unroll
        for (int i = 0; i < 8; ++i) {
            int r = (t >> 5) + 8*i;
            int c = (t & 31) * 4;
            float4 av = *(const float4*)(A + (size_t)(row0 + r)*K + kb + c);
            short4 hi4, lo4;
            split2(av.x, hi4.x, lo4.x);
            split2(av.y, hi4.y, lo4.y);
            split2(av.z, hi4.z, lo4.z);
            split2(av.w, hi4.w, lo4.w);
            *(short4*)&Ahi[r*136 + c] = hi4;
            *(short4*)&Alo[r*136 + c] = lo4;
        }
        __syncthreads();

#pragma unroll
        for (int ks = 0; ks < 4; ++ks) {
            bf16x8 wh[2], wl[2];
#pragma unroll
            for (int j = 0; j < 2; ++j) {
                size_t wi = (size_t)(col0 + 32*w + 16*j + m)*K + kb + 32*ks + 8*qd;
                wh[j] = *(const bf16x8*)(Whi + wi);
                wl[j] = *(const bf16x8*)(Wlo + wi);
            }
#pragma unroll
            for (int r4 = 0; r4 < 4; ++r4) {
                bf16x8 ah = *(const bf16x8*)&Ahi[(16*r4 + m)*136 + 32*ks + 8*qd];
                bf16x8 al = *(const bf16x8*)&Alo[(16*r4 + m)*136 + 32*ks + 8*qd];
#pragma unroll
                for (int j = 0; j < 2; ++j) {
                    acc[r4][j] = __builtin_amdgcn_mfma_f32_16x16x32_bf16(wh[j], ah, acc[r4][j], 0, 0, 0);
                    acc[r4][j] = __builtin_amdgcn_mfma_f32_16x16x32_bf16(wh[j], al, acc[r4][j], 0, 0, 0);
                    acc[r4][j] = __builtin_amdgcn_mfma_f32_16x16x32_bf16(wl[j], ah, acc[r4][j], 0, 0, 0);
                }
            }
        }
    }

#pragma unroll
    for (int r4 = 0; r4 < 4; ++r4) {
        int row = row0 + 16*r4 + m;
        float dotp = 0.0f;
#pragma unroll
        for (int j = 0; j < 2; ++j) {
            int col = col0 + 32*w + 16*j + 4*qd;
            f32x4 v = acc[r4][j];
            if (EPI == 2 || EPI == 3 || EPI == 7) {
                float4 bv = *(const float4*)(bias + col);
                v[0] += bv.x; v[1] += bv.y; v[2] += bv.z; v[3] += bv.w;
            }
            if (EPI == 2) {
#pragma unroll
                for (int e = 0; e < 4; ++e)
                    v[e] = 0.5f * v[e] * (1.0f + erff(v[e] * 0.70710678118654752f));
            }
            if (EPI == 7) {
#pragma unroll
                for (int e = 0; e < 4; ++e) v[e] = tanhf(v[e]);
            }
            if (EPI == 3) {
                float4 rv = *(const float4*)(resid + (size_t)row*N + col);
                v[0] += rv.x; v[1] += rv.y; v[2] += rv.z; v[3] += rv.w;
            }
            if (EPI == 7) {
                float4 uv = *(const float4*)(resid + col);   // uf
                dotp += v[0]*uv.x + v[1]*uv.y + v[2]*uv.z + v[3]*uv.w;
            } else {
                float4 sv = {v[0], v[1], v[2], v[3]};
                *(float4*)(out + (size_t)row*N + col) = sv;
            }
        }
        if (EPI == 7) part[16*r4 + m][4*w + qd] = dotp;
    }
    if (EPI == 7) {
        __syncthreads();
        if (t < 64) {
            const float* fm = (const float*)ohi;
            float s = 0.0f;
#pragma unroll
            for (int i = 0; i < 16; ++i) s += part[t][i];
            out[row0 + t] = s + fm[row0 + t];
        }
    }
}

// ---------------------------------------------------------------------------
// Fused QKV GEMM with mask compaction:
// Q -> fp32 at COMPACT rows; K -> hi/lo head-major at compact index;
// V -> hi/lo transposed head-major at compact column; meanV += column sums
// over ALL rows (for masked-query outputs).
// ---------------------------------------------------------------------------
__global__ __launch_bounds__(256)
void gemm_qkv_fused(const float* __restrict__ A, const short* __restrict__ Whi,
                    const short* __restrict__ Wlo, const int* __restrict__ pos,
                    float* __restrict__ qout,
                    short* __restrict__ khi, short* __restrict__ klo,
                    short* __restrict__ vhiT, short* __restrict__ vloT,
                    float* __restrict__ meanV)
{
    __shared__ short Ahi[64*136];
    __shared__ short Alo[64*136];
    const int t = threadIdx.x;
    const int w = t >> 6, lane = t & 63;
    const int m = lane & 15, qd = lane >> 4;
    const int row0 = blockIdx.x * 64;
    const int bb = row0 >> 11;

    int cpos[4];
#pragma unroll
    for (int r4 = 0; r4 < 4; ++r4) cpos[r4] = pos[row0 + 16*r4 + m];

#pragma unroll
    for (int i = 0; i < 8; ++i) {
        int r = (t >> 5) + 8*i;
        int c = (t & 31) * 4;
        float4 av = *(const float4*)(A + (size_t)(row0 + r)*D_ + c);
        short4 hi4, lo4;
        split2(av.x, hi4.x, lo4.x);
        split2(av.y, hi4.y, lo4.y);
        split2(av.z, hi4.z, lo4.z);
        split2(av.w, hi4.w, lo4.w);
        *(short4*)&Ahi[r*136 + c] = hi4;
        *(short4*)&Alo[r*136 + c] = lo4;
    }
    __syncthreads();

#pragma unroll
    for (int sec = 0; sec < 3; ++sec) {
        const short* Wh = Whi + sec*16384;
        const short* Wl = Wlo + sec*16384;
        f32x4 acc[4][2];
#pragma unroll
        for (int r4 = 0; r4 < 4; ++r4)
#pragma unroll
            for (int j = 0; j < 2; ++j) acc[r4][j] = (f32x4){0,0,0,0};

#pragma unroll
        for (int ks = 0; ks < 4; ++ks) {
            bf16x8 wh[2], wl[2];
#pragma unroll
            for (int j = 0; j < 2; ++j) {
                size_t wi = (size_t)(32*w + 16*j + m)*D_ + 32*ks + 8*qd;
                wh[j] = *(const bf16x8*)(Wh + wi);
                wl[j] = *(const bf16x8*)(Wl + wi);
            }
#pragma unroll
            for (int r4 = 0; r4 < 4; ++r4) {
                bf16x8 ah = *(const bf16x8*)&Ahi[(16*r4 + m)*136 + 32*ks + 8*qd];
                bf16x8 al = *(const bf16x8*)&Alo[(16*r4 + m)*136 + 32*ks + 8*qd];
#pragma unroll
                for (int j = 0; j < 2; ++j) {
                    acc[r4][j] = __builtin_amdgcn_mfma_f32_16x16x32_bf16(wh[j], ah, acc[r4][j], 0, 0, 0);
                    acc[r4][j] = __builtin_amdgcn_mfma_f32_16x16x32_bf16(wh[j], al, acc[r4][j], 0, 0, 0);
                    acc[r4][j] = __builtin_amdgcn_mfma_f32_16x16x32_bf16(wl[j], ah, acc[r4][j], 0, 0, 0);
                }
            }
        }

        if (sec == 2) {
            // meanV column sums over ALL 64 rows of this block
            float vs[2][4];
#pragma unroll
            for (int j = 0; j < 2; ++j)
#pragma unroll
                for (int e = 0; e < 4; ++e) {
                    vs[j][e] = acc[0][j][e] + acc[1][j][e] + acc[2][j][e] + acc[3][j][e];
                }
#pragma unroll
            for (int d2 = 1; d2 < 16; d2 <<= 1)
#pragma unroll
                for (int j = 0; j < 2; ++j)
#pragma unroll
                    for (int e = 0; e < 4; ++e)
                        vs[j][e] += __shfl_xor(vs[j][e], d2);
            if (m == 0) {
#pragma unroll
                for (int j = 0; j < 2; ++j)
#pragma unroll
                    for (int e = 0; e < 4; ++e)
                        atomicAdd(&meanV[bb*128 + 32*w + 16*j + 4*qd + e], vs[j][e]);
            }
        }

#pragma unroll
        for (int r4 = 0; r4 < 4; ++r4) {
            int cq = cpos[r4];
            if (cq < 0) continue;
#pragma unroll
            for (int j = 0; j < 2; ++j) {
                int col = 32*w + 16*j + 4*qd;
                f32x4 v = acc[r4][j];
                if (sec == 0) {
                    float4 sv = {v[0], v[1], v[2], v[3]};
                    *(float4*)(qout + ((size_t)(bb*2048 + cq))*D_ + col) = sv;
                } else if (sec == 1) {
                    size_t idx = ((size_t)((bb*4 + w)*2048 + cq))*32 + (col & 31);
                    short4 hi4, lo4;
                    split2(v[0], hi4.x, lo4.x);
                    split2(v[1], hi4.y, lo4.y);
                    split2(v[2], hi4.z, lo4.z);
                    split2(v[3], hi4.w, lo4.w);
                    *(short4*)(khi + idx) = hi4;
                    *(short4*)(klo + idx) = lo4;
                } else {
                    size_t basep = (size_t)(bb*4 + w)*32;
#pragma unroll
                    for (int e = 0; e < 4; ++e) {
                        int d = 16*j + 4*qd + e;
                        short hh, ll; split2(v[e], hh, ll);
                        vhiT[(basep + d)*2048 + cq] = hh;
                        vloT[(basep + d)*2048 + cq] = ll;
                    }
                }
            }
        }
    }
}

// ---------------------------------------------------------------------------
// MFMA flash attention over COMPACT keys/queries (all unmasked).
// nt = ceil(Kb/64) tiles; padding keys carry cfm=FMIN and zero K/V data.
// Reads compact Q rows, writes compact O rows (in place in qb).
// ---------------------------------------------------------------------------
__global__ __launch_bounds__(256)
void attn_mfma_kernel(const float* __restrict__ q,
                      const short* __restrict__ khi, const short* __restrict__ klo,
                      const short* __restrict__ vhiT, const short* __restrict__ vloT,
                      const int* __restrict__ kcount, const float* __restrict__ cfm,
                      float* __restrict__ o)
{
    __shared__ short KhiS[64*32];
    __shared__ short KloS[64*32];
    __shared__ short Vthi[32*72];
    __shared__ short Vtlo[32*72];
    __shared__ short Pshi[4][16*PSTR];
    __shared__ short Pslo[4][16*PSTR];
    __shared__ float kmf[64];
    __shared__ float al_ls[4][16];
    __shared__ float l_ls [4][16];

    const int t    = threadIdx.x;
    const int w    = t >> 6;
    const int lane = t & 63;
    const int m    = lane & 15;
    const int qd   = lane >> 4;
    const int qt = blockIdx.x, h = blockIdx.y, b = blockIdx.z;

    const int Kb = kcount[b];
    if (qt*64 >= Kb) return;
    const int nt = (Kb + 63) >> 6;

    const size_t hd = ((size_t)(b*4 + h))*2048*32;
    const int vd = t >> 3;
    const int vk = (t & 7) * 8;
    const size_t vbase = ((size_t)(b*4 + h)*32 + vd)*2048 + vk;

    const int qrow = qt*64 + 16*w + m;       // compact row
    const float* qp = q + ((size_t)(b*L_ + qrow))*D_ + h*DK_ + 8*qd;
    float qf[8];
    *(float4*)&qf[0] = *(const float4*)qp;
    *(float4*)&qf[4] = *(const float4*)(qp + 4);
    bf16x8 qhi, qlo;
#pragma unroll
    for (int j = 0; j < 8; ++j) {
        float qs = qf[j] * LOG2E;
        short hs = f2bf(qs);
        qhi[j] = hs;
        qlo[j] = f2bf(qs - bf2f(hs));
    }

    // prefetch tile 0
    bf16x8 pkh, pkl, pvh, pvl;
    float4 pmask = {0,0,0,0};
    {
        const size_t gk = hd + (size_t)t*8;
        pkh = *(const bf16x8*)(khi + gk);
        pkl = *(const bf16x8*)(klo + gk);
        pvh = *(const bf16x8*)(vhiT + vbase);
        pvl = *(const bf16x8*)(vloT + vbase);
        if (t < 16) pmask = ((const float4*)(cfm + (size_t)b*L_))[t];
    }

    float m_old = -INFINITY, l_run = 0.0f;
    f32x4 o_acc[2] = {{0,0,0,0},{0,0,0,0}};

    for (int kt = 0; kt < nt; ++kt) {
        __syncthreads();
        *(bf16x8*)&KhiS[t*8] = pkh;
        *(bf16x8*)&KloS[t*8] = pkl;
        *(bf16x8*)&Vthi[vd*72 + vk] = pvh;
        *(bf16x8*)&Vtlo[vd*72 + vk] = pvl;
        if (t < 16) ((float4*)kmf)[t] = pmask;
        __syncthreads();
        if (kt + 1 < nt) {
            const size_t gk = hd + (size_t)(kt+1)*64*32 + t*8;
            pkh = *(const bf16x8*)(khi + gk);
            pkl = *(const bf16x8*)(klo + gk);
            pvh = *(const bf16x8*)(vhiT + vbase + (size_t)(kt+1)*64);
            pvl = *(const bf16x8*)(vloT + vbase + (size_t)(kt+1)*64);
            if (t < 16) pmask = ((const float4*)(cfm + (size_t)b*L_ + (size_t)(kt+1)*64))[t];
        }

        f32x4 sf[4];
#pragma unroll
        for (int k4 = 0; k4 < 4; ++k4) {
            bf16x8 ka = *(const bf16x8*)&KhiS[(16*k4 + m)*32 + 8*qd];
            bf16x8 kl = *(const bf16x8*)&KloS[(16*k4 + m)*32 + 8*qd];
            f32x4 c = {0,0,0,0};
            c = __builtin_amdgcn_mfma_f32_16x16x32_bf16(ka, qhi, c, 0, 0, 0);
            c = __builtin_amdgcn_mfma_f32_16x16x32_bf16(ka, qlo, c, 0, 0, 0);
            c = __builtin_amdgcn_mfma_f32_16x16x32_bf16(kl, qhi, c, 0, 0, 0);
            sf[k4] = c;
        }

        float sv[16];
#pragma unroll
        for (int k4 = 0; k4 < 4; ++k4) {
            float4 kmv = *(const float4*)&kmf[16*k4 + 4*qd];
            sv[4*k4+0] = sf[k4][0] + kmv.x;
            sv[4*k4+1] = sf[k4][1] + kmv.y;
            sv[4*k4+2] = sf[k4][2] + kmv.z;
            sv[4*k4+3] = sf[k4][3] + kmv.w;
        }

        float tmax = sv[0];
#pragma unroll
        for (int j = 1; j < 16; ++j) tmax = fmaxf(tmax, sv[j]);
        tmax = fmaxf(tmax, __shfl_xor(tmax, 16));
        tmax = fmaxf(tmax, __shfl_xor(tmax, 32));
        float mnew  = fmaxf(m_old, tmax);
        float alpha = EXP2F(m_old - mnew);
        float psum = 0.0f;
        short pbh[16], pbl[16];
#pragma unroll
        for (int j = 0; j < 16; ++j) {
            float p = EXP2F(sv[j] - mnew);
            psum += p;
            split_trunc(p, pbh[j], pbl[j]);
        }
        psum += __shfl_xor(psum, 16);
        psum += __shfl_xor(psum, 32);
        l_run = l_run * alpha + psum;
        m_old = mnew;

#pragma unroll
        for (int k4 = 0; k4 < 4; ++k4) {
            short4 s4h, s4l;
            s4h.x = pbh[4*k4+0]; s4h.y = pbh[4*k4+1]; s4h.z = pbh[4*k4+2]; s4h.w = pbh[4*k4+3];
            s4l.x = pbl[4*k4+0]; s4l.y = pbl[4*k4+1]; s4l.z = pbl[4*k4+2]; s4l.w = pbl[4*k4+3];
            *(short4*)&Pshi[w][m*PSTR + 16*k4 + 4*qd] = s4h;
            *(short4*)&Pslo[w][m*PSTR + 16*k4 + 4*qd] = s4l;
        }
        if (lane < 16) al_ls[w][lane] = alpha;

        {
            float4 alr = *(const float4*)&al_ls[w][4*qd];
            o_acc[0][0]*=alr.x; o_acc[0][1]*=alr.y; o_acc[0][2]*=alr.z; o_acc[0][3]*=alr.w;
            o_acc[1][0]*=alr.x; o_acc[1][1]*=alr.y; o_acc[1][2]*=alr.z; o_acc[1][3]*=alr.w;
        }
#pragma unroll
        for (int s = 0; s < 2; ++s) {
            bf16x8 pah = *(const bf16x8*)&Pshi[w][m*PSTR + 32*s + 8*qd];
            bf16x8 pal = *(const bf16x8*)&Pslo[w][m*PSTR + 32*s + 8*qd];
#pragma unroll
            for (int tp = 0; tp < 2; ++tp) {
                bf16x8 vh = *(const bf16x8*)&Vthi[(16*tp + m)*72 + 32*s + 8*qd];
                bf16x8 vl = *(const bf16x8*)&Vtlo[(16*tp + m)*72 + 32*s + 8*qd];
                o_acc[tp] = __builtin_amdgcn_mfma_f32_16x16x32_bf16(pah, vh, o_acc[tp], 0, 0, 0);
                o_acc[tp] = __builtin_amdgcn_mfma_f32_16x16x32_bf16(pah, vl, o_acc[tp], 0, 0, 0);
                o_acc[tp] = __builtin_amdgcn_mfma_f32_16x16x32_bf16(pal, vh, o_acc[tp], 0, 0, 0);
            }
        }
    }

    if (lane < 16) l_ls[w][lane] = l_run;
    float4 lr = *(const float4*)&l_ls[w][4*qd];
    float li[4] = {1.0f/lr.x, 1.0f/lr.y, 1.0f/lr.z, 1.0f/lr.w};
#pragma unroll
    for (int tp = 0; tp < 2; ++tp)
#pragma unroll
        for (int r = 0; r < 4; ++r)
            o[((size_t)(b*L_ + qt*64 + 16*w + 4*qd + r))*D_ + h*DK_ + 16*tp + m] =
                o_acc[tp][r] * li[r];
}

// ---------------------------------------------------------------------------
// Wo GEMM with row gather: A row = pos>=0 ? compactO[pos] : meanV/2048.
// x = gather(o) @ Wo + x. Fixed N=K=128.
// ---------------------------------------------------------------------------
__global__ __launch_bounds__(256)
void gemm_wo(const float* __restrict__ A, const int* __restrict__ pos,
             const float* __restrict__ meanV,
             const short* __restrict__ Whi, const short* __restrict__ Wlo,
             const float* __restrict__ resid, float* __restrict__ out)
{
    __shared__ short Ahi[64*136];
    __shared__ short Alo[64*136];
    const int t = threadIdx.x;
    const int w = t >> 6, lane = t & 63;
    const int m = lane & 15, qd = lane >> 4;
    const int row0 = blockIdx.x * 64;

#pragma unroll
    for (int i = 0; i < 8; ++i) {
        int r = (t >> 5) + 8*i;
        int c = (t & 31) * 4;
        int row = row0 + r;
        int p = pos[row];
        const float* src = (p >= 0)
            ? (A + ((size_t)((row & ~2047) + p))*D_ + c)
            : (meanV + (size_t)(row >> 11)*128 + c);
        float4 av = *(const float4*)src;
        float sc = (p >= 0) ? 1.0f : (1.0f/2048.0f);
        av.x *= sc; av.y *= sc; av.z *= sc; av.w *= sc;
        short4 hi4, lo4;
        split2(av.x, hi4.x, lo4.x);
        split2(av.y, hi4.y, lo4.y);
        split2(av.z, hi4.z, lo4.z);
        split2(av.w, hi4.w, lo4.w);
        *(short4*)&Ahi[r*136 + c] = hi4;
        *(short4*)&Alo[r*136 + c] = lo4;
    }
    __syncthreads();

    f32x4 acc[4][2];
#pragma unroll
    for (int r4 = 0; r4 < 4; ++r4)
#pragma unroll
        for (int j = 0; j < 2; ++j) acc[r4][j] = (f32x4){0,0,0,0};

#pragma unroll
    for (int ks = 0; ks < 4; ++ks) {
        bf16x8 wh[2], wl[2];
#pragma unroll
        for (int j = 0; j < 2; ++j) {
            size_t wi = (size_t)(32*w + 16*j + m)*D_ + 32*ks + 8*qd;
            wh[j] = *(const bf16x8*)(Whi + wi);
            wl[j] = *(const bf16x8*)(Wlo + wi);
        }
#pragma unroll
        for (int r4 = 0; r4 < 4; ++r4) {
            bf16x8 ah = *(const bf16x8*)&Ahi[(16*r4 + m)*136 + 32*ks + 8*qd];
            bf16x8 al = *(const bf16x8*)&Alo[(16*r4 + m)*136 + 32*ks + 8*qd];
#pragma unroll
            for (int j = 0; j < 2; ++j) {
                acc[r4][j] = __builtin_amdgcn_mfma_f32_16x16x32_bf16(wh[j], ah, acc[r4][j], 0, 0, 0);
                acc[r4][j] = __builtin_amdgcn_mfma_f32_16x16x32_bf16(wh[j], al, acc[r4][j], 0, 0, 0);
                acc[r4][j] = __builtin_amdgcn_mfma_f32_16x16x32_bf16(wl[j], ah, acc[r4][j], 0, 0, 0);
            }
        }
    }

#pragma unroll
    for (int r4 = 0; r4 < 4; ++r4) {
        int row = row0 + 16*r4 + m;
#pragma unroll
        for (int j = 0; j < 2; ++j) {
            int col = 32*w + 16*j + 4*qd;
            f32x4 v = acc[r4][j];
            float4 rv = *(const float4*)(resid + (size_t)row*D_ + col);
            float4 sv = {v[0]+rv.x, v[1]+rv.y, v[2]+rv.z, v[3]+rv.w};
            *(float4*)(out + (size_t)row*D_ + col) = sv;
        }
    }
}

// ---------------------------------------------------------------------------
// Pooling stages
// ---------------------------------------------------------------------------
__global__ __launch_bounds__(256)
void pool_stats_kernel(const float* __restrict__ att, float* __restrict__ p)
{
    int b = blockIdx.x, t = threadIdx.x;
    __shared__ float red[4];
    __shared__ float a_s[L_];

    float m = -INFINITY;
    for (int l = t; l < L_; l += 256) {
        float a = att[b*L_ + l];
        a_s[l] = a;
        m = fmaxf(m, a);
    }
#pragma unroll
    for (int s = 1; s < 64; s <<= 1) m = fmaxf(m, __shfl_xor(m, s));
    if ((t & 63) == 0) red[t >> 6] = m;
    __syncthreads();
    m = fmaxf(fmaxf(red[0], red[1]), fmaxf(red[2], red[3]));
    __syncthreads();

    float s = 0.0f;
    for (int l = t; l < L_; l += 256) s += __expf(a_s[l] - m);
#pragma unroll
    for (int st = 1; st < 64; st <<= 1) s += __shfl_xor(s, st);
    if ((t & 63) == 0) red[t >> 6] = s;
    __syncthreads();
    s = red[0] + red[1] + red[2] + red[3];
    float inv = 1.0f / s;
    for (int l = t; l < L_; l += 256) p[b*L_ + l] = __expf(a_s[l] - m) * inv;
}

__global__ __launch_bounds__(128)
void pool_partial_kernel(const float* __restrict__ p, const float* __restrict__ x,
                         float* __restrict__ part)
{
    int c = blockIdx.x, b = blockIdx.y, d = threadIdx.x;
    const float* xb = x + ((size_t)(b*L_ + c*128))*D_ + d;
    const float* pb = p + b*L_ + c*128;
    float acc = 0.0f;
#pragma unroll 4
    for (int i = 0; i < 128; ++i) acc += pb[i] * xb[(size_t)i*D_];
    part[((size_t)b*16 + c)*D_ + d] = acc;
}

// ---------------------------------------------------------------------------
// Demographics MLP
// ---------------------------------------------------------------------------
__global__ __launch_bounds__(256)
void demo_kernel(const float* __restrict__ demog, const float* __restrict__ Wd1,
                 const float* __restrict__ bd1, const float* __restrict__ Wd2,
                 const float* __restrict__ bd2, float* __restrict__ demo_out)
{
    int t = threadIdx.x;
    __shared__ float dsm[B_][DM_];
    __shared__ float hs[B_][2*D_];
    if (t < B_*DM_) dsm[t >> 4][t & 15] = demog[t];
    __syncthreads();
    {
        int col = t;
#pragma unroll
        for (int r = 0; r < B_; ++r) {
            float acc = bd1[col];
#pragma unroll
            for (int kk = 0; kk < DM_; ++kk) acc += dsm[r][kk]*Wd1[kk*(2*D_)+col];
            hs[r][col] = tanhf(acc);
        }
    }
    __syncthreads();
    {
        int c  = t & (D_-1);
        int r0 = t >> 7;
        for (int r = r0; r < B_; r += 2) {
            float acc = bd2[c];
            for (int kk = 0; kk < 2*D_; ++kk) acc += hs[r][kk]*Wd2[kk*D_+c];
            demo_out[r*D_+c] = acc;
        }
    }
}

// ---------------------------------------------------------------------------
// Head
// ---------------------------------------------------------------------------
__global__ __launch_bounds__(256)
void head_kernel(const float* __restrict__ part, const float* __restrict__ demo,
                 const float* __restrict__ Wh, const float* __restrict__ bh,
                 float* __restrict__ out)
{
    int b = blockIdx.x, t = threadIdx.x;
    __shared__ float tss[128];
    if (t < 128) {
        float s = 0.0f;
#pragma unroll
        for (int c = 0; c < 16; ++c) s += part[((size_t)b*16 + c)*D_ + t];
        tss[t] = s;
    }
    __syncthreads();
    if (t >= F_OUT) return;
    float acc = bh[t];
    for (int k2 = 0; k2 < D_; ++k2) acc += tss[k2]         * Wh[k2*F_OUT + t];
    for (int k2 = 0; k2 < D_; ++k2) acc += demo[b*D_ + k2] * Wh[(D_+k2)*F_OUT + t];
    out[b*F_OUT + t] = acc;
}

// ---------------------------------------------------------------------------
extern "C" void kernel_launch(void* const* d_in, const int* in_sizes, int n_in,
                              void* d_out, int out_size, void* d_ws, size_t ws_size,
                              hipStream_t stream)
{
    (void)in_sizes; (void)n_in; (void)out_size; (void)ws_size;
    const float* values       = (const float*)d_in[0];
    const float* times        = (const float*)d_in[1];
    const int*   variables    = (const int*)  d_in[2];
    const int*   input_mask   = (const int*)  d_in[3];
    const float* demographics = (const float*)d_in[4];
    const float* W1t = (const float*)d_in[5];
    const float* b1t = (const float*)d_in[6];
    const float* W2t = (const float*)d_in[7];
    const float* W1v = (const float*)d_in[8];
    const float* b1v = (const float*)d_in[9];
    const float* W2v = (const float*)d_in[10];
    const float* var_table = (const float*)d_in[11];
    const float* Wq  = (const float*)d_in[12];
    const float* Wk  = (const float*)d_in[13];
    const float* Wv  = (const float*)d_in[14];
    const float* Wo  = (const float*)d_in[15];
    const float* W1  = (const float*)d_in[16];
    const float* b1  = (const float*)d_in[17];
    const float* W2  = (const float*)d_in[18];
    const float* b2  = (const float*)d_in[19];
    const float* Wf  = (const float*)d_in[20];
    const float* bfv = (const float*)d_in[21];
    const float* uf  = (const float*)d_in[22];
    const float* Wd1 = (const float*)d_in[23];
    const float* bd1 = (const float*)d_in[24];
    const float* Wd2 = (const float*)d_in[25];
    const float* bd2 = (const float*)d_in[26];
    const float* Wh  = (const float*)d_in[27];
    const float* bhv = (const float*)d_in[28];
    float* out = (float*)d_out;

    float* ws     = (float*)d_ws;
    float* x      = ws;
    float* qb     = ws + (size_t)SZ_X;
    float* region = ws + (size_t)2*SZ_X;
    short* khi    = (short*)region;
    short* klo    = khi + (size_t)SZ_X;
    short* vhiT   = klo + (size_t)SZ_X;
    short* vloT   = vhiT + (size_t)SZ_X;
    float* hb     = region;               // alias (FFN hidden)
    float* attb   = ws + (size_t)4*SZ_X;  // BL_
    float* attp   = attb + BL_;           // BL_
    float* partb  = attp + BL_;           // B_*16*D_
    float* demob  = partb + B_*16*D_;     // B_*D_
    short* wt_hi  = (short*)(demob + B_*D_);
    short* wt_lo  = wt_hi + (size_t)NL_*WT_TOT;
    short* wfhi   = wt_lo + (size_t)NL_*WT_TOT;
    short* wflo   = wfhi + 16384;
    float* fm     = (float*)(wflo + 16384);     // BL_
    int*   posb   = (int*)(fm + BL_);           // BL_
    int*   kcountb= posb + BL_;                 // B_
    float* cfmb   = (float*)(kcountb + B_);     // BL_
    float* meanVb = cfmb + BL_;                 // B_*128

    embed_kernel<<<BL_, 128, 0, stream>>>(values, times, variables,
                                          W1t, b1t, W2t, W1v, b1v, W2v,
                                          var_table, x);
    maskprep_kernel<<<BL_/256, 256, 0, stream>>>(input_mask, fm);
    compact_kernel<<<B_, 256, 0, stream>>>(input_mask, posb, kcountb, cfmb);
    demo_kernel<<<1, 256, 0, stream>>>(demographics, Wd1, bd1, Wd2, bd2, demob);
    split_nk_kernel<<<64, 256, 0, stream>>>(Wf, wfhi, wflo, D_, D_);
    split_all_kernel<<<NL_*512, 256, 0, stream>>>(Wq, Wk, Wv, Wo, W1, W2, wt_hi, wt_lo);

    for (int i = 0; i < NL_; ++i) {
        short* whL = wt_hi + (size_t)i*WT_TOT;
        short* wlL = wt_lo + (size_t)i*WT_TOT;
        tailzero_kernel<<<B_, 256, 0, stream>>>(kcountb, khi, klo, vhiT, vloT, meanVb);
        gemm_qkv_fused<<<BL_/64, 256, 0, stream>>>(x, whL, wlL, posb,
            qb, khi, klo, vhiT, vloT, meanVb);
        attn_mfma_kernel<<<dim3(L_/64, H_, B_), 256, 0, stream>>>(qb, khi, klo, vhiT, vloT,
                                                                  kcountb, cfmb, qb);
        gemm_wo<<<BL_/64, 256, 0, stream>>>(qb, posb, meanVb,
            whL+WT_O, wlL+WT_O, x, x);
        gemm_mfma<2><<<dim3(BL_/64, 2), 256, 0, stream>>>(x, whL+WT_1, wlL+WT_1,
            b1 + i*DFF_, nullptr, hb, nullptr, nullptr, DFF_, D_);
        gemm_mfma<3><<<dim3(BL_/64, 1), 256, 0, stream>>>(hb, whL+WT_2, wlL+WT_2,
            b2 + i*D_, x, x, nullptr, nullptr, D_, DFF_);
    }

    gemm_mfma<7><<<dim3(BL_/64, 1), 256, 0, stream>>>(x, wfhi, wflo,
        bfv, uf, attb, (short*)fm, nullptr, D_, D_);
    pool_stats_kernel<<<B_, 256, 0, stream>>>(attb, attp);
    pool_partial_kernel<<<dim3(16, B_), 128, 0, stream>>>(attp, x, partb);
    head_kernel<<<B_, 256, 0, stream>>>(partb, demob, Wh, bhv, out);
}

// Round 11
// 851.290 us; speedup vs baseline: 4.0015x; 1.0489x over previous
//
#include <hip/hip_runtime.h>
#include <hip/hip_bf16.h>
#include <math.h>

#define B_   16
#define L_   2048
#define D_   128
#define H_   4
#define NL_  4
#define DK_  32
#define DFF_ 256
#define INTD_ 11
#define F_OUT 129
#define DM_  16
#define FMINV (-3.402823466e38f)
#define LOG2E 1.4426950408889634f

#define BL_  (B_*L_)      // 32768
#define SZ_X (BL_*D_)     // 4194304 floats

#define PSTR 72           // attn P-scratch stride

#define WT_Q 0
#define WT_K 16384
#define WT_V 32768
#define WT_O 49152
#define WT_1 65536
#define WT_2 98304
#define WT_TOT 131072

typedef __attribute__((ext_vector_type(8))) short bf16x8;
typedef __attribute__((ext_vector_type(4))) float f32x4;

#if __has_builtin(__builtin_amdgcn_exp2f)
#define EXP2F(x) __builtin_amdgcn_exp2f(x)
#else
#define EXP2F(x) __expf(0.69314718055994531f*(x))
#endif

static __device__ __forceinline__ short f2bf(float x) {
    union { __hip_bfloat16 h; short s; } u;
    u.h = __float2bfloat16(x);
    return u.s;
}
static __device__ __forceinline__ float bf2f(short s) {
    union { __hip_bfloat16 h; short t; } u;
    u.t = s;
    return __bfloat162float(u.h);
}
static __device__ __forceinline__ void split2(float v, short& h, short& l) {
    h = f2bf(v); l = f2bf(v - bf2f(h));
}
static __device__ __forceinline__ void split_trunc(float v, short& h, short& l) {
    unsigned u = __float_as_uint(v);
    h = (short)(u >> 16);
    float r = v - __uint_as_float(u & 0xffff0000u);
    l = (short)(__float_as_uint(r) >> 16);
}

// ---------------------------------------------------------------------------
// Mask compaction: pos[b,l] = compact index or -1; kcount[b]; cfm[b,j]=0/FMIN.
// ---------------------------------------------------------------------------
__global__ __launch_bounds__(256)
void compact_kernel(const int* __restrict__ mask, int* __restrict__ pos,
                    int* __restrict__ kcount, float* __restrict__ cfm)
{
    int b = blockIdx.x, t = threadIdx.x;
    int lane = t & 63, w = t >> 6;
    __shared__ int wsum[4];
    __shared__ int tot_s;
    int mv[8], loc[8], s = 0;
#pragma unroll
    for (int i = 0; i < 8; ++i) {
        mv[i] = mask[b*L_ + t*8 + i];
        loc[i] = s;
        s += mv[i];
    }
    int v = s;
#pragma unroll
    for (int d = 1; d < 64; d <<= 1) {
        int y = __shfl_up(v, d);
        if (lane >= d) v += y;
    }
    int excl = v - s;
    if (lane == 63) wsum[w] = v;
    __syncthreads();
    int wbase = 0;
    for (int i = 0; i < w; ++i) wbase += wsum[i];
    int base = wbase + excl;
#pragma unroll
    for (int i = 0; i < 8; ++i)
        pos[b*L_ + t*8 + i] = mv[i] ? (base + loc[i]) : -1;
    if (t == 255) { kcount[b] = base + s; tot_s = base + s; }
    __syncthreads();
    int tot = tot_s;
    for (int l = t; l < L_; l += 256) cfm[b*L_ + l] = (l < tot) ? 0.0f : FMINV;
}

// ---------------------------------------------------------------------------
// Embedding with compaction: write row to its compact slot (skip masked).
// ---------------------------------------------------------------------------
__global__ __launch_bounds__(128)
void embed_kernel(const float* __restrict__ values, const float* __restrict__ times,
                  const int* __restrict__ variables, const int* __restrict__ pos,
                  const float* __restrict__ W1t, const float* __restrict__ b1t,
                  const float* __restrict__ W2t,
                  const float* __restrict__ W1v, const float* __restrict__ b1v,
                  const float* __restrict__ W2v,
                  const float* __restrict__ var_table, float* __restrict__ x)
{
    int bl = blockIdx.x;
    int p  = pos[bl];
    if (p < 0) return;
    int t  = threadIdx.x;
    __shared__ float th[INTD_], vh[INTD_];
    if (t < INTD_)                th[t]    = tanhf(times[bl]  * W1t[t]    + b1t[t]);
    if (t >= 64 && t < 64+INTD_)  vh[t-64] = tanhf(values[bl] * W1v[t-64] + b1v[t-64]);
    __syncthreads();
    int var = variables[bl];
    float acc = var_table[var*D_ + t];
#pragma unroll
    for (int i = 0; i < INTD_; ++i)
        acc += th[i]*W2t[i*D_ + t] + vh[i]*W2v[i*D_ + t];
    x[((size_t)((bl >> 11)*2048 + p))*D_ + t] = acc;
}

// zero compact x tail rows [Kb, ceil64(Kb)) once
__global__ __launch_bounds__(256)
void xtail_zero_kernel(const int* __restrict__ kcount, float* __restrict__ x)
{
    int b = blockIdx.x, t = threadIdx.x;
    int Kb = kcount[b];
    int end = (Kb + 63) & ~63;
    int tot = (end - Kb) * D_;
    for (int i = t; i < tot; i += 256)
        x[((size_t)(b*2048 + Kb))*D_ + i] = 0.0f;
}

// ---------------------------------------------------------------------------
// Weight pre-splits
// ---------------------------------------------------------------------------
__global__ __launch_bounds__(256)
void split_all_kernel(const float* __restrict__ Wq, const float* __restrict__ Wk,
                      const float* __restrict__ Wv, const float* __restrict__ Wo,
                      const float* __restrict__ W1, const float* __restrict__ W2,
                      short* __restrict__ hi, short* __restrict__ lo)
{
    int gidx = blockIdx.x*256 + threadIdx.x;
    int layer = gidx >> 17;
    int idx   = gidx & 131071;
    float v;
    if (idx < 49152) {
        int which = idx >> 14;
        int r = idx & 16383;
        int col = r >> 7, k = r & 127;
        int h = col >> 5, e = col & 31;
        const float* src = ((which == 0) ? Wq : (which == 1) ? Wk : Wv)
                           + (size_t)layer*H_*D_*DK_;
        v = src[(h*D_ + k)*DK_ + e];
    } else if (idx < 65536) {
        int r = idx - 49152;
        int col = r >> 7, k = r & 127;
        v = Wo[(size_t)layer*D_*D_ + k*D_ + col];
    } else if (idx < 98304) {
        int r = idx - 65536;
        int col = r >> 7, k = r & 127;
        v = W1[(size_t)layer*D_*DFF_ + k*DFF_ + col];
    } else {
        int r = idx - 98304;
        int col = r >> 8, k = r & 255;
        v = W2[(size_t)layer*DFF_*D_ + k*D_ + col];
    }
    short h2, l2; split2(v, h2, l2);
    hi[gidx] = h2; lo[gidx] = l2;
}

__global__ __launch_bounds__(256)
void split_nk_kernel(const float* __restrict__ W, short* __restrict__ hi,
                     short* __restrict__ lo, int N, int K)
{
    int idx = blockIdx.x*256 + threadIdx.x;
    int col = idx / K, k = idx - col*K;
    float v = W[k*N + col];
    short h2, l2; split2(v, h2, l2);
    hi[idx] = h2; lo[idx] = l2;
}

// ---------------------------------------------------------------------------
// MFMA GEMM on COMPACT rows (early-exit past ceil64(Kb)).
// EPI: 1=+resid 2=+bias,gelu 3=+bias,+resid 7=fusion att dot (+cfm)
// ---------------------------------------------------------------------------
template<int EPI>
__global__ __launch_bounds__(256)
void gemm_mfma(const float* __restrict__ A, const short* __restrict__ Whi,
               const short* __restrict__ Wlo, const float* __restrict__ bias,
               const float* __restrict__ resid, float* __restrict__ out,
               const float* __restrict__ cfm, const int* __restrict__ kcount,
               int N, int K)
{
    const int row0 = blockIdx.x * 64;
    const int bb = row0 >> 11;
    if (((row0 >> 6) & 31) >= ((kcount[bb] + 63) >> 6)) return;

    __shared__ short Ahi[64*136];
    __shared__ short Alo[64*136];
    __shared__ float part[64][16];
    const int t = threadIdx.x;
    const int w = t >> 6, lane = t & 63;
    const int m = lane & 15, qd = lane >> 4;
    const int col0 = blockIdx.y * 128;

    f32x4 acc[4][2];
#pragma unroll
    for (int r4 = 0; r4 < 4; ++r4)
#pragma unroll
        for (int j = 0; j < 2; ++j) acc[r4][j] = (f32x4){0,0,0,0};

    for (int kb = 0; kb < K; kb += 128) {
        if (kb) __syncthreads();
#pragma unroll
        for (int i = 0; i < 8; ++i) {
            int r = (t >> 5) + 8*i;
            int c = (t & 31) * 4;
            float4 av = *(const float4*)(A + (size_t)(row0 + r)*K + kb + c);
            short4 hi4, lo4;
            split2(av.x, hi4.x, lo4.x);
            split2(av.y, hi4.y, lo4.y);
            split2(av.z, hi4.z, lo4.z);
            split2(av.w, hi4.w, lo4.w);
            *(short4*)&Ahi[r*136 + c] = hi4;
            *(short4*)&Alo[r*136 + c] = lo4;
        }
        __syncthreads();

#pragma unroll
        for (int ks = 0; ks < 4; ++ks) {
            bf16x8 wh[2], wl[2];
#pragma unroll
            for (int j = 0; j < 2; ++j) {
                size_t wi = (size_t)(col0 + 32*w + 16*j + m)*K + kb + 32*ks + 8*qd;
                wh[j] = *(const bf16x8*)(Whi + wi);
                wl[j] = *(const bf16x8*)(Wlo + wi);
            }
#pragma unroll
            for (int r4 = 0; r4 < 4; ++r4) {
                bf16x8 ah = *(const bf16x8*)&Ahi[(16*r4 + m)*136 + 32*ks + 8*qd];
                bf16x8 al = *(const bf16x8*)&Alo[(16*r4 + m)*136 + 32*ks + 8*qd];
#pragma unroll
                for (int j = 0; j < 2; ++j) {
                    acc[r4][j] = __builtin_amdgcn_mfma_f32_16x16x32_bf16(wh[j], ah, acc[r4][j], 0, 0, 0);
                    acc[r4][j] = __builtin_amdgcn_mfma_f32_16x16x32_bf16(wh[j], al, acc[r4][j], 0, 0, 0);
                    acc[r4][j] = __builtin_amdgcn_mfma_f32_16x16x32_bf16(wl[j], ah, acc[r4][j], 0, 0, 0);
                }
            }
        }
    }

#pragma unroll
    for (int r4 = 0; r4 < 4; ++r4) {
        int row = row0 + 16*r4 + m;
        float dotp = 0.0f;
#pragma unroll
        for (int j = 0; j < 2; ++j) {
            int col = col0 + 32*w + 16*j + 4*qd;
            f32x4 v = acc[r4][j];
            if (EPI == 2 || EPI == 3 || EPI == 7) {
                float4 bv = *(const float4*)(bias + col);
                v[0] += bv.x; v[1] += bv.y; v[2] += bv.z; v[3] += bv.w;
            }
            if (EPI == 2) {
#pragma unroll
                for (int e = 0; e < 4; ++e)
                    v[e] = 0.5f * v[e] * (1.0f + erff(v[e] * 0.70710678118654752f));
            }
            if (EPI == 7) {
#pragma unroll
                for (int e = 0; e < 4; ++e) v[e] = tanhf(v[e]);
            }
            if (EPI == 1 || EPI == 3) {
                float4 rv = *(const float4*)(resid + (size_t)row*N + col);
                v[0] += rv.x; v[1] += rv.y; v[2] += rv.z; v[3] += rv.w;
            }
            if (EPI == 7) {
                float4 uv = *(const float4*)(resid + col);   // uf
                dotp += v[0]*uv.x + v[1]*uv.y + v[2]*uv.z + v[3]*uv.w;
            } else {
                float4 sv = {v[0], v[1], v[2], v[3]};
                *(float4*)(out + (size_t)row*N + col) = sv;
            }
        }
        if (EPI == 7) part[16*r4 + m][4*w + qd] = dotp;
    }
    if (EPI == 7) {
        __syncthreads();
        if (t < 64) {
            float s = 0.0f;
#pragma unroll
            for (int i = 0; i < 16; ++i) s += part[t][i];
            out[row0 + t] = s + cfm[row0 + t];
        }
    }
}

// ---------------------------------------------------------------------------
// Fused QKV GEMM on compact rows: Q fp32; K hi/lo head-major; V^T hi/lo.
// ---------------------------------------------------------------------------
__global__ __launch_bounds__(256)
void gemm_qkv_fused(const float* __restrict__ A, const short* __restrict__ Whi,
                    const short* __restrict__ Wlo, const int* __restrict__ kcount,
                    float* __restrict__ qout,
                    short* __restrict__ khi, short* __restrict__ klo,
                    short* __restrict__ vhiT, short* __restrict__ vloT)
{
    const int row0 = blockIdx.x * 64;
    const int bb = row0 >> 11;
    if (((row0 >> 6) & 31) >= ((kcount[bb] + 63) >> 6)) return;

    __shared__ short Ahi[64*136];
    __shared__ short Alo[64*136];
    const int t = threadIdx.x;
    const int w = t >> 6, lane = t & 63;
    const int m = lane & 15, qd = lane >> 4;

#pragma unroll
    for (int i = 0; i < 8; ++i) {
        int r = (t >> 5) + 8*i;
        int c = (t & 31) * 4;
        float4 av = *(const float4*)(A + (size_t)(row0 + r)*D_ + c);
        short4 hi4, lo4;
        split2(av.x, hi4.x, lo4.x);
        split2(av.y, hi4.y, lo4.y);
        split2(av.z, hi4.z, lo4.z);
        split2(av.w, hi4.w, lo4.w);
        *(short4*)&Ahi[r*136 + c] = hi4;
        *(short4*)&Alo[r*136 + c] = lo4;
    }
    __syncthreads();

#pragma unroll
    for (int sec = 0; sec < 3; ++sec) {
        const short* Wh = Whi + sec*16384;
        const short* Wl = Wlo + sec*16384;
        f32x4 acc[4][2];
#pragma unroll
        for (int r4 = 0; r4 < 4; ++r4)
#pragma unroll
            for (int j = 0; j < 2; ++j) acc[r4][j] = (f32x4){0,0,0,0};

#pragma unroll
        for (int ks = 0; ks < 4; ++ks) {
            bf16x8 wh[2], wl[2];
#pragma unroll
            for (int j = 0; j < 2; ++j) {
                size_t wi = (size_t)(32*w + 16*j + m)*D_ + 32*ks + 8*qd;
                wh[j] = *(const bf16x8*)(Wh + wi);
                wl[j] = *(const bf16x8*)(Wl + wi);
            }
#pragma unroll
            for (int r4 = 0; r4 < 4; ++r4) {
                bf16x8 ah = *(const bf16x8*)&Ahi[(16*r4 + m)*136 + 32*ks + 8*qd];
                bf16x8 al = *(const bf16x8*)&Alo[(16*r4 + m)*136 + 32*ks + 8*qd];
#pragma unroll
                for (int j = 0; j < 2; ++j) {
                    acc[r4][j] = __builtin_amdgcn_mfma_f32_16x16x32_bf16(wh[j], ah, acc[r4][j], 0, 0, 0);
                    acc[r4][j] = __builtin_amdgcn_mfma_f32_16x16x32_bf16(wh[j], al, acc[r4][j], 0, 0, 0);
                    acc[r4][j] = __builtin_amdgcn_mfma_f32_16x16x32_bf16(wl[j], ah, acc[r4][j], 0, 0, 0);
                }
            }
        }

#pragma unroll
        for (int r4 = 0; r4 < 4; ++r4) {
            int row = row0 + 16*r4 + m;
            int l = row & 2047;
#pragma unroll
            for (int j = 0; j < 2; ++j) {
                int col = 32*w + 16*j + 4*qd;
                f32x4 v = acc[r4][j];
                if (sec == 0) {
                    float4 sv = {v[0], v[1], v[2], v[3]};
                    *(float4*)(qout + (size_t)row*D_ + col) = sv;
                } else if (sec == 1) {
                    size_t idx = ((size_t)((bb*4 + w)*2048 + l))*32 + (col & 31);
                    short4 hi4, lo4;
                    split2(v[0], hi4.x, lo4.x);
                    split2(v[1], hi4.y, lo4.y);
                    split2(v[2], hi4.z, lo4.z);
                    split2(v[3], hi4.w, lo4.w);
                    *(short4*)(khi + idx) = hi4;
                    *(short4*)(klo + idx) = lo4;
                } else {
                    size_t basep = (size_t)(bb*4 + w)*32;
#pragma unroll
                    for (int e = 0; e < 4; ++e) {
                        int d = 16*j + 4*qd + e;
                        short hh, ll; split2(v[e], hh, ll);
                        vhiT[(basep + d)*2048 + l] = hh;
                        vloT[(basep + d)*2048 + l] = ll;
                    }
                }
            }
        }
    }
}

// ---------------------------------------------------------------------------
// MFMA flash attention over compact rows (unchanged from R10 core).
// ---------------------------------------------------------------------------
__global__ __launch_bounds__(256)
void attn_mfma_kernel(const float* __restrict__ q,
                      const short* __restrict__ khi, const short* __restrict__ klo,
                      const short* __restrict__ vhiT, const short* __restrict__ vloT,
                      const int* __restrict__ kcount, const float* __restrict__ cfm,
                      float* __restrict__ o)
{
    __shared__ short KhiS[64*32];
    __shared__ short KloS[64*32];
    __shared__ short Vthi[32*72];
    __shared__ short Vtlo[32*72];
    __shared__ short Pshi[4][16*PSTR];
    __shared__ short Pslo[4][16*PSTR];
    __shared__ float kmf[64];
    __shared__ float al_ls[4][16];
    __shared__ float l_ls [4][16];

    const int t    = threadIdx.x;
    const int w    = t >> 6;
    const int lane = t & 63;
    const int m    = lane & 15;
    const int qd   = lane >> 4;
    const int qt = blockIdx.x, h = blockIdx.y, b = blockIdx.z;

    const int Kb = kcount[b];
    if (qt*64 >= Kb) return;
    const int nt = (Kb + 63) >> 6;

    const size_t hd = ((size_t)(b*4 + h))*2048*32;
    const int vd = t >> 3;
    const int vk = (t & 7) * 8;
    const size_t vbase = ((size_t)(b*4 + h)*32 + vd)*2048 + vk;

    const int qrow = qt*64 + 16*w + m;
    const float* qp = q + ((size_t)(b*L_ + qrow))*D_ + h*DK_ + 8*qd;
    float qf[8];
    *(float4*)&qf[0] = *(const float4*)qp;
    *(float4*)&qf[4] = *(const float4*)(qp + 4);
    bf16x8 qhi, qlo;
#pragma unroll
    for (int j = 0; j < 8; ++j) {
        float qs = qf[j] * LOG2E;
        short hs = f2bf(qs);
        qhi[j] = hs;
        qlo[j] = f2bf(qs - bf2f(hs));
    }

    bf16x8 pkh, pkl, pvh, pvl;
    float4 pmask = {0,0,0,0};
    {
        const size_t gk = hd + (size_t)t*8;
        pkh = *(const bf16x8*)(khi + gk);
        pkl = *(const bf16x8*)(klo + gk);
        pvh = *(const bf16x8*)(vhiT + vbase);
        pvl = *(const bf16x8*)(vloT + vbase);
        if (t < 16) pmask = ((const float4*)(cfm + (size_t)b*L_))[t];
    }

    float m_old = -INFINITY, l_run = 0.0f;
    f32x4 o_acc[2] = {{0,0,0,0},{0,0,0,0}};

    for (int kt = 0; kt < nt; ++kt) {
        __syncthreads();
        *(bf16x8*)&KhiS[t*8] = pkh;
        *(bf16x8*)&KloS[t*8] = pkl;
        *(bf16x8*)&Vthi[vd*72 + vk] = pvh;
        *(bf16x8*)&Vtlo[vd*72 + vk] = pvl;
        if (t < 16) ((float4*)kmf)[t] = pmask;
        __syncthreads();
        if (kt + 1 < nt) {
            const size_t gk = hd + (size_t)(kt+1)*64*32 + t*8;
            pkh = *(const bf16x8*)(khi + gk);
            pkl = *(const bf16x8*)(klo + gk);
            pvh = *(const bf16x8*)(vhiT + vbase + (size_t)(kt+1)*64);
            pvl = *(const bf16x8*)(vloT + vbase + (size_t)(kt+1)*64);
            if (t < 16) pmask = ((const float4*)(cfm + (size_t)b*L_ + (size_t)(kt+1)*64))[t];
        }

        f32x4 sf[4];
#pragma unroll
        for (int k4 = 0; k4 < 4; ++k4) {
            bf16x8 ka = *(const bf16x8*)&KhiS[(16*k4 + m)*32 + 8*qd];
            bf16x8 kl = *(const bf16x8*)&KloS[(16*k4 + m)*32 + 8*qd];
            f32x4 c = {0,0,0,0};
            c = __builtin_amdgcn_mfma_f32_16x16x32_bf16(ka, qhi, c, 0, 0, 0);
            c = __builtin_amdgcn_mfma_f32_16x16x32_bf16(ka, qlo, c, 0, 0, 0);
            c = __builtin_amdgcn_mfma_f32_16x16x32_bf16(kl, qhi, c, 0, 0, 0);
            sf[k4] = c;
        }

        float sv[16];
#pragma unroll
        for (int k4 = 0; k4 < 4; ++k4) {
            float4 kmv = *(const float4*)&kmf[16*k4 + 4*qd];
            sv[4*k4+0] = sf[k4][0] + kmv.x;
            sv[4*k4+1] = sf[k4][1] + kmv.y;
            sv[4*k4+2] = sf[k4][2] + kmv.z;
            sv[4*k4+3] = sf[k4][3] + kmv.w;
        }

        float tmax = sv[0];
#pragma unroll
        for (int j = 1; j < 16; ++j) tmax = fmaxf(tmax, sv[j]);
        tmax = fmaxf(tmax, __shfl_xor(tmax, 16));
        tmax = fmaxf(tmax, __shfl_xor(tmax, 32));
        float mnew  = fmaxf(m_old, tmax);
        float alpha = EXP2F(m_old - mnew);
        float psum = 0.0f;
        short pbh[16], pbl[16];
#pragma unroll
        for (int j = 0; j < 16; ++j) {
            float p = EXP2F(sv[j] - mnew);
            psum += p;
            split_trunc(p, pbh[j], pbl[j]);
        }
        psum += __shfl_xor(psum, 16);
        psum += __shfl_xor(psum, 32);
        l_run = l_run * alpha + psum;
        m_old = mnew;

#pragma unroll
        for (int k4 = 0; k4 < 4; ++k4) {
            short4 s4h, s4l;
            s4h.x = pbh[4*k4+0]; s4h.y = pbh[4*k4+1]; s4h.z = pbh[4*k4+2]; s4h.w = pbh[4*k4+3];
            s4l.x = pbl[4*k4+0]; s4l.y = pbl[4*k4+1]; s4l.z = pbl[4*k4+2]; s4l.w = pbl[4*k4+3];
            *(short4*)&Pshi[w][m*PSTR + 16*k4 + 4*qd] = s4h;
            *(short4*)&Pslo[w][m*PSTR + 16*k4 + 4*qd] = s4l;
        }
        if (lane < 16) al_ls[w][lane] = alpha;

        {
            float4 alr = *(const float4*)&al_ls[w][4*qd];
            o_acc[0][0]*=alr.x; o_acc[0][1]*=alr.y; o_acc[0][2]*=alr.z; o_acc[0][3]*=alr.w;
            o_acc[1][0]*=alr.x; o_acc[1][1]*=alr.y; o_acc[1][2]*=alr.z; o_acc[1][3]*=alr.w;
        }
#pragma unroll
        for (int s = 0; s < 2; ++s) {
            bf16x8 pah = *(const bf16x8*)&Pshi[w][m*PSTR + 32*s + 8*qd];
            bf16x8 pal = *(const bf16x8*)&Pslo[w][m*PSTR + 32*s + 8*qd];
#pragma unroll
            for (int tp = 0; tp < 2; ++tp) {
                bf16x8 vh = *(const bf16x8*)&Vthi[(16*tp + m)*72 + 32*s + 8*qd];
                bf16x8 vl = *(const bf16x8*)&Vtlo[(16*tp + m)*72 + 32*s + 8*qd];
                o_acc[tp] = __builtin_amdgcn_mfma_f32_16x16x32_bf16(pah, vh, o_acc[tp], 0, 0, 0);
                o_acc[tp] = __builtin_amdgcn_mfma_f32_16x16x32_bf16(pah, vl, o_acc[tp], 0, 0, 0);
                o_acc[tp] = __builtin_amdgcn_mfma_f32_16x16x32_bf16(pal, vh, o_acc[tp], 0, 0, 0);
            }
        }
    }

    if (lane < 16) l_ls[w][lane] = l_run;
    float4 lr = *(const float4*)&l_ls[w][4*qd];
    float li[4] = {1.0f/lr.x, 1.0f/lr.y, 1.0f/lr.z, 1.0f/lr.w};
#pragma unroll
    for (int tp = 0; tp < 2; ++tp)
#pragma unroll
        for (int r = 0; r < 4; ++r)
            o[((size_t)(b*L_ + qt*64 + 16*w + 4*qd + r))*D_ + h*DK_ + 16*tp + m] =
                o_acc[tp][r] * li[r];
}

// ---------------------------------------------------------------------------
// Pooling: per-batch softmax over compact att rows (< ceil64(Kb)); p=0 beyond.
// ---------------------------------------------------------------------------
__global__ __launch_bounds__(256)
void pool_stats_kernel(const float* __restrict__ att, const int* __restrict__ kcount,
                       float* __restrict__ p)
{
    int b = blockIdx.x, t = threadIdx.x;
    int lim = (kcount[b] + 63) & ~63;
    __shared__ float red[4];
    __shared__ float a_s[L_];

    float m = -INFINITY;
    for (int l = t; l < L_; l += 256) {
        float a = (l < lim) ? att[b*L_ + l] : FMINV;
        a_s[l] = a;
        m = fmaxf(m, a);
    }
#pragma unroll
    for (int s = 1; s < 64; s <<= 1) m = fmaxf(m, __shfl_xor(m, s));
    if ((t & 63) == 0) red[t >> 6] = m;
    __syncthreads();
    m = fmaxf(fmaxf(red[0], red[1]), fmaxf(red[2], red[3]));
    __syncthreads();

    float s = 0.0f;
    for (int l = t; l < L_; l += 256) s += __expf(a_s[l] - m);
#pragma unroll
    for (int st = 1; st < 64; st <<= 1) s += __shfl_xor(s, st);
    if ((t & 63) == 0) red[t >> 6] = s;
    __syncthreads();
    s = red[0] + red[1] + red[2] + red[3];
    float inv = 1.0f / s;
    for (int l = t; l < L_; l += 256)
        p[b*L_ + l] = (l < lim) ? __expf(a_s[l] - m) * inv : 0.0f;
}

__global__ __launch_bounds__(128)
void pool_partial_kernel(const float* __restrict__ p, const float* __restrict__ x,
                         float* __restrict__ part)
{
    int c = blockIdx.x, b = blockIdx.y, d = threadIdx.x;
    const float* xb = x + ((size_t)(b*L_ + c*128))*D_ + d;
    const float* pb = p + b*L_ + c*128;
    float acc = 0.0f;
#pragma unroll 4
    for (int i = 0; i < 128; ++i) acc += pb[i] * xb[(size_t)i*D_];
    part[((size_t)b*16 + c)*D_ + d] = acc;
}

// ---------------------------------------------------------------------------
// Demographics MLP
// ---------------------------------------------------------------------------
__global__ __launch_bounds__(256)
void demo_kernel(const float* __restrict__ demog, const float* __restrict__ Wd1,
                 const float* __restrict__ bd1, const float* __restrict__ Wd2,
                 const float* __restrict__ bd2, float* __restrict__ demo_out)
{
    int t = threadIdx.x;
    __shared__ float dsm[B_][DM_];
    __shared__ float hs[B_][2*D_];
    if (t < B_*DM_) dsm[t >> 4][t & 15] = demog[t];
    __syncthreads();
    {
        int col = t;
#pragma unroll
        for (int r = 0; r < B_; ++r) {
            float acc = bd1[col];
#pragma unroll
            for (int kk = 0; kk < DM_; ++kk) acc += dsm[r][kk]*Wd1[kk*(2*D_)+col];
            hs[r][col] = tanhf(acc);
        }
    }
    __syncthreads();
    {
        int c  = t & (D_-1);
        int r0 = t >> 7;
        for (int r = r0; r < B_; r += 2) {
            float acc = bd2[c];
            for (int kk = 0; kk < 2*D_; ++kk) acc += hs[r][kk]*Wd2[kk*D_+c];
            demo_out[r*D_+c] = acc;
        }
    }
}

// ---------------------------------------------------------------------------
// Head
// ---------------------------------------------------------------------------
__global__ __launch_bounds__(256)
void head_kernel(const float* __restrict__ part, const float* __restrict__ demo,
                 const float* __restrict__ Wh, const float* __restrict__ bh,
                 float* __restrict__ out)
{
    int b = blockIdx.x, t = threadIdx.x;
    __shared__ float tss[128];
    if (t < 128) {
        float s = 0.0f;
#pragma unroll
        for (int c = 0; c < 16; ++c) s += part[((size_t)b*16 + c)*D_ + t];
        tss[t] = s;
    }
    __syncthreads();
    if (t >= F_OUT) return;
    float acc = bh[t];
    for (int k2 = 0; k2 < D_; ++k2) acc += tss[k2]         * Wh[k2*F_OUT + t];
    for (int k2 = 0; k2 < D_; ++k2) acc += demo[b*D_ + k2] * Wh[(D_+k2)*F_OUT + t];
    out[b*F_OUT + t] = acc;
}

// ---------------------------------------------------------------------------
extern "C" void kernel_launch(void* const* d_in, const int* in_sizes, int n_in,
                              void* d_out, int out_size, void* d_ws, size_t ws_size,
                              hipStream_t stream)
{
    (void)in_sizes; (void)n_in; (void)out_size; (void)ws_size;
    const float* values       = (const float*)d_in[0];
    const float* times        = (const float*)d_in[1];
    const int*   variables    = (const int*)  d_in[2];
    const int*   input_mask   = (const int*)  d_in[3];
    const float* demographics = (const float*)d_in[4];
    const float* W1t = (const float*)d_in[5];
    const float* b1t = (const float*)d_in[6];
    const float* W2t = (const float*)d_in[7];
    const float* W1v = (const float*)d_in[8];
    const float* b1v = (const float*)d_in[9];
    const float* W2v = (const float*)d_in[10];
    const float* var_table = (const float*)d_in[11];
    const float* Wq  = (const float*)d_in[12];
    const float* Wk  = (const float*)d_in[13];
    const float* Wv  = (const float*)d_in[14];
    const float* Wo  = (const float*)d_in[15];
    const float* W1  = (const float*)d_in[16];
    const float* b1  = (const float*)d_in[17];
    const float* W2  = (const float*)d_in[18];
    const float* b2  = (const float*)d_in[19];
    const float* Wf  = (const float*)d_in[20];
    const float* bfv = (const float*)d_in[21];
    const float* uf  = (const float*)d_in[22];
    const float* Wd1 = (const float*)d_in[23];
    const float* bd1 = (const float*)d_in[24];
    const float* Wd2 = (const float*)d_in[25];
    const float* bd2 = (const float*)d_in[26];
    const float* Wh  = (const float*)d_in[27];
    const float* bhv = (const float*)d_in[28];
    float* out = (float*)d_out;

    float* ws     = (float*)d_ws;
    float* x      = ws;                   // compact rows
    float* qb     = ws + (size_t)SZ_X;
    float* region = ws + (size_t)2*SZ_X;
    short* khi    = (short*)region;
    short* klo    = khi + (size_t)SZ_X;
    short* vhiT   = klo + (size_t)SZ_X;
    short* vloT   = vhiT + (size_t)SZ_X;
    float* hb     = region;               // alias (FFN hidden)
    float* attb   = ws + (size_t)4*SZ_X;  // BL_
    float* attp   = attb + BL_;           // BL_
    float* partb  = attp + BL_;           // B_*16*D_
    float* demob  = partb + B_*16*D_;     // B_*D_
    short* wt_hi  = (short*)(demob + B_*D_);
    short* wt_lo  = wt_hi + (size_t)NL_*WT_TOT;
    short* wfhi   = wt_lo + (size_t)NL_*WT_TOT;
    short* wflo   = wfhi + 16384;
    int*   posb   = (int*)(wflo + 16384);       // BL_
    int*   kcountb= posb + BL_;                 // B_
    float* cfmb   = (float*)(kcountb + B_);     // BL_

    compact_kernel<<<B_, 256, 0, stream>>>(input_mask, posb, kcountb, cfmb);
    embed_kernel<<<BL_, 128, 0, stream>>>(values, times, variables, posb,
                                          W1t, b1t, W2t, W1v, b1v, W2v,
                                          var_table, x);
    xtail_zero_kernel<<<B_, 256, 0, stream>>>(kcountb, x);
    demo_kernel<<<1, 256, 0, stream>>>(demographics, Wd1, bd1, Wd2, bd2, demob);
    split_nk_kernel<<<64, 256, 0, stream>>>(Wf, wfhi, wflo, D_, D_);
    split_all_kernel<<<NL_*512, 256, 0, stream>>>(Wq, Wk, Wv, Wo, W1, W2, wt_hi, wt_lo);

    for (int i = 0; i < NL_; ++i) {
        short* whL = wt_hi + (size_t)i*WT_TOT;
        short* wlL = wt_lo + (size_t)i*WT_TOT;
        gemm_qkv_fused<<<BL_/64, 256, 0, stream>>>(x, whL, wlL, kcountb,
            qb, khi, klo, vhiT, vloT);
        attn_mfma_kernel<<<dim3(L_/64, H_, B_), 256, 0, stream>>>(qb, khi, klo, vhiT, vloT,
                                                                  kcountb, cfmb, qb);
        gemm_mfma<1><<<dim3(BL_/64, 1), 256, 0, stream>>>(qb, whL+WT_O, wlL+WT_O,
            nullptr, x, x, nullptr, kcountb, D_, D_);
        gemm_mfma<2><<<dim3(BL_/64, 2), 256, 0, stream>>>(x, whL+WT_1, wlL+WT_1,
            b1 + i*DFF_, nullptr, hb, nullptr, kcountb, DFF_, D_);
        gemm_mfma<3><<<dim3(BL_/64, 1), 256, 0, stream>>>(hb, whL+WT_2, wlL+WT_2,
            b2 + i*D_, x, x, nullptr, kcountb, D_, DFF_);
    }

    // fused fusion-attention on compact rows: att = tanh(x@Wf+bf).uf + cfm
    gemm_mfma<7><<<dim3(BL_/64, 1), 256, 0, stream>>>(x, wfhi, wflo,
        bfv, uf, attb, cfmb, kcountb, D_, D_);
    pool_stats_kernel<<<B_, 256, 0, stream>>>(attb, kcountb, attp);
    pool_partial_kernel<<<dim3(16, B_), 128, 0, stream>>>(attp, x, partb);
    head_kernel<<<B_, 256, 0, stream>>>(partb, demob, Wh, bhv, out);
}